// Round 1
// baseline (12669.547 us; speedup 1.0000x reference)
//
#include <hip/hip_runtime.h>
#include <math.h>

// Problem constants (fixed by the reference).
#define NN   100000
#define EE   1600000
#define F    128      // IN_FEATS == H == 128
#define ZD   32       // Z_DIM
#define NB3  384      // H * 3 thetas
#define ROWS 8        // rows per block in fused GEMM kernels

// THETAS (D=2):
//   t0 = [3, -3, 0.75], t1 = [0, 3, -1.5], t2 = [0, 0, 0.75]
// hs = [3x - 3y1 + 0.75y2 | 3y1 - 1.5y2 | 0.75y2],  y1 = P(x), y2 = P(y1)
// P(x) = x - dinv * A(x * dinv),  A = scatter-add over edges (src -> dst)
// output scalar == vgae_loss = sum((x_rec - feats)^2) - 0.5*sum(1 + mu - mu^2 - exp(mu))

__device__ __forceinline__ unsigned pcg_hash(unsigned v) {
    v = v * 747796405u + 2891336453u;
    unsigned w = ((v >> ((v >> 28u) + 4u)) ^ v) * 277803737u;
    return (w >> 22u) ^ w;
}

__device__ __forceinline__ float block_reduce_sum(float v) {
    #pragma unroll
    for (int o = 32; o > 0; o >>= 1) v += __shfl_down(v, o, 64);
    __shared__ float s[8];
    int lane = threadIdx.x & 63, w = threadIdx.x >> 6;
    if (lane == 0) s[w] = v;
    __syncthreads();
    float t = 0.f;
    if (threadIdx.x == 0) {
        int nw = (blockDim.x + 63) >> 6;
        for (int i = 0; i < nw; ++i) t += s[i];
    }
    return t;
}

// ---------- degree / dinv ----------
__global__ __launch_bounds__(256) void deg_kernel(const int* __restrict__ dst,
                                                  int* __restrict__ degs, int e) {
    int i = blockIdx.x * 256 + threadIdx.x;
    if (i < e) atomicAdd(&degs[dst[i]], 1);
}

__global__ __launch_bounds__(256) void dinv_kernel(const int* __restrict__ degs,
                                                   float* __restrict__ dinv, int n) {
    int i = blockIdx.x * 256 + threadIdx.x;
    if (i < n) {
        float d = fmaxf((float)degs[i], 1.f);
        dinv[i] = 1.f / sqrtf(d);
    }
}

// ---------- enc fc1: out = relu(x @ w.T + b), x (n,128), w (128,128) ----------
__global__ __launch_bounds__(128) void fc1_relu_kernel(const float* __restrict__ x,
                                                       const float* __restrict__ w,
                                                       const float* __restrict__ b,
                                                       float* __restrict__ out, int n) {
    __shared__ float xr[ROWS][F];
    int r0 = blockIdx.x * ROWS;
    int j = threadIdx.x;
    for (int rr = 0; rr < ROWS; ++rr) {
        int r = r0 + rr;
        xr[rr][j] = (r < n) ? x[(size_t)r * F + j] : 0.f;
    }
    __syncthreads();
    float acc[ROWS];
    float bj = b[j];
    #pragma unroll
    for (int rr = 0; rr < ROWS; ++rr) acc[rr] = bj;
    const float* wrow = w + (size_t)j * F;
    for (int k = 0; k < F; ++k) {
        float wv = wrow[k];
        #pragma unroll
        for (int rr = 0; rr < ROWS; ++rr) acc[rr] += xr[rr][k] * wv;
    }
    for (int rr = 0; rr < ROWS; ++rr) {
        int r = r0 + rr;
        if (r < n) out[(size_t)r * F + j] = fmaxf(acc[rr], 0.f);
    }
}

// ---------- SpMM scatter: agg[dst] += x[src]*dinv[src] (4 floats/thread) ----------
__global__ __launch_bounds__(256) void spmm_scatter_kernel(const float* __restrict__ x,
                                                           const int* __restrict__ src,
                                                           const int* __restrict__ dst,
                                                           const float* __restrict__ dinv,
                                                           float* __restrict__ agg, int e) {
    int tid = blockIdx.x * 256 + threadIdx.x;   // e*32 threads
    int edge = tid >> 5;
    if (edge >= e) return;
    int c = (tid & 31) * 4;
    int s = src[edge], d = dst[edge];
    float sc = dinv[s];
    float4 v = *reinterpret_cast<const float4*>(x + (size_t)s * F + c);
    float* p = agg + (size_t)d * F + c;
    atomicAdd(p + 0, v.x * sc);
    atomicAdd(p + 1, v.y * sc);
    atomicAdd(p + 2, v.z * sc);
    atomicAdd(p + 3, v.w * sc);
}

// ---------- SpMM finish: agg = x - dinv*agg ----------
__global__ __launch_bounds__(256) void spmm_finish_kernel(const float* __restrict__ x,
                                                          const float* __restrict__ dinv,
                                                          float* __restrict__ agg, int n) {
    int tid = blockIdx.x * 256 + threadIdx.x;   // n*32 float4 slots
    if (tid >= n * 32) return;
    int row = tid >> 5;
    float di = dinv[row];
    float4 a = *reinterpret_cast<float4*>(agg + (size_t)tid * 4);
    float4 xv = *reinterpret_cast<const float4*>(x + (size_t)tid * 4);
    float4 o;
    o.x = xv.x - di * a.x;
    o.y = xv.y - di * a.y;
    o.z = xv.z - di * a.z;
    o.w = xv.w - di * a.w;
    *reinterpret_cast<float4*>(agg + (size_t)tid * 4) = o;
}

// ---------- enc fc2 (hs @ w2.T + b2) fused with rep projection -> mu ----------
__global__ __launch_bounds__(128) void enc2rep_kernel(const float* __restrict__ xA,
                                                      const float* __restrict__ y1,
                                                      const float* __restrict__ y2,
                                                      const float* __restrict__ w2,
                                                      const float* __restrict__ b2,
                                                      const float* __restrict__ repw,
                                                      const float* __restrict__ repb,
                                                      float* __restrict__ mu, int n) {
    __shared__ float hs[ROWS][NB3];
    __shared__ float pos[ROWS][F];
    int r0 = blockIdx.x * ROWS;
    int j = threadIdx.x;
    for (int rr = 0; rr < ROWS; ++rr) {
        int r = r0 + rr;
        float xv = 0.f, a = 0.f, bv = 0.f;
        if (r < n) {
            size_t o = (size_t)r * F + j;
            xv = xA[o]; a = y1[o]; bv = y2[o];
        }
        hs[rr][j]       = 3.f * xv - 3.f * a + 0.75f * bv;
        hs[rr][128 + j] = 3.f * a - 1.5f * bv;
        hs[rr][256 + j] = 0.75f * bv;
    }
    __syncthreads();
    float acc[ROWS];
    float bj = b2[j];
    #pragma unroll
    for (int rr = 0; rr < ROWS; ++rr) acc[rr] = bj;
    const float* wrow = w2 + (size_t)j * NB3;
    for (int k = 0; k < NB3; ++k) {
        float wv = wrow[k];
        #pragma unroll
        for (int rr = 0; rr < ROWS; ++rr) acc[rr] += hs[rr][k] * wv;
    }
    for (int rr = 0; rr < ROWS; ++rr) pos[rr][j] = acc[rr];
    __syncthreads();
    // mu: ROWS*32 = 256 outputs across 128 threads
    #pragma unroll
    for (int p = 0; p < 2; ++p) {
        int idx = j + p * 128;
        int rr = idx >> 5;
        int i  = idx & 31;
        float m = repb[i];
        const float* rw = repw + (size_t)i * F;
        for (int k = 0; k < F; ++k) m += pos[rr][k] * rw[k];
        int r = r0 + rr;
        if (r < n) mu[(size_t)r * ZD + i] = m;
    }
}

// ---------- KL accumulation + reparameterize z (in place over mu) ----------
__global__ __launch_bounds__(256) void zkl_kernel(float* __restrict__ m,
                                                  double* __restrict__ acc, int total) {
    int i = blockIdx.x * 256 + threadIdx.x;
    float v = 0.f;
    if (i < total) {
        float mu = m[i];
        v = 1.f + mu - mu * mu - expf(mu);
        unsigned h1 = pcg_hash(2u * (unsigned)i + 1u);
        unsigned h2 = pcg_hash(2u * (unsigned)i + 2u);
        float u1 = ((float)h1 + 0.5f) * 2.3283064365386963e-10f;  // (0,1)
        float u2 = ((float)h2 + 0.5f) * 2.3283064365386963e-10f;
        float rad = sqrtf(-2.f * logf(u1));
        float eps = rad * cosf(6.283185307179586f * u2);
        m[i] = mu + eps * expf(0.5f * mu);
    }
    float bs = block_reduce_sum(v);
    if (threadIdx.x == 0) atomicAdd(&acc[1], (double)bs);
}

// ---------- rec linear (z @ rec_w.T + rec_b) fused with dec fc1 relu ----------
__global__ __launch_bounds__(128) void recdec1_kernel(const float* __restrict__ z,
                                                      const float* __restrict__ recw,
                                                      const float* __restrict__ recb,
                                                      const float* __restrict__ w1,
                                                      const float* __restrict__ b1,
                                                      float* __restrict__ out, int n) {
    __shared__ float zs[ROWS][ZD];
    __shared__ float zz[ROWS][F];
    int r0 = blockIdx.x * ROWS;
    int j = threadIdx.x;
    #pragma unroll
    for (int p = 0; p < 2; ++p) {
        int idx = j + p * 128;
        int rr = idx >> 5, i = idx & 31;
        int r = r0 + rr;
        zs[rr][i] = (r < n) ? z[(size_t)r * ZD + i] : 0.f;
    }
    __syncthreads();
    const float* rw = recw + (size_t)j * ZD;
    float rbj = recb[j];
    for (int rr = 0; rr < ROWS; ++rr) {
        float a = rbj;
        #pragma unroll
        for (int i = 0; i < ZD; ++i) a += zs[rr][i] * rw[i];
        zz[rr][j] = a;
    }
    __syncthreads();
    float acc[ROWS];
    float bj = b1[j];
    #pragma unroll
    for (int rr = 0; rr < ROWS; ++rr) acc[rr] = bj;
    const float* wrow = w1 + (size_t)j * F;
    for (int k = 0; k < F; ++k) {
        float wv = wrow[k];
        #pragma unroll
        for (int rr = 0; rr < ROWS; ++rr) acc[rr] += zz[rr][k] * wv;
    }
    for (int rr = 0; rr < ROWS; ++rr) {
        int r = r0 + rr;
        if (r < n) out[(size_t)r * F + j] = fmaxf(acc[rr], 0.f);
    }
}

// ---------- dec fc2 fused with reconstruction loss ----------
__global__ __launch_bounds__(128) void dec2loss_kernel(const float* __restrict__ xA,
                                                       const float* __restrict__ y1,
                                                       const float* __restrict__ y2,
                                                       const float* __restrict__ w2,
                                                       const float* __restrict__ b2,
                                                       const float* __restrict__ feats,
                                                       double* __restrict__ acc, int n) {
    __shared__ float hs[ROWS][NB3];
    int r0 = blockIdx.x * ROWS;
    int j = threadIdx.x;
    for (int rr = 0; rr < ROWS; ++rr) {
        int r = r0 + rr;
        float xv = 0.f, a = 0.f, bv = 0.f;
        if (r < n) {
            size_t o = (size_t)r * F + j;
            xv = xA[o]; a = y1[o]; bv = y2[o];
        }
        hs[rr][j]       = 3.f * xv - 3.f * a + 0.75f * bv;
        hs[rr][128 + j] = 3.f * a - 1.5f * bv;
        hs[rr][256 + j] = 0.75f * bv;
    }
    __syncthreads();
    float accv[ROWS];
    float bj = b2[j];
    #pragma unroll
    for (int rr = 0; rr < ROWS; ++rr) accv[rr] = bj;
    const float* wrow = w2 + (size_t)j * NB3;
    for (int k = 0; k < NB3; ++k) {
        float wv = wrow[k];
        #pragma unroll
        for (int rr = 0; rr < ROWS; ++rr) accv[rr] += hs[rr][k] * wv;
    }
    float local = 0.f;
    for (int rr = 0; rr < ROWS; ++rr) {
        int r = r0 + rr;
        if (r < n) {
            float d = accv[rr] - feats[(size_t)r * F + j];
            local += d * d;
        }
    }
    float bs = block_reduce_sum(local);
    if (threadIdx.x == 0) atomicAdd(&acc[0], (double)bs);
}

__global__ void finalize_kernel(const double* __restrict__ acc, float* __restrict__ out) {
    out[0] = (float)(acc[0] - 0.5 * acc[1]);
}

extern "C" void kernel_launch(void* const* d_in, const int* in_sizes, int n_in,
                              void* d_out, int out_size, void* d_ws, size_t ws_size,
                              hipStream_t stream) {
    const float* feats  = (const float*)d_in[0];
    const int*   src    = (const int*)d_in[1];
    const int*   dst    = (const int*)d_in[2];
    const float* enc_w1 = (const float*)d_in[3];
    const float* enc_b1 = (const float*)d_in[4];
    const float* enc_w2 = (const float*)d_in[5];
    const float* enc_b2 = (const float*)d_in[6];
    const float* dec_w1 = (const float*)d_in[7];
    const float* dec_b1 = (const float*)d_in[8];
    const float* dec_w2 = (const float*)d_in[9];
    const float* dec_b2 = (const float*)d_in[10];
    const float* rep_w  = (const float*)d_in[11];
    const float* rep_b  = (const float*)d_in[12];
    const float* rec_w  = (const float*)d_in[13];
    const float* rec_b  = (const float*)d_in[14];
    // d_in[15] = disc_w: unused (dgi branch cancels analytically)

    const int n = NN, e = EE;
    char* ws = (char*)d_ws;
    size_t off = 0;
    auto alloc = [&](size_t bytes) -> void* {
        void* p = ws + off;
        off += (bytes + 255) & ~(size_t)255;
        return p;
    };
    const size_t NF4 = (size_t)n * F * sizeof(float);   // 51.2 MB
    int*    degs = (int*)alloc((size_t)n * sizeof(int));
    float*  dinv = (float*)alloc((size_t)n * sizeof(float));
    float*  A    = (float*)alloc(NF4);                  // x1 / x1d
    float*  B    = (float*)alloc(NF4);                  // y1 / y1d
    float*  C    = (float*)alloc(NF4);                  // y2 / y2d
    float*  M    = (float*)alloc((size_t)n * ZD * sizeof(float));  // mu -> z
    double* acc  = (double*)alloc(2 * sizeof(double));  // [0]=reconst, [1]=kl raw sum

    const int gemmBlocks = (n + ROWS - 1) / ROWS;        // 12500
    const int scatBlocks = (e * 32 + 255) / 256;         // 200000
    const int finBlocks  = (n * 32 + 255) / 256;         // 12500

    // degrees + dinv
    hipMemsetAsync(degs, 0, (size_t)n * sizeof(int), stream);
    deg_kernel<<<(e + 255) / 256, 256, 0, stream>>>(dst, degs, e);
    dinv_kernel<<<(n + 255) / 256, 256, 0, stream>>>(degs, dinv, n);

    // encoder
    fc1_relu_kernel<<<gemmBlocks, 128, 0, stream>>>(feats, enc_w1, enc_b1, A, n);
    hipMemsetAsync(B, 0, NF4, stream);
    spmm_scatter_kernel<<<scatBlocks, 256, 0, stream>>>(A, src, dst, dinv, B, e);
    spmm_finish_kernel<<<finBlocks, 256, 0, stream>>>(A, dinv, B, n);
    hipMemsetAsync(C, 0, NF4, stream);
    spmm_scatter_kernel<<<scatBlocks, 256, 0, stream>>>(B, src, dst, dinv, C, e);
    spmm_finish_kernel<<<finBlocks, 256, 0, stream>>>(B, dinv, C, n);
    enc2rep_kernel<<<gemmBlocks, 128, 0, stream>>>(A, B, C, enc_w2, enc_b2,
                                                   rep_w, rep_b, M, n);

    // kl + reparameterize (z over mu, in place)
    hipMemsetAsync(acc, 0, 2 * sizeof(double), stream);
    zkl_kernel<<<(n * ZD + 255) / 256, 256, 0, stream>>>(M, acc, n * ZD);

    // decoder
    recdec1_kernel<<<gemmBlocks, 128, 0, stream>>>(M, rec_w, rec_b, dec_w1, dec_b1, A, n);
    hipMemsetAsync(B, 0, NF4, stream);
    spmm_scatter_kernel<<<scatBlocks, 256, 0, stream>>>(A, src, dst, dinv, B, e);
    spmm_finish_kernel<<<finBlocks, 256, 0, stream>>>(A, dinv, B, n);
    hipMemsetAsync(C, 0, NF4, stream);
    spmm_scatter_kernel<<<scatBlocks, 256, 0, stream>>>(B, src, dst, dinv, C, e);
    spmm_finish_kernel<<<finBlocks, 256, 0, stream>>>(B, dinv, C, n);
    dec2loss_kernel<<<gemmBlocks, 128, 0, stream>>>(A, B, C, dec_w2, dec_b2,
                                                    feats, acc, n);

    finalize_kernel<<<1, 1, 0, stream>>>(acc, (float*)d_out);
}

// Round 2
// 2408.751 us; speedup vs baseline: 5.2598x; 5.2598x over previous
//
#include <hip/hip_runtime.h>
#include <math.h>

// Problem constants (fixed by the reference).
#define NN   100000
#define EE   1600000
#define F    128      // IN_FEATS == H == 128
#define ZD   32       // Z_DIM
#define NB3  384      // H * 3 thetas
#define ROWS 8        // rows per block in fused GEMM kernels
#define SCAN_B 256

// THETAS (D=2): t0=[3,-3,0.75], t1=[0,3,-1.5], t2=[0,0,0.75]
// hs = [3x-3y1+0.75y2 | 3y1-1.5y2 | 0.75y2],  y1=P(x), y2=P(y1)
// P(x) = x - dinv * A(x * dinv)  computed as CSR GATHER per dst row (no atomics).
// output scalar == vgae_loss = sum((x_rec-feats)^2) - 0.5*sum(1+mu-mu^2-exp(mu))

__device__ __forceinline__ unsigned pcg_hash(unsigned v) {
    v = v * 747796405u + 2891336453u;
    unsigned w = ((v >> ((v >> 28u) + 4u)) ^ v) * 277803737u;
    return (w >> 22u) ^ w;
}

__device__ __forceinline__ float block_reduce_sum(float v) {
    #pragma unroll
    for (int o = 32; o > 0; o >>= 1) v += __shfl_down(v, o, 64);
    __shared__ float s[8];
    int lane = threadIdx.x & 63, w = threadIdx.x >> 6;
    if (lane == 0) s[w] = v;
    __syncthreads();
    float t = 0.f;
    if (threadIdx.x == 0) {
        int nw = (blockDim.x + 63) >> 6;
        for (int i = 0; i < nw; ++i) t += s[i];
    }
    return t;
}

// ---------- degree / dinv ----------
__global__ __launch_bounds__(256) void deg_kernel(const int* __restrict__ dst,
                                                  int* __restrict__ degs, int e) {
    int i = blockIdx.x * 256 + threadIdx.x;
    if (i < e) atomicAdd(&degs[dst[i]], 1);
}

__global__ __launch_bounds__(256) void dinv_kernel(const int* __restrict__ degs,
                                                   float* __restrict__ dinv, int n) {
    int i = blockIdx.x * 256 + threadIdx.x;
    if (i < n) {
        float d = fmaxf((float)degs[i], 1.f);
        dinv[i] = 1.f / sqrtf(d);
    }
}

// ---------- two-level exclusive scan over degs -> rowstart ----------
__global__ __launch_bounds__(SCAN_B) void scan_block_kernel(const int* __restrict__ degs,
                                                            int* __restrict__ rowstart,
                                                            int* __restrict__ blocksums, int n) {
    __shared__ int sh[SCAN_B];
    int i = blockIdx.x * SCAN_B + threadIdx.x;
    int v = (i < n) ? degs[i] : 0;
    sh[threadIdx.x] = v;
    __syncthreads();
    for (int o = 1; o < SCAN_B; o <<= 1) {
        int t = (threadIdx.x >= o) ? sh[threadIdx.x - o] : 0;
        __syncthreads();
        sh[threadIdx.x] += t;
        __syncthreads();
    }
    if (i < n) rowstart[i] = sh[threadIdx.x] - v;   // exclusive
    if (threadIdx.x == SCAN_B - 1) blocksums[blockIdx.x] = sh[threadIdx.x];
}

__global__ __launch_bounds__(512) void scan_sums_kernel(int* __restrict__ blocksums, int nb) {
    __shared__ int sh[512];
    int v = (threadIdx.x < nb) ? blocksums[threadIdx.x] : 0;
    sh[threadIdx.x] = v;
    __syncthreads();
    for (int o = 1; o < 512; o <<= 1) {
        int t = (threadIdx.x >= o) ? sh[threadIdx.x - o] : 0;
        __syncthreads();
        sh[threadIdx.x] += t;
        __syncthreads();
    }
    if (threadIdx.x < nb) blocksums[threadIdx.x] = sh[threadIdx.x] - v;  // exclusive
}

__global__ __launch_bounds__(SCAN_B) void scan_add_kernel(int* __restrict__ rowstart,
                                                          int* __restrict__ cursor,
                                                          const int* __restrict__ blocksums, int n) {
    int i = blockIdx.x * SCAN_B + threadIdx.x;
    if (i < n) {
        int v = rowstart[i] + blocksums[blockIdx.x];
        rowstart[i] = v;
        cursor[i] = v;
    }
}

// ---------- CSR build: bucket-scatter src indices by dst ----------
__global__ __launch_bounds__(256) void csr_build_kernel(const int* __restrict__ src,
                                                        const int* __restrict__ dst,
                                                        int* __restrict__ cursor,
                                                        int* __restrict__ csr_src, int e) {
    int i = blockIdx.x * 256 + threadIdx.x;
    if (i < e) {
        int d = dst[i];
        int pos = atomicAdd(&cursor[d], 1);
        csr_src[pos] = src[i];
    }
}

// ---------- SpMM gather: out[r] = x[r] - dinv[r] * sum_e dinv[s]*x[s] ----------
// one wave (64 threads) per row, float2 per lane (128 floats/row)
__global__ __launch_bounds__(256) void spmm_gather_kernel(const float* __restrict__ x,
                                                          const int* __restrict__ csr_src,
                                                          const int* __restrict__ rowstart,
                                                          const int* __restrict__ degs,
                                                          const float* __restrict__ dinv,
                                                          float* __restrict__ out, int n) {
    int r = blockIdx.x * 4 + (threadIdx.x >> 6);
    if (r >= n) return;
    int lane = threadIdx.x & 63;
    int c = lane * 2;
    int start = rowstart[r];
    int deg = degs[r];
    float ax = 0.f, ay = 0.f;
    int i = 0;
    for (; i + 2 <= deg; i += 2) {
        int s0 = csr_src[start + i];
        int s1 = csr_src[start + i + 1];
        float sc0 = dinv[s0], sc1 = dinv[s1];
        float2 v0 = *reinterpret_cast<const float2*>(x + (size_t)s0 * F + c);
        float2 v1 = *reinterpret_cast<const float2*>(x + (size_t)s1 * F + c);
        ax += v0.x * sc0 + v1.x * sc1;
        ay += v0.y * sc0 + v1.y * sc1;
    }
    if (i < deg) {
        int s = csr_src[start + i];
        float sc = dinv[s];
        float2 v = *reinterpret_cast<const float2*>(x + (size_t)s * F + c);
        ax += v.x * sc;
        ay += v.y * sc;
    }
    float di = dinv[r];
    float2 xv = *reinterpret_cast<const float2*>(x + (size_t)r * F + c);
    float2 o;
    o.x = xv.x - di * ax;
    o.y = xv.y - di * ay;
    *reinterpret_cast<float2*>(out + (size_t)r * F + c) = o;
}

// ---------- enc fc1: out = relu(x @ w.T + b) ----------
__global__ __launch_bounds__(128) void fc1_relu_kernel(const float* __restrict__ x,
                                                       const float* __restrict__ w,
                                                       const float* __restrict__ b,
                                                       float* __restrict__ out, int n) {
    __shared__ float xr[ROWS][F];
    int r0 = blockIdx.x * ROWS;
    int j = threadIdx.x;
    for (int rr = 0; rr < ROWS; ++rr) {
        int r = r0 + rr;
        xr[rr][j] = (r < n) ? x[(size_t)r * F + j] : 0.f;
    }
    __syncthreads();
    float acc[ROWS];
    float bj = b[j];
    #pragma unroll
    for (int rr = 0; rr < ROWS; ++rr) acc[rr] = bj;
    const float* wrow = w + (size_t)j * F;
    for (int k = 0; k < F; ++k) {
        float wv = wrow[k];
        #pragma unroll
        for (int rr = 0; rr < ROWS; ++rr) acc[rr] += xr[rr][k] * wv;
    }
    for (int rr = 0; rr < ROWS; ++rr) {
        int r = r0 + rr;
        if (r < n) out[(size_t)r * F + j] = fmaxf(acc[rr], 0.f);
    }
}

// ---------- enc fc2 fused with rep projection -> mu ----------
__global__ __launch_bounds__(128) void enc2rep_kernel(const float* __restrict__ xA,
                                                      const float* __restrict__ y1,
                                                      const float* __restrict__ y2,
                                                      const float* __restrict__ w2,
                                                      const float* __restrict__ b2,
                                                      const float* __restrict__ repw,
                                                      const float* __restrict__ repb,
                                                      float* __restrict__ mu, int n) {
    __shared__ float hs[ROWS][NB3];
    __shared__ float pos[ROWS][F];
    int r0 = blockIdx.x * ROWS;
    int j = threadIdx.x;
    for (int rr = 0; rr < ROWS; ++rr) {
        int r = r0 + rr;
        float xv = 0.f, a = 0.f, bv = 0.f;
        if (r < n) {
            size_t o = (size_t)r * F + j;
            xv = xA[o]; a = y1[o]; bv = y2[o];
        }
        hs[rr][j]       = 3.f * xv - 3.f * a + 0.75f * bv;
        hs[rr][128 + j] = 3.f * a - 1.5f * bv;
        hs[rr][256 + j] = 0.75f * bv;
    }
    __syncthreads();
    float acc[ROWS];
    float bj = b2[j];
    #pragma unroll
    for (int rr = 0; rr < ROWS; ++rr) acc[rr] = bj;
    const float* wrow = w2 + (size_t)j * NB3;
    for (int k = 0; k < NB3; ++k) {
        float wv = wrow[k];
        #pragma unroll
        for (int rr = 0; rr < ROWS; ++rr) acc[rr] += hs[rr][k] * wv;
    }
    for (int rr = 0; rr < ROWS; ++rr) pos[rr][j] = acc[rr];
    __syncthreads();
    #pragma unroll
    for (int p = 0; p < 2; ++p) {
        int idx = j + p * 128;
        int rr = idx >> 5;
        int i  = idx & 31;
        float m = repb[i];
        const float* rw = repw + (size_t)i * F;
        for (int k = 0; k < F; ++k) m += pos[rr][k] * rw[k];
        int r = r0 + rr;
        if (r < n) mu[(size_t)r * ZD + i] = m;
    }
}

// ---------- KL accumulation + reparameterize z (in place over mu) ----------
__global__ __launch_bounds__(256) void zkl_kernel(float* __restrict__ m,
                                                  double* __restrict__ acc, int total) {
    int i = blockIdx.x * 256 + threadIdx.x;
    float v = 0.f;
    if (i < total) {
        float mu = m[i];
        v = 1.f + mu - mu * mu - expf(mu);
        unsigned h1 = pcg_hash(2u * (unsigned)i + 1u);
        unsigned h2 = pcg_hash(2u * (unsigned)i + 2u);
        float u1 = ((float)h1 + 0.5f) * 2.3283064365386963e-10f;  // (0,1)
        float u2 = ((float)h2 + 0.5f) * 2.3283064365386963e-10f;
        float rad = sqrtf(-2.f * logf(u1));
        float eps = rad * cosf(6.283185307179586f * u2);
        m[i] = mu + eps * expf(0.5f * mu);
    }
    float bs = block_reduce_sum(v);
    if (threadIdx.x == 0) atomicAdd(&acc[1], (double)bs);
}

// ---------- rec linear fused with dec fc1 relu ----------
__global__ __launch_bounds__(128) void recdec1_kernel(const float* __restrict__ z,
                                                      const float* __restrict__ recw,
                                                      const float* __restrict__ recb,
                                                      const float* __restrict__ w1,
                                                      const float* __restrict__ b1,
                                                      float* __restrict__ out, int n) {
    __shared__ float zs[ROWS][ZD];
    __shared__ float zz[ROWS][F];
    int r0 = blockIdx.x * ROWS;
    int j = threadIdx.x;
    #pragma unroll
    for (int p = 0; p < 2; ++p) {
        int idx = j + p * 128;
        int rr = idx >> 5, i = idx & 31;
        int r = r0 + rr;
        zs[rr][i] = (r < n) ? z[(size_t)r * ZD + i] : 0.f;
    }
    __syncthreads();
    const float* rw = recw + (size_t)j * ZD;
    float rbj = recb[j];
    for (int rr = 0; rr < ROWS; ++rr) {
        float a = rbj;
        #pragma unroll
        for (int i = 0; i < ZD; ++i) a += zs[rr][i] * rw[i];
        zz[rr][j] = a;
    }
    __syncthreads();
    float acc[ROWS];
    float bj = b1[j];
    #pragma unroll
    for (int rr = 0; rr < ROWS; ++rr) acc[rr] = bj;
    const float* wrow = w1 + (size_t)j * F;
    for (int k = 0; k < F; ++k) {
        float wv = wrow[k];
        #pragma unroll
        for (int rr = 0; rr < ROWS; ++rr) acc[rr] += zz[rr][k] * wv;
    }
    for (int rr = 0; rr < ROWS; ++rr) {
        int r = r0 + rr;
        if (r < n) out[(size_t)r * F + j] = fmaxf(acc[rr], 0.f);
    }
}

// ---------- dec fc2 fused with reconstruction loss ----------
__global__ __launch_bounds__(128) void dec2loss_kernel(const float* __restrict__ xA,
                                                       const float* __restrict__ y1,
                                                       const float* __restrict__ y2,
                                                       const float* __restrict__ w2,
                                                       const float* __restrict__ b2,
                                                       const float* __restrict__ feats,
                                                       double* __restrict__ acc, int n) {
    __shared__ float hs[ROWS][NB3];
    int r0 = blockIdx.x * ROWS;
    int j = threadIdx.x;
    for (int rr = 0; rr < ROWS; ++rr) {
        int r = r0 + rr;
        float xv = 0.f, a = 0.f, bv = 0.f;
        if (r < n) {
            size_t o = (size_t)r * F + j;
            xv = xA[o]; a = y1[o]; bv = y2[o];
        }
        hs[rr][j]       = 3.f * xv - 3.f * a + 0.75f * bv;
        hs[rr][128 + j] = 3.f * a - 1.5f * bv;
        hs[rr][256 + j] = 0.75f * bv;
    }
    __syncthreads();
    float accv[ROWS];
    float bj = b2[j];
    #pragma unroll
    for (int rr = 0; rr < ROWS; ++rr) accv[rr] = bj;
    const float* wrow = w2 + (size_t)j * NB3;
    for (int k = 0; k < NB3; ++k) {
        float wv = wrow[k];
        #pragma unroll
        for (int rr = 0; rr < ROWS; ++rr) accv[rr] += hs[rr][k] * wv;
    }
    float local = 0.f;
    for (int rr = 0; rr < ROWS; ++rr) {
        int r = r0 + rr;
        if (r < n) {
            float d = accv[rr] - feats[(size_t)r * F + j];
            local += d * d;
        }
    }
    float bs = block_reduce_sum(local);
    if (threadIdx.x == 0) atomicAdd(&acc[0], (double)bs);
}

__global__ void finalize_kernel(const double* __restrict__ acc, float* __restrict__ out) {
    out[0] = (float)(acc[0] - 0.5 * acc[1]);
}

extern "C" void kernel_launch(void* const* d_in, const int* in_sizes, int n_in,
                              void* d_out, int out_size, void* d_ws, size_t ws_size,
                              hipStream_t stream) {
    const float* feats  = (const float*)d_in[0];
    const int*   src    = (const int*)d_in[1];
    const int*   dst    = (const int*)d_in[2];
    const float* enc_w1 = (const float*)d_in[3];
    const float* enc_b1 = (const float*)d_in[4];
    const float* enc_w2 = (const float*)d_in[5];
    const float* enc_b2 = (const float*)d_in[6];
    const float* dec_w1 = (const float*)d_in[7];
    const float* dec_b1 = (const float*)d_in[8];
    const float* dec_w2 = (const float*)d_in[9];
    const float* dec_b2 = (const float*)d_in[10];
    const float* rep_w  = (const float*)d_in[11];
    const float* rep_b  = (const float*)d_in[12];
    const float* rec_w  = (const float*)d_in[13];
    const float* rec_b  = (const float*)d_in[14];
    // d_in[15] = disc_w: unused (dgi branch cancels analytically)

    const int n = NN, e = EE;
    char* ws = (char*)d_ws;
    size_t off = 0;
    auto alloc = [&](size_t bytes) -> void* {
        void* p = ws + off;
        off += (bytes + 255) & ~(size_t)255;
        return p;
    };
    const size_t NF4 = (size_t)n * F * sizeof(float);   // 51.2 MB
    const int nScanBlocks = (n + SCAN_B - 1) / SCAN_B;  // 391
    int*    degs    = (int*)alloc((size_t)n * sizeof(int));
    float*  dinv    = (float*)alloc((size_t)n * sizeof(float));
    int*    rowst   = (int*)alloc((size_t)n * sizeof(int));
    int*    cursor  = (int*)alloc((size_t)n * sizeof(int));
    int*    bsums   = (int*)alloc((size_t)nScanBlocks * sizeof(int));
    int*    csr_src = (int*)alloc((size_t)e * sizeof(int));
    float*  A    = (float*)alloc(NF4);
    float*  B    = (float*)alloc(NF4);
    float*  C    = (float*)alloc(NF4);
    float*  M    = (float*)alloc((size_t)n * ZD * sizeof(float));  // mu -> z
    double* acc  = (double*)alloc(2 * sizeof(double));

    const int gemmBlocks = (n + ROWS - 1) / ROWS;   // 12500
    const int gathBlocks = (n + 3) / 4;             // 25000

    // degrees + dinv + CSR
    hipMemsetAsync(degs, 0, (size_t)n * sizeof(int), stream);
    deg_kernel<<<(e + 255) / 256, 256, 0, stream>>>(dst, degs, e);
    dinv_kernel<<<(n + 255) / 256, 256, 0, stream>>>(degs, dinv, n);
    scan_block_kernel<<<nScanBlocks, SCAN_B, 0, stream>>>(degs, rowst, bsums, n);
    scan_sums_kernel<<<1, 512, 0, stream>>>(bsums, nScanBlocks);
    scan_add_kernel<<<nScanBlocks, SCAN_B, 0, stream>>>(rowst, cursor, bsums, n);
    csr_build_kernel<<<(e + 255) / 256, 256, 0, stream>>>(src, dst, cursor, csr_src, e);

    // encoder
    fc1_relu_kernel<<<gemmBlocks, 128, 0, stream>>>(feats, enc_w1, enc_b1, A, n);
    spmm_gather_kernel<<<gathBlocks, 256, 0, stream>>>(A, csr_src, rowst, degs, dinv, B, n);
    spmm_gather_kernel<<<gathBlocks, 256, 0, stream>>>(B, csr_src, rowst, degs, dinv, C, n);
    enc2rep_kernel<<<gemmBlocks, 128, 0, stream>>>(A, B, C, enc_w2, enc_b2,
                                                   rep_w, rep_b, M, n);

    // kl + reparameterize (z over mu, in place)
    hipMemsetAsync(acc, 0, 2 * sizeof(double), stream);
    zkl_kernel<<<(n * ZD + 255) / 256, 256, 0, stream>>>(M, acc, n * ZD);

    // decoder
    recdec1_kernel<<<gemmBlocks, 128, 0, stream>>>(M, rec_w, rec_b, dec_w1, dec_b1, A, n);
    spmm_gather_kernel<<<gathBlocks, 256, 0, stream>>>(A, csr_src, rowst, degs, dinv, B, n);
    spmm_gather_kernel<<<gathBlocks, 256, 0, stream>>>(B, csr_src, rowst, degs, dinv, C, n);
    dec2loss_kernel<<<gemmBlocks, 128, 0, stream>>>(A, B, C, dec_w2, dec_b2,
                                                    feats, acc, n);

    finalize_kernel<<<1, 1, 0, stream>>>(acc, (float*)d_out);
}

// Round 3
// 837.592 us; speedup vs baseline: 15.1262x; 2.8758x over previous
//
#include <hip/hip_runtime.h>
#include <math.h>

// Problem constants (fixed by the reference).
#define NN   100000
#define EE   1600000
#define F    128      // IN_FEATS == H == 128
#define ZD   32       // Z_DIM
#define SCAN_B 256

// Algebra:
//  hs = [3x-3y1+0.75y2 | 3y1-1.5y2 | 0.75y2], y1=P(x), y2=P(y1)
//  hs @ W^T = x@(3W0)^T + y1@(3W1-3W0)^T + y2@(0.75W0-1.5W1+0.75W2)^T
//  mu  = hs @ (rep_w@enc_w2)^T + (rep_b + rep_w@enc_b2)      (positive never formed)
//  x1d = relu(z @ (dec_w1@rec_w)^T + (dec_b1 + dec_w1@rec_b))
//  out = vgae_loss = sum((x_rec-feats)^2) - 0.5*sum(1+mu-mu^2-exp(mu))

typedef float f32x4 __attribute__((ext_vector_type(4)));
typedef int   i32x4 __attribute__((ext_vector_type(4)));
typedef __bf16 bf16x8 __attribute__((ext_vector_type(8)));

__device__ __forceinline__ f32x4 mfma16(i32x4 a, i32x4 b, f32x4 c) {
    return __builtin_amdgcn_mfma_f32_16x16x32_bf16(
        __builtin_bit_cast(bf16x8, a), __builtin_bit_cast(bf16x8, b), c, 0, 0, 0);
}

__device__ __forceinline__ unsigned f2bf(float f) {   // RNE float->bf16 (as u16)
    unsigned u = __float_as_uint(f);
    return (u + 0x7fffu + ((u >> 16) & 1u)) >> 16;
}
__device__ __forceinline__ float bf2f(unsigned h) { return __uint_as_float(h << 16); }

__device__ __forceinline__ unsigned pcg_hash(unsigned v) {
    v = v * 747796405u + 2891336453u;
    unsigned w = ((v >> ((v >> 28u) + 4u)) ^ v) * 277803737u;
    return (w >> 22u) ^ w;
}

__device__ __forceinline__ float block_reduce_sum(float v) {
    #pragma unroll
    for (int o = 32; o > 0; o >>= 1) v += __shfl_down(v, o, 64);
    __shared__ float s[8];
    int lane = threadIdx.x & 63, w = threadIdx.x >> 6;
    if (lane == 0) s[w] = v;
    __syncthreads();
    float t = 0.f;
    if (threadIdx.x == 0) {
        int nw = (blockDim.x + 63) >> 6;
        for (int i = 0; i < nw; ++i) t += s[i];
    }
    return t;
}

// ---------- degree / dinv ----------
__global__ __launch_bounds__(256) void deg_kernel(const int* __restrict__ dst,
                                                  int* __restrict__ degs, int e) {
    int i = blockIdx.x * 256 + threadIdx.x;
    if (i < e) atomicAdd(&degs[dst[i]], 1);
}

__global__ __launch_bounds__(256) void dinv_kernel(const int* __restrict__ degs,
                                                   float* __restrict__ dinv, int n) {
    int i = blockIdx.x * 256 + threadIdx.x;
    if (i < n) dinv[i] = 1.f / sqrtf(fmaxf((float)degs[i], 1.f));
}

// ---------- two-level exclusive scan -> rowstart ----------
__global__ __launch_bounds__(SCAN_B) void scan_block_kernel(const int* __restrict__ degs,
                                                            int* __restrict__ rowstart,
                                                            int* __restrict__ blocksums, int n) {
    __shared__ int sh[SCAN_B];
    int i = blockIdx.x * SCAN_B + threadIdx.x;
    int v = (i < n) ? degs[i] : 0;
    sh[threadIdx.x] = v;
    __syncthreads();
    for (int o = 1; o < SCAN_B; o <<= 1) {
        int t = (threadIdx.x >= o) ? sh[threadIdx.x - o] : 0;
        __syncthreads();
        sh[threadIdx.x] += t;
        __syncthreads();
    }
    if (i < n) rowstart[i] = sh[threadIdx.x] - v;
    if (threadIdx.x == SCAN_B - 1) blocksums[blockIdx.x] = sh[threadIdx.x];
}

__global__ __launch_bounds__(512) void scan_sums_kernel(int* __restrict__ blocksums, int nb) {
    __shared__ int sh[512];
    int v = (threadIdx.x < nb) ? blocksums[threadIdx.x] : 0;
    sh[threadIdx.x] = v;
    __syncthreads();
    for (int o = 1; o < 512; o <<= 1) {
        int t = (threadIdx.x >= o) ? sh[threadIdx.x - o] : 0;
        __syncthreads();
        sh[threadIdx.x] += t;
        __syncthreads();
    }
    if (threadIdx.x < nb) blocksums[threadIdx.x] = sh[threadIdx.x] - v;
}

__global__ __launch_bounds__(SCAN_B) void scan_add_kernel(int* __restrict__ rowstart,
                                                          int* __restrict__ cursor,
                                                          const int* __restrict__ blocksums, int n) {
    int i = blockIdx.x * SCAN_B + threadIdx.x;
    if (i < n) {
        int v = rowstart[i] + blocksums[blockIdx.x];
        rowstart[i] = v;
        cursor[i] = v;
    }
}

__global__ __launch_bounds__(256) void csr_build_kernel(const int* __restrict__ src,
                                                        const int* __restrict__ dst,
                                                        int* __restrict__ cursor,
                                                        int* __restrict__ csr_src, int e) {
    int i = blockIdx.x * 256 + threadIdx.x;
    if (i < e) {
        int pos = atomicAdd(&cursor[dst[i]], 1);
        csr_src[pos] = src[i];
    }
}

// ---------- weight prep ----------
__global__ __launch_bounds__(256) void prep_wmu_kernel(const float* __restrict__ repw,
                                                       const float* __restrict__ w2,
                                                       unsigned short* __restrict__ Wa,
                                                       unsigned short* __restrict__ Wb,
                                                       unsigned short* __restrict__ Wc) {
    int idx = blockIdx.x * 256 + threadIdx.x;       // 32*128
    if (idx >= 32 * 128) return;
    int i = idx >> 7, k = idx & 127;
    float m0 = 0.f, m1 = 0.f, m2 = 0.f;
    for (int h = 0; h < 128; ++h) {
        float r = repw[i * 128 + h];
        const float* wr = w2 + (size_t)h * 384 + k;
        m0 += r * wr[0];
        m1 += r * wr[128];
        m2 += r * wr[256];
    }
    Wa[idx] = (unsigned short)f2bf(3.f * m0);
    Wb[idx] = (unsigned short)f2bf(3.f * (m1 - m0));
    Wc[idx] = (unsigned short)f2bf(0.75f * m0 - 1.5f * m1 + 0.75f * m2);
}

__global__ void prep_bmu_kernel(const float* __restrict__ repw, const float* __restrict__ b2,
                                const float* __restrict__ repb, float* __restrict__ bmu) {
    int i = threadIdx.x;
    if (i < 32) {
        float s = repb[i];
        for (int h = 0; h < 128; ++h) s += repw[i * 128 + h] * b2[h];
        bmu[i] = s;
    }
}

__global__ __launch_bounds__(256) void prep_wd2_kernel(const float* __restrict__ w2d,
                                                       unsigned short* __restrict__ Wa,
                                                       unsigned short* __restrict__ Wb,
                                                       unsigned short* __restrict__ Wc) {
    int idx = blockIdx.x * 256 + threadIdx.x;       // 128*128
    if (idx >= 128 * 128) return;
    int j = idx >> 7, k = idx & 127;
    const float* wr = w2d + (size_t)j * 384 + k;
    float w0 = wr[0], w1 = wr[128], w2v = wr[256];
    Wa[idx] = (unsigned short)f2bf(3.f * w0);
    Wb[idx] = (unsigned short)f2bf(3.f * (w1 - w0));
    Wc[idx] = (unsigned short)f2bf(0.75f * w0 - 1.5f * w1 + 0.75f * w2v);
}

__global__ __launch_bounds__(256) void prep_wrd_kernel(const float* __restrict__ w1d,
                                                       const float* __restrict__ recw,
                                                       const float* __restrict__ recb,
                                                       const float* __restrict__ b1d,
                                                       unsigned short* __restrict__ Wrd,
                                                       float* __restrict__ brd) {
    int idx = blockIdx.x * 256 + threadIdx.x;       // 128*32
    if (idx < 128 * 32) {
        int j = idx >> 5, i = idx & 31;
        float s = 0.f;
        for (int h = 0; h < 128; ++h) s += w1d[j * 128 + h] * recw[h * 32 + i];
        Wrd[idx] = (unsigned short)f2bf(s);
    }
    if (idx < 128) {
        float s = b1d[idx];
        for (int h = 0; h < 128; ++h) s += w1d[idx * 128 + h] * recb[h];
        brd[idx] = s;
    }
}

__global__ __launch_bounds__(256) void cvt_w_kernel(const float* __restrict__ w,
                                                    unsigned short* __restrict__ wbf, int total) {
    int i = blockIdx.x * 256 + threadIdx.x;
    if (i < total) wbf[i] = (unsigned short)f2bf(w[i]);
}

// ---------- fc1: A = relu(feats @ enc_w1^T + b1), bf16 out ----------
__global__ __launch_bounds__(256) void fc1_mfma_kernel(const float* __restrict__ x,
                                                       const unsigned short* __restrict__ wbf,
                                                       const float* __restrict__ b,
                                                       unsigned short* __restrict__ out, int n) {
    int wv = threadIdx.x >> 6, lane = threadIdx.x & 63;
    int l16 = lane & 15, lhi = lane >> 4;
    int rowbase = blockIdx.x * 64 + wv * 16;
    int arow = rowbase + l16;
    f32x4 acc[8];
    #pragma unroll
    for (int jt = 0; jt < 8; ++jt) {
        float bj = b[jt * 16 + l16];
        acc[jt] = (f32x4){bj, bj, bj, bj};
    }
    #pragma unroll
    for (int kk = 0; kk < 4; ++kk) {
        int kbase = kk * 32 + lhi * 8;
        i32x4 afrag = {0, 0, 0, 0};
        if (arow < n) {
            const float* ap = x + (size_t)arow * F + kbase;
            f32x4 f0 = *reinterpret_cast<const f32x4*>(ap);
            f32x4 f1 = *reinterpret_cast<const f32x4*>(ap + 4);
            afrag.x = (int)(f2bf(f0.x) | (f2bf(f0.y) << 16));
            afrag.y = (int)(f2bf(f0.z) | (f2bf(f0.w) << 16));
            afrag.z = (int)(f2bf(f1.x) | (f2bf(f1.y) << 16));
            afrag.w = (int)(f2bf(f1.z) | (f2bf(f1.w) << 16));
        }
        #pragma unroll
        for (int jt = 0; jt < 8; ++jt) {
            i32x4 bfrag = *reinterpret_cast<const i32x4*>(wbf + (size_t)(jt * 16 + l16) * F + kbase);
            acc[jt] = mfma16(afrag, bfrag, acc[jt]);
        }
    }
    #pragma unroll
    for (int jt = 0; jt < 8; ++jt)
        #pragma unroll
        for (int r = 0; r < 4; ++r) {
            int row = rowbase + lhi * 4 + r;
            if (row < n)
                out[(size_t)row * F + jt * 16 + l16] =
                    (unsigned short)f2bf(fmaxf(acc[jt][r], 0.f));
        }
}

// ---------- SpMM gather (bf16): out[r] = x[r] - dinv[r]*sum dinv[s]*x[s] ----------
__global__ __launch_bounds__(256) void spmm_gather_bf_kernel(const unsigned short* __restrict__ x,
                                                             const int* __restrict__ csr_src,
                                                             const int* __restrict__ rowstart,
                                                             const int* __restrict__ degs,
                                                             const float* __restrict__ dinv,
                                                             unsigned short* __restrict__ out, int n) {
    int r = blockIdx.x * 4 + (threadIdx.x >> 6);
    if (r >= n) return;
    int lane = threadIdx.x & 63;
    int c = lane * 2;
    int start = rowstart[r], deg = degs[r];
    float ax = 0.f, ay = 0.f;
    int i = 0;
    for (; i + 2 <= deg; i += 2) {
        int s0 = csr_src[start + i], s1 = csr_src[start + i + 1];
        float sc0 = dinv[s0], sc1 = dinv[s1];
        unsigned v0 = *reinterpret_cast<const unsigned*>(x + (size_t)s0 * F + c);
        unsigned v1 = *reinterpret_cast<const unsigned*>(x + (size_t)s1 * F + c);
        ax += bf2f(v0 & 0xffffu) * sc0 + bf2f(v1 & 0xffffu) * sc1;
        ay += bf2f(v0 >> 16) * sc0 + bf2f(v1 >> 16) * sc1;
    }
    if (i < deg) {
        int s = csr_src[start + i];
        float sc = dinv[s];
        unsigned v = *reinterpret_cast<const unsigned*>(x + (size_t)s * F + c);
        ax += bf2f(v & 0xffffu) * sc;
        ay += bf2f(v >> 16) * sc;
    }
    float di = dinv[r];
    unsigned xv = *reinterpret_cast<const unsigned*>(x + (size_t)r * F + c);
    float ox = bf2f(xv & 0xffffu) - di * ax;
    float oy = bf2f(xv >> 16) - di * ay;
    *reinterpret_cast<unsigned*>(out + (size_t)r * F + c) = f2bf(ox) | (f2bf(oy) << 16);
}

// ---------- mu GEMM (K=384 distributed over A,B,C) fused with KL + reparam z ----------
__global__ __launch_bounds__(256) void mu_mfma_kernel(const unsigned short* __restrict__ A,
                                                      const unsigned short* __restrict__ B,
                                                      const unsigned short* __restrict__ C,
                                                      const unsigned short* __restrict__ Wa,
                                                      const unsigned short* __restrict__ Wb,
                                                      const unsigned short* __restrict__ Wc,
                                                      const float* __restrict__ bmu,
                                                      unsigned short* __restrict__ Z,
                                                      double* __restrict__ accd, int n) {
    int wv = threadIdx.x >> 6, lane = threadIdx.x & 63;
    int l16 = lane & 15, lhi = lane >> 4;
    int rowbase = blockIdx.x * 64 + wv * 16;
    int arow = rowbase + l16;
    f32x4 acc[2];
    #pragma unroll
    for (int jt = 0; jt < 2; ++jt) {
        float bj = bmu[jt * 16 + l16];
        acc[jt] = (f32x4){bj, bj, bj, bj};
    }
    const unsigned short* mats[3] = {A, B, C};
    const unsigned short* ws[3]   = {Wa, Wb, Wc};
    #pragma unroll
    for (int s = 0; s < 3; ++s) {
        #pragma unroll
        for (int kk = 0; kk < 4; ++kk) {
            int kbase = kk * 32 + lhi * 8;
            i32x4 afrag = {0, 0, 0, 0};
            if (arow < n)
                afrag = *reinterpret_cast<const i32x4*>(mats[s] + (size_t)arow * F + kbase);
            #pragma unroll
            for (int jt = 0; jt < 2; ++jt) {
                i32x4 bfrag = *reinterpret_cast<const i32x4*>(ws[s] + (size_t)(jt * 16 + l16) * F + kbase);
                acc[jt] = mfma16(afrag, bfrag, acc[jt]);
            }
        }
    }
    float kl = 0.f;
    #pragma unroll
    for (int jt = 0; jt < 2; ++jt)
        #pragma unroll
        for (int r = 0; r < 4; ++r) {
            int row = rowbase + lhi * 4 + r;
            int j = jt * 16 + l16;
            if (row < n) {
                float m = acc[jt][r];
                kl += 1.f + m - m * m - expf(m);
                unsigned idx = (unsigned)(row * ZD + j);
                unsigned h1 = pcg_hash(2u * idx + 1u);
                unsigned h2 = pcg_hash(2u * idx + 2u);
                float u1 = ((float)h1 + 0.5f) * 2.3283064365386963e-10f;
                float u2 = ((float)h2 + 0.5f) * 2.3283064365386963e-10f;
                float eps = sqrtf(-2.f * logf(u1)) * cosf(6.283185307179586f * u2);
                float z = m + eps * expf(0.5f * m);
                Z[(size_t)row * ZD + j] = (unsigned short)f2bf(z);
            }
        }
    float bs = block_reduce_sum(kl);
    if (threadIdx.x == 0) atomicAdd(&accd[1], (double)bs);
}

// ---------- recdec1: A = relu(Z @ Wrd^T + brd), K=32 ----------
__global__ __launch_bounds__(256) void recdec1_mfma_kernel(const unsigned short* __restrict__ Z,
                                                           const unsigned short* __restrict__ Wrd,
                                                           const float* __restrict__ brd,
                                                           unsigned short* __restrict__ out, int n) {
    int wv = threadIdx.x >> 6, lane = threadIdx.x & 63;
    int l16 = lane & 15, lhi = lane >> 4;
    int rowbase = blockIdx.x * 64 + wv * 16;
    int arow = rowbase + l16;
    int kbase = lhi * 8;
    i32x4 afrag = {0, 0, 0, 0};
    if (arow < n)
        afrag = *reinterpret_cast<const i32x4*>(Z + (size_t)arow * ZD + kbase);
    #pragma unroll
    for (int jt = 0; jt < 8; ++jt) {
        float bj = brd[jt * 16 + l16];
        f32x4 acc = (f32x4){bj, bj, bj, bj};
        i32x4 bfrag = *reinterpret_cast<const i32x4*>(Wrd + (size_t)(jt * 16 + l16) * ZD + kbase);
        acc = mfma16(afrag, bfrag, acc);
        #pragma unroll
        for (int r = 0; r < 4; ++r) {
            int row = rowbase + lhi * 4 + r;
            if (row < n)
                out[(size_t)row * F + jt * 16 + l16] =
                    (unsigned short)f2bf(fmaxf(acc[r], 0.f));
        }
    }
}

// ---------- dec2 GEMM (K=384 distributed) fused with reconstruction loss ----------
__global__ __launch_bounds__(256) void dec2loss_mfma_kernel(const unsigned short* __restrict__ A,
                                                            const unsigned short* __restrict__ B,
                                                            const unsigned short* __restrict__ C,
                                                            const unsigned short* __restrict__ Wa,
                                                            const unsigned short* __restrict__ Wb,
                                                            const unsigned short* __restrict__ Wc,
                                                            const float* __restrict__ b2,
                                                            const float* __restrict__ feats,
                                                            double* __restrict__ accd, int n) {
    int wv = threadIdx.x >> 6, lane = threadIdx.x & 63;
    int l16 = lane & 15, lhi = lane >> 4;
    int rowbase = blockIdx.x * 64 + wv * 16;
    int arow = rowbase + l16;
    f32x4 acc[8];
    #pragma unroll
    for (int jt = 0; jt < 8; ++jt) {
        float bj = b2[jt * 16 + l16];
        acc[jt] = (f32x4){bj, bj, bj, bj};
    }
    const unsigned short* mats[3] = {A, B, C};
    const unsigned short* ws[3]   = {Wa, Wb, Wc};
    #pragma unroll
    for (int s = 0; s < 3; ++s) {
        #pragma unroll
        for (int kk = 0; kk < 4; ++kk) {
            int kbase = kk * 32 + lhi * 8;
            i32x4 afrag = {0, 0, 0, 0};
            if (arow < n)
                afrag = *reinterpret_cast<const i32x4*>(mats[s] + (size_t)arow * F + kbase);
            #pragma unroll
            for (int jt = 0; jt < 8; ++jt) {
                i32x4 bfrag = *reinterpret_cast<const i32x4*>(ws[s] + (size_t)(jt * 16 + l16) * F + kbase);
                acc[jt] = mfma16(afrag, bfrag, acc[jt]);
            }
        }
    }
    float local = 0.f;
    #pragma unroll
    for (int jt = 0; jt < 8; ++jt)
        #pragma unroll
        for (int r = 0; r < 4; ++r) {
            int row = rowbase + lhi * 4 + r;
            if (row < n) {
                float d = acc[jt][r] - feats[(size_t)row * F + jt * 16 + l16];
                local += d * d;
            }
        }
    float bs = block_reduce_sum(local);
    if (threadIdx.x == 0) atomicAdd(&accd[0], (double)bs);
}

__global__ void finalize_kernel(const double* __restrict__ acc, float* __restrict__ out) {
    out[0] = (float)(acc[0] - 0.5 * acc[1]);
}

extern "C" void kernel_launch(void* const* d_in, const int* in_sizes, int n_in,
                              void* d_out, int out_size, void* d_ws, size_t ws_size,
                              hipStream_t stream) {
    const float* feats  = (const float*)d_in[0];
    const int*   src    = (const int*)d_in[1];
    const int*   dst    = (const int*)d_in[2];
    const float* enc_w1 = (const float*)d_in[3];
    const float* enc_b1 = (const float*)d_in[4];
    const float* enc_w2 = (const float*)d_in[5];
    const float* enc_b2 = (const float*)d_in[6];
    const float* dec_w1 = (const float*)d_in[7];
    const float* dec_b1 = (const float*)d_in[8];
    const float* dec_w2 = (const float*)d_in[9];
    const float* dec_b2 = (const float*)d_in[10];
    const float* rep_w  = (const float*)d_in[11];
    const float* rep_b  = (const float*)d_in[12];
    const float* rec_w  = (const float*)d_in[13];
    const float* rec_b  = (const float*)d_in[14];
    // d_in[15] = disc_w: unused (dgi branch cancels analytically)

    const int n = NN, e = EE;
    char* ws = (char*)d_ws;
    size_t off = 0;
    auto alloc = [&](size_t bytes) -> void* {
        void* p = ws + off;
        off += (bytes + 255) & ~(size_t)255;
        return p;
    };
    const size_t NFB = (size_t)n * F * sizeof(unsigned short);   // 25.6 MB
    const int nScanBlocks = (n + SCAN_B - 1) / SCAN_B;
    int*    degs    = (int*)alloc((size_t)n * sizeof(int));
    float*  dinv    = (float*)alloc((size_t)n * sizeof(float));
    int*    rowst   = (int*)alloc((size_t)n * sizeof(int));
    int*    cursor  = (int*)alloc((size_t)n * sizeof(int));
    int*    bsums   = (int*)alloc((size_t)nScanBlocks * sizeof(int));
    int*    csr_src = (int*)alloc((size_t)e * sizeof(int));
    unsigned short* Abf = (unsigned short*)alloc(NFB);
    unsigned short* Bbf = (unsigned short*)alloc(NFB);
    unsigned short* Cbf = (unsigned short*)alloc(NFB);
    unsigned short* Zbf = (unsigned short*)alloc((size_t)n * ZD * sizeof(unsigned short));
    unsigned short* w1bf   = (unsigned short*)alloc(128 * 128 * sizeof(unsigned short));
    unsigned short* wmu_a  = (unsigned short*)alloc(32 * 128 * sizeof(unsigned short));
    unsigned short* wmu_b  = (unsigned short*)alloc(32 * 128 * sizeof(unsigned short));
    unsigned short* wmu_c  = (unsigned short*)alloc(32 * 128 * sizeof(unsigned short));
    unsigned short* wd2_a  = (unsigned short*)alloc(128 * 128 * sizeof(unsigned short));
    unsigned short* wd2_b  = (unsigned short*)alloc(128 * 128 * sizeof(unsigned short));
    unsigned short* wd2_c  = (unsigned short*)alloc(128 * 128 * sizeof(unsigned short));
    unsigned short* wrd    = (unsigned short*)alloc(128 * 32 * sizeof(unsigned short));
    float* bmu = (float*)alloc(32 * sizeof(float));
    float* brd = (float*)alloc(128 * sizeof(float));
    double* acc = (double*)alloc(2 * sizeof(double));

    const int gemm64   = (n + 63) / 64;     // 1563
    const int gathBlks = (n + 3) / 4;       // 25000

    // graph structure
    hipMemsetAsync(degs, 0, (size_t)n * sizeof(int), stream);
    hipMemsetAsync(acc, 0, 2 * sizeof(double), stream);
    deg_kernel<<<(e + 255) / 256, 256, 0, stream>>>(dst, degs, e);
    dinv_kernel<<<(n + 255) / 256, 256, 0, stream>>>(degs, dinv, n);
    scan_block_kernel<<<nScanBlocks, SCAN_B, 0, stream>>>(degs, rowst, bsums, n);
    scan_sums_kernel<<<1, 512, 0, stream>>>(bsums, nScanBlocks);
    scan_add_kernel<<<nScanBlocks, SCAN_B, 0, stream>>>(rowst, cursor, bsums, n);
    csr_build_kernel<<<(e + 255) / 256, 256, 0, stream>>>(src, dst, cursor, csr_src, e);

    // weight prep
    prep_wmu_kernel<<<16, 256, 0, stream>>>(rep_w, enc_w2, wmu_a, wmu_b, wmu_c);
    prep_bmu_kernel<<<1, 32, 0, stream>>>(rep_w, enc_b2, rep_b, bmu);
    prep_wd2_kernel<<<64, 256, 0, stream>>>(dec_w2, wd2_a, wd2_b, wd2_c);
    prep_wrd_kernel<<<16, 256, 0, stream>>>(dec_w1, rec_w, rec_b, dec_b1, wrd, brd);
    cvt_w_kernel<<<64, 256, 0, stream>>>(enc_w1, w1bf, 128 * 128);

    // encoder
    fc1_mfma_kernel<<<gemm64, 256, 0, stream>>>(feats, w1bf, enc_b1, Abf, n);
    spmm_gather_bf_kernel<<<gathBlks, 256, 0, stream>>>(Abf, csr_src, rowst, degs, dinv, Bbf, n);
    spmm_gather_bf_kernel<<<gathBlks, 256, 0, stream>>>(Bbf, csr_src, rowst, degs, dinv, Cbf, n);
    mu_mfma_kernel<<<gemm64, 256, 0, stream>>>(Abf, Bbf, Cbf, wmu_a, wmu_b, wmu_c,
                                               bmu, Zbf, acc, n);

    // decoder
    recdec1_mfma_kernel<<<gemm64, 256, 0, stream>>>(Zbf, wrd, brd, Abf, n);
    spmm_gather_bf_kernel<<<gathBlks, 256, 0, stream>>>(Abf, csr_src, rowst, degs, dinv, Bbf, n);
    spmm_gather_bf_kernel<<<gathBlks, 256, 0, stream>>>(Bbf, csr_src, rowst, degs, dinv, Cbf, n);
    dec2loss_mfma_kernel<<<gemm64, 256, 0, stream>>>(Abf, Bbf, Cbf, wd2_a, wd2_b, wd2_c,
                                                     dec_b2, feats, acc, n);

    finalize_kernel<<<1, 1, 0, stream>>>(acc, (float*)d_out);
}

// Round 4
// 760.222 us; speedup vs baseline: 16.6656x; 1.1018x over previous
//
#include <hip/hip_runtime.h>
#include <math.h>

// Problem constants (fixed by the reference).
#define NN   100000
#define EE   1600000
#define F    128      // IN_FEATS == H == 128
#define ZD   32       // Z_DIM
#define SCAN_B 256

// Algebra:
//  hs = [3x-3y1+0.75y2 | 3y1-1.5y2 | 0.75y2], y1=P(x), y2=P(y1)
//  hs @ W^T = x@(3W0)^T + y1@(3W1-3W0)^T + y2@(0.75W0-1.5W1+0.75W2)^T
//  P commutes with right-multiplication: (P X) M = P (X M).
//  Encoder (mu weights are 32x128):
//    G0=A Wa^T, G1=A Wb^T, G2=A Wc^T   (one n x 96 GEMM)
//    [H1|H2] = P([G1|G2])  (64-wide gather) ;  H3 = P(H2) (32-wide gather)
//    mu = G0 + H1 + H3 + bmu            (fused with KL + reparam z)
//  Decoder keeps the 128-wide form (weights are square).
//  out = vgae_loss = sum((x_rec-feats)^2) - 0.5*sum(1+mu-mu^2-exp(mu))

typedef float f32x4 __attribute__((ext_vector_type(4)));
typedef int   i32x4 __attribute__((ext_vector_type(4)));
typedef __bf16 bf16x8 __attribute__((ext_vector_type(8)));

__device__ __forceinline__ f32x4 mfma16(i32x4 a, i32x4 b, f32x4 c) {
    return __builtin_amdgcn_mfma_f32_16x16x32_bf16(
        __builtin_bit_cast(bf16x8, a), __builtin_bit_cast(bf16x8, b), c, 0, 0, 0);
}

__device__ __forceinline__ unsigned f2bf(float f) {   // RNE float->bf16 (as u16)
    unsigned u = __float_as_uint(f);
    return (u + 0x7fffu + ((u >> 16) & 1u)) >> 16;
}
__device__ __forceinline__ float bf2f(unsigned h) { return __uint_as_float(h << 16); }

__device__ __forceinline__ unsigned pcg_hash(unsigned v) {
    v = v * 747796405u + 2891336453u;
    unsigned w = ((v >> ((v >> 28u) + 4u)) ^ v) * 277803737u;
    return (w >> 22u) ^ w;
}

__device__ __forceinline__ float block_reduce_sum(float v) {
    #pragma unroll
    for (int o = 32; o > 0; o >>= 1) v += __shfl_down(v, o, 64);
    __shared__ float s[8];
    int lane = threadIdx.x & 63, w = threadIdx.x >> 6;
    if (lane == 0) s[w] = v;
    __syncthreads();
    float t = 0.f;
    if (threadIdx.x == 0) {
        int nw = (blockDim.x + 63) >> 6;
        for (int i = 0; i < nw; ++i) t += s[i];
    }
    return t;
}

// ---------- degree ----------
__global__ __launch_bounds__(256) void deg_kernel(const int* __restrict__ dst,
                                                  int* __restrict__ degs, int e) {
    int i = blockIdx.x * 256 + threadIdx.x;
    if (i < e) atomicAdd(&degs[dst[i]], 1);
}

// ---------- two-level exclusive scan -> rowstart (+ dinv fused) ----------
__global__ __launch_bounds__(SCAN_B) void scan_block_kernel(const int* __restrict__ degs,
                                                            int* __restrict__ rowstart,
                                                            int* __restrict__ blocksums,
                                                            float* __restrict__ dinv, int n) {
    __shared__ int sh[SCAN_B];
    int i = blockIdx.x * SCAN_B + threadIdx.x;
    int v = (i < n) ? degs[i] : 0;
    sh[threadIdx.x] = v;
    __syncthreads();
    for (int o = 1; o < SCAN_B; o <<= 1) {
        int t = (threadIdx.x >= o) ? sh[threadIdx.x - o] : 0;
        __syncthreads();
        sh[threadIdx.x] += t;
        __syncthreads();
    }
    if (i < n) {
        rowstart[i] = sh[threadIdx.x] - v;
        dinv[i] = 1.f / sqrtf(fmaxf((float)v, 1.f));
    }
    if (threadIdx.x == SCAN_B - 1) blocksums[blockIdx.x] = sh[threadIdx.x];
}

__global__ __launch_bounds__(512) void scan_sums_kernel(int* __restrict__ blocksums, int nb) {
    __shared__ int sh[512];
    int v = (threadIdx.x < nb) ? blocksums[threadIdx.x] : 0;
    sh[threadIdx.x] = v;
    __syncthreads();
    for (int o = 1; o < 512; o <<= 1) {
        int t = (threadIdx.x >= o) ? sh[threadIdx.x - o] : 0;
        __syncthreads();
        sh[threadIdx.x] += t;
        __syncthreads();
    }
    if (threadIdx.x < nb) blocksums[threadIdx.x] = sh[threadIdx.x] - v;
}

__global__ __launch_bounds__(SCAN_B) void scan_add_kernel(int* __restrict__ rowstart,
                                                          int* __restrict__ cursor,
                                                          const int* __restrict__ blocksums, int n) {
    int i = blockIdx.x * SCAN_B + threadIdx.x;
    if (i < n) {
        int v = rowstart[i] + blocksums[blockIdx.x];
        rowstart[i] = v;
        cursor[i] = v;
    }
}

__global__ __launch_bounds__(256) void csr_build_kernel(const int* __restrict__ src,
                                                        const int* __restrict__ dst,
                                                        int* __restrict__ cursor,
                                                        int* __restrict__ csr_src, int e) {
    int i = blockIdx.x * 256 + threadIdx.x;
    if (i < e) {
        int pos = atomicAdd(&cursor[dst[i]], 1);
        __builtin_nontemporal_store(src[i], &csr_src[pos]);
    }
}

// ---------- consolidated weight prep (161 blocks, branch by block) ----------
__global__ __launch_bounds__(256) void prep_all_kernel(
        const float* __restrict__ repw, const float* __restrict__ w2e,
        const float* __restrict__ b2e,  const float* __restrict__ repb,
        const float* __restrict__ w2d,
        const float* __restrict__ w1d,  const float* __restrict__ recw,
        const float* __restrict__ recb, const float* __restrict__ b1d,
        const float* __restrict__ w1e,
        unsigned short* __restrict__ Wcat,   // 96 x 128 (enc combo, pre-folded rep_w)
        float* __restrict__ bmu,             // 32
        unsigned short* __restrict__ wd2_a,  // 128 x 128
        unsigned short* __restrict__ wd2_b,
        unsigned short* __restrict__ wd2_c,
        unsigned short* __restrict__ wrd,    // 128 x 32
        float* __restrict__ brd,             // 128
        unsigned short* __restrict__ w1bf) { // 128 x 128
    int bid = blockIdx.x, tid = threadIdx.x;
    if (bid < 16) {                       // Wcat: 32*128 entries
        int idx = bid * 256 + tid;
        int i = idx >> 7, k = idx & 127;
        float m0 = 0.f, m1 = 0.f, m2 = 0.f;
        for (int h = 0; h < 128; ++h) {
            float r = repw[i * 128 + h];
            const float* wr = w2e + (size_t)h * 384 + k;
            m0 += r * wr[0];
            m1 += r * wr[128];
            m2 += r * wr[256];
        }
        Wcat[(size_t)i * 128 + k]        = (unsigned short)f2bf(3.f * m0);
        Wcat[(size_t)(32 + i) * 128 + k] = (unsigned short)f2bf(3.f * (m1 - m0));
        Wcat[(size_t)(64 + i) * 128 + k] = (unsigned short)f2bf(0.75f * m0 - 1.5f * m1 + 0.75f * m2);
    } else if (bid == 16) {               // bmu
        if (tid < 32) {
            float s = repb[tid];
            for (int h = 0; h < 128; ++h) s += repw[tid * 128 + h] * b2e[h];
            bmu[tid] = s;
        }
    } else if (bid < 81) {                // wd2: 128*128
        int idx = (bid - 17) * 256 + tid;
        int j = idx >> 7, k = idx & 127;
        const float* wr = w2d + (size_t)j * 384 + k;
        float w0 = wr[0], w1 = wr[128], w2v = wr[256];
        wd2_a[idx] = (unsigned short)f2bf(3.f * w0);
        wd2_b[idx] = (unsigned short)f2bf(3.f * (w1 - w0));
        wd2_c[idx] = (unsigned short)f2bf(0.75f * w0 - 1.5f * w1 + 0.75f * w2v);
    } else if (bid < 97) {                // wrd: 128*32 (+brd)
        int idx = (bid - 81) * 256 + tid;
        int j = idx >> 5, i = idx & 31;
        float s = 0.f;
        for (int h = 0; h < 128; ++h) s += w1d[j * 128 + h] * recw[h * 32 + i];
        wrd[idx] = (unsigned short)f2bf(s);
        if (idx < 128) {
            float b = b1d[idx];
            for (int h = 0; h < 128; ++h) b += w1d[idx * 128 + h] * recb[h];
            brd[idx] = b;
        }
    } else {                              // w1 convert: 128*128
        int idx = (bid - 97) * 256 + tid;
        w1bf[idx] = (unsigned short)f2bf(w1e[idx]);
    }
}

// ---------- fc1: A = relu(feats @ enc_w1^T + b1), bf16 out ----------
__global__ __launch_bounds__(256) void fc1_mfma_kernel(const float* __restrict__ x,
                                                       const unsigned short* __restrict__ wbf,
                                                       const float* __restrict__ b,
                                                       unsigned short* __restrict__ out, int n) {
    int wv = threadIdx.x >> 6, lane = threadIdx.x & 63;
    int l16 = lane & 15, lhi = lane >> 4;
    int rowbase = blockIdx.x * 64 + wv * 16;
    int arow = rowbase + l16;
    f32x4 acc[8];
    #pragma unroll
    for (int jt = 0; jt < 8; ++jt) {
        float bj = b[jt * 16 + l16];
        acc[jt] = (f32x4){bj, bj, bj, bj};
    }
    #pragma unroll
    for (int kk = 0; kk < 4; ++kk) {
        int kbase = kk * 32 + lhi * 8;
        i32x4 afrag = {0, 0, 0, 0};
        if (arow < n) {
            const float* ap = x + (size_t)arow * F + kbase;
            f32x4 f0 = *reinterpret_cast<const f32x4*>(ap);
            f32x4 f1 = *reinterpret_cast<const f32x4*>(ap + 4);
            afrag.x = (int)(f2bf(f0.x) | (f2bf(f0.y) << 16));
            afrag.y = (int)(f2bf(f0.z) | (f2bf(f0.w) << 16));
            afrag.z = (int)(f2bf(f1.x) | (f2bf(f1.y) << 16));
            afrag.w = (int)(f2bf(f1.z) | (f2bf(f1.w) << 16));
        }
        #pragma unroll
        for (int jt = 0; jt < 8; ++jt) {
            i32x4 bfrag = *reinterpret_cast<const i32x4*>(wbf + (size_t)(jt * 16 + l16) * F + kbase);
            acc[jt] = mfma16(afrag, bfrag, acc[jt]);
        }
    }
    #pragma unroll
    for (int jt = 0; jt < 8; ++jt)
        #pragma unroll
        for (int r = 0; r < 4; ++r) {
            int row = rowbase + lhi * 4 + r;
            if (row < n)
                out[(size_t)row * F + jt * 16 + l16] =
                    (unsigned short)f2bf(fmaxf(acc[jt][r], 0.f));
        }
}

// ---------- encoder projection: G = A @ Wcat^T  (n x 96) ----------
__global__ __launch_bounds__(256) void encproj_kernel(const unsigned short* __restrict__ A,
                                                      const unsigned short* __restrict__ Wcat,
                                                      unsigned short* __restrict__ G0,   // n x 32
                                                      unsigned short* __restrict__ G12,  // n x 64
                                                      int n) {
    int wv = threadIdx.x >> 6, lane = threadIdx.x & 63;
    int l16 = lane & 15, lhi = lane >> 4;
    int rowbase = blockIdx.x * 64 + wv * 16;
    int arow = rowbase + l16;
    f32x4 acc[6];
    #pragma unroll
    for (int jt = 0; jt < 6; ++jt) acc[jt] = (f32x4){0.f, 0.f, 0.f, 0.f};
    #pragma unroll
    for (int kk = 0; kk < 4; ++kk) {
        int kbase = kk * 32 + lhi * 8;
        i32x4 afrag = {0, 0, 0, 0};
        if (arow < n)
            afrag = *reinterpret_cast<const i32x4*>(A + (size_t)arow * F + kbase);
        #pragma unroll
        for (int jt = 0; jt < 6; ++jt) {
            i32x4 bfrag = *reinterpret_cast<const i32x4*>(Wcat + (size_t)(jt * 16 + l16) * F + kbase);
            acc[jt] = mfma16(afrag, bfrag, acc[jt]);
        }
    }
    #pragma unroll
    for (int jt = 0; jt < 6; ++jt)
        #pragma unroll
        for (int r = 0; r < 4; ++r) {
            int row = rowbase + lhi * 4 + r;
            int j = jt * 16 + l16;
            if (row < n) {
                unsigned short v = (unsigned short)f2bf(acc[jt][r]);
                if (j < 32) G0[(size_t)row * 32 + j] = v;
                else        G12[(size_t)row * 64 + (j - 32)] = v;
            }
        }
}

// ---------- 64-wide gather: H12 = P(G12) ; 2 rows per wave ----------
__global__ __launch_bounds__(256) void gather64_kernel(const unsigned short* __restrict__ X,
                                                       const int* __restrict__ csr_src,
                                                       const int* __restrict__ rowstart,
                                                       const int* __restrict__ degs,
                                                       const float* __restrict__ dinv,
                                                       unsigned short* __restrict__ out, int n) {
    int wv = threadIdx.x >> 6, lane = threadIdx.x & 63;
    int r = blockIdx.x * 8 + wv * 2 + (lane >> 5);
    if (r >= n) return;
    int c = (lane & 31) * 2;
    int start = rowstart[r], deg = degs[r];
    float ax = 0.f, ay = 0.f;
    int i = 0;
    for (; i + 2 <= deg; i += 2) {
        int s0 = csr_src[start + i], s1 = csr_src[start + i + 1];
        float sc0 = dinv[s0], sc1 = dinv[s1];
        unsigned v0 = *reinterpret_cast<const unsigned*>(X + (size_t)s0 * 64 + c);
        unsigned v1 = *reinterpret_cast<const unsigned*>(X + (size_t)s1 * 64 + c);
        ax += bf2f(v0 & 0xffffu) * sc0 + bf2f(v1 & 0xffffu) * sc1;
        ay += bf2f(v0 >> 16) * sc0 + bf2f(v1 >> 16) * sc1;
    }
    if (i < deg) {
        int s = csr_src[start + i];
        float sc = dinv[s];
        unsigned v = *reinterpret_cast<const unsigned*>(X + (size_t)s * 64 + c);
        ax += bf2f(v & 0xffffu) * sc;
        ay += bf2f(v >> 16) * sc;
    }
    float di = dinv[r];
    unsigned xv = *reinterpret_cast<const unsigned*>(X + (size_t)r * 64 + c);
    float ox = bf2f(xv & 0xffffu) - di * ax;
    float oy = bf2f(xv >> 16) - di * ay;
    *reinterpret_cast<unsigned*>(out + (size_t)r * 64 + c) = f2bf(ox) | (f2bf(oy) << 16);
}

// ---------- 32-wide gather H3=P(H2) fused with mu/KL/reparam ----------
__global__ __launch_bounds__(256) void gather32_mukl_kernel(const unsigned short* __restrict__ H12,
                                                            const unsigned short* __restrict__ G0,
                                                            const int* __restrict__ csr_src,
                                                            const int* __restrict__ rowstart,
                                                            const int* __restrict__ degs,
                                                            const float* __restrict__ dinv,
                                                            const float* __restrict__ bmu,
                                                            unsigned short* __restrict__ Z,
                                                            double* __restrict__ accd, int n) {
    int wv = threadIdx.x >> 6, lane = threadIdx.x & 63;
    int r = blockIdx.x * 16 + wv * 4 + (lane >> 4);
    int c = (lane & 15) * 2;
    float kl = 0.f;
    if (r < n) {
        int start = rowstart[r], deg = degs[r];
        float ax = 0.f, ay = 0.f;
        int i = 0;
        for (; i + 2 <= deg; i += 2) {
            int s0 = csr_src[start + i], s1 = csr_src[start + i + 1];
            float sc0 = dinv[s0], sc1 = dinv[s1];
            unsigned v0 = *reinterpret_cast<const unsigned*>(H12 + (size_t)s0 * 64 + 32 + c);
            unsigned v1 = *reinterpret_cast<const unsigned*>(H12 + (size_t)s1 * 64 + 32 + c);
            ax += bf2f(v0 & 0xffffu) * sc0 + bf2f(v1 & 0xffffu) * sc1;
            ay += bf2f(v0 >> 16) * sc0 + bf2f(v1 >> 16) * sc1;
        }
        if (i < deg) {
            int s = csr_src[start + i];
            float sc = dinv[s];
            unsigned v = *reinterpret_cast<const unsigned*>(H12 + (size_t)s * 64 + 32 + c);
            ax += bf2f(v & 0xffffu) * sc;
            ay += bf2f(v >> 16) * sc;
        }
        float di = dinv[r];
        unsigned h2v = *reinterpret_cast<const unsigned*>(H12 + (size_t)r * 64 + 32 + c);
        float h3x = bf2f(h2v & 0xffffu) - di * ax;
        float h3y = bf2f(h2v >> 16) - di * ay;
        unsigned g0v = *reinterpret_cast<const unsigned*>(G0 + (size_t)r * 32 + c);
        unsigned h1v = *reinterpret_cast<const unsigned*>(H12 + (size_t)r * 64 + c);
        float mu0 = bf2f(g0v & 0xffffu) + bf2f(h1v & 0xffffu) + h3x + bmu[c];
        float mu1 = bf2f(g0v >> 16)     + bf2f(h1v >> 16)     + h3y + bmu[c + 1];
        kl = (1.f + mu0 - mu0 * mu0 - expf(mu0)) + (1.f + mu1 - mu1 * mu1 - expf(mu1));
        unsigned idx0 = (unsigned)(r * ZD + c);
        unsigned h1 = pcg_hash(2u * idx0 + 1u);
        unsigned h2 = pcg_hash(2u * idx0 + 2u);
        float u1 = ((float)h1 + 0.5f) * 2.3283064365386963e-10f;
        float u2 = ((float)h2 + 0.5f) * 2.3283064365386963e-10f;
        float eps0 = sqrtf(-2.f * logf(u1)) * cosf(6.283185307179586f * u2);
        unsigned idx1 = idx0 + 1u;
        unsigned h3 = pcg_hash(2u * idx1 + 1u);
        unsigned h4 = pcg_hash(2u * idx1 + 2u);
        float u3 = ((float)h3 + 0.5f) * 2.3283064365386963e-10f;
        float u4 = ((float)h4 + 0.5f) * 2.3283064365386963e-10f;
        float eps1 = sqrtf(-2.f * logf(u3)) * cosf(6.283185307179586f * u4);
        float z0 = mu0 + eps0 * expf(0.5f * mu0);
        float z1 = mu1 + eps1 * expf(0.5f * mu1);
        *reinterpret_cast<unsigned*>(Z + (size_t)r * ZD + c) = f2bf(z0) | (f2bf(z1) << 16);
    }
    float bs = block_reduce_sum(kl);
    if (threadIdx.x == 0) atomicAdd(&accd[1], (double)bs);
}

// ---------- 128-wide gather (decoder): out = P(x) ----------
__global__ __launch_bounds__(256) void spmm_gather_bf_kernel(const unsigned short* __restrict__ x,
                                                             const int* __restrict__ csr_src,
                                                             const int* __restrict__ rowstart,
                                                             const int* __restrict__ degs,
                                                             const float* __restrict__ dinv,
                                                             unsigned short* __restrict__ out, int n) {
    int r = blockIdx.x * 4 + (threadIdx.x >> 6);
    if (r >= n) return;
    int lane = threadIdx.x & 63;
    int c = lane * 2;
    int start = rowstart[r], deg = degs[r];
    float ax = 0.f, ay = 0.f;
    int i = 0;
    for (; i + 2 <= deg; i += 2) {
        int s0 = csr_src[start + i], s1 = csr_src[start + i + 1];
        float sc0 = dinv[s0], sc1 = dinv[s1];
        unsigned v0 = *reinterpret_cast<const unsigned*>(x + (size_t)s0 * F + c);
        unsigned v1 = *reinterpret_cast<const unsigned*>(x + (size_t)s1 * F + c);
        ax += bf2f(v0 & 0xffffu) * sc0 + bf2f(v1 & 0xffffu) * sc1;
        ay += bf2f(v0 >> 16) * sc0 + bf2f(v1 >> 16) * sc1;
    }
    if (i < deg) {
        int s = csr_src[start + i];
        float sc = dinv[s];
        unsigned v = *reinterpret_cast<const unsigned*>(x + (size_t)s * F + c);
        ax += bf2f(v & 0xffffu) * sc;
        ay += bf2f(v >> 16) * sc;
    }
    float di = dinv[r];
    unsigned xv = *reinterpret_cast<const unsigned*>(x + (size_t)r * F + c);
    float ox = bf2f(xv & 0xffffu) - di * ax;
    float oy = bf2f(xv >> 16) - di * ay;
    *reinterpret_cast<unsigned*>(out + (size_t)r * F + c) = f2bf(ox) | (f2bf(oy) << 16);
}

// ---------- recdec1: A = relu(Z @ Wrd^T + brd), K=32 ----------
__global__ __launch_bounds__(256) void recdec1_mfma_kernel(const unsigned short* __restrict__ Z,
                                                           const unsigned short* __restrict__ Wrd,
                                                           const float* __restrict__ brd,
                                                           unsigned short* __restrict__ out, int n) {
    int wv = threadIdx.x >> 6, lane = threadIdx.x & 63;
    int l16 = lane & 15, lhi = lane >> 4;
    int rowbase = blockIdx.x * 64 + wv * 16;
    int arow = rowbase + l16;
    int kbase = lhi * 8;
    i32x4 afrag = {0, 0, 0, 0};
    if (arow < n)
        afrag = *reinterpret_cast<const i32x4*>(Z + (size_t)arow * ZD + kbase);
    #pragma unroll
    for (int jt = 0; jt < 8; ++jt) {
        float bj = brd[jt * 16 + l16];
        f32x4 acc = (f32x4){bj, bj, bj, bj};
        i32x4 bfrag = *reinterpret_cast<const i32x4*>(Wrd + (size_t)(jt * 16 + l16) * ZD + kbase);
        acc = mfma16(afrag, bfrag, acc);
        #pragma unroll
        for (int r = 0; r < 4; ++r) {
            int row = rowbase + lhi * 4 + r;
            if (row < n)
                out[(size_t)row * F + jt * 16 + l16] =
                    (unsigned short)f2bf(fmaxf(acc[r], 0.f));
        }
    }
}

// ---------- dec2 GEMM (K=384 distributed) fused with reconstruction loss ----------
__global__ __launch_bounds__(256) void dec2loss_mfma_kernel(const unsigned short* __restrict__ A,
                                                            const unsigned short* __restrict__ B,
                                                            const unsigned short* __restrict__ C,
                                                            const unsigned short* __restrict__ Wa,
                                                            const unsigned short* __restrict__ Wb,
                                                            const unsigned short* __restrict__ Wc,
                                                            const float* __restrict__ b2,
                                                            const float* __restrict__ feats,
                                                            double* __restrict__ accd, int n) {
    int wv = threadIdx.x >> 6, lane = threadIdx.x & 63;
    int l16 = lane & 15, lhi = lane >> 4;
    int rowbase = blockIdx.x * 64 + wv * 16;
    int arow = rowbase + l16;
    f32x4 acc[8];
    #pragma unroll
    for (int jt = 0; jt < 8; ++jt) {
        float bj = b2[jt * 16 + l16];
        acc[jt] = (f32x4){bj, bj, bj, bj};
    }
    const unsigned short* mats[3] = {A, B, C};
    const unsigned short* ws[3]   = {Wa, Wb, Wc};
    #pragma unroll
    for (int s = 0; s < 3; ++s) {
        #pragma unroll
        for (int kk = 0; kk < 4; ++kk) {
            int kbase = kk * 32 + lhi * 8;
            i32x4 afrag = {0, 0, 0, 0};
            if (arow < n)
                afrag = *reinterpret_cast<const i32x4*>(mats[s] + (size_t)arow * F + kbase);
            #pragma unroll
            for (int jt = 0; jt < 8; ++jt) {
                i32x4 bfrag = *reinterpret_cast<const i32x4*>(ws[s] + (size_t)(jt * 16 + l16) * F + kbase);
                acc[jt] = mfma16(afrag, bfrag, acc[jt]);
            }
        }
    }
    float local = 0.f;
    #pragma unroll
    for (int jt = 0; jt < 8; ++jt)
        #pragma unroll
        for (int r = 0; r < 4; ++r) {
            int row = rowbase + lhi * 4 + r;
            if (row < n) {
                float d = acc[jt][r] - feats[(size_t)row * F + jt * 16 + l16];
                local += d * d;
            }
        }
    float bs = block_reduce_sum(local);
    if (threadIdx.x == 0) atomicAdd(&accd[0], (double)bs);
}

__global__ void finalize_kernel(const double* __restrict__ acc, float* __restrict__ out) {
    out[0] = (float)(acc[0] - 0.5 * acc[1]);
}

extern "C" void kernel_launch(void* const* d_in, const int* in_sizes, int n_in,
                              void* d_out, int out_size, void* d_ws, size_t ws_size,
                              hipStream_t stream) {
    const float* feats  = (const float*)d_in[0];
    const int*   src    = (const int*)d_in[1];
    const int*   dst    = (const int*)d_in[2];
    const float* enc_w1 = (const float*)d_in[3];
    const float* enc_b1 = (const float*)d_in[4];
    const float* enc_w2 = (const float*)d_in[5];
    const float* enc_b2 = (const float*)d_in[6];
    const float* dec_w1 = (const float*)d_in[7];
    const float* dec_b1 = (const float*)d_in[8];
    const float* dec_w2 = (const float*)d_in[9];
    const float* dec_b2 = (const float*)d_in[10];
    const float* rep_w  = (const float*)d_in[11];
    const float* rep_b  = (const float*)d_in[12];
    const float* rec_w  = (const float*)d_in[13];
    const float* rec_b  = (const float*)d_in[14];
    // d_in[15] = disc_w: unused (dgi branch cancels analytically)

    const int n = NN, e = EE;
    char* ws = (char*)d_ws;
    size_t off = 0;
    auto alloc = [&](size_t bytes) -> void* {
        void* p = ws + off;
        off += (bytes + 255) & ~(size_t)255;
        return p;
    };
    const size_t NFB = (size_t)n * F * sizeof(unsigned short);   // 25.6 MB
    const int nScanBlocks = (n + SCAN_B - 1) / SCAN_B;
    int*    degs    = (int*)alloc((size_t)n * sizeof(int));
    float*  dinv    = (float*)alloc((size_t)n * sizeof(float));
    int*    rowst   = (int*)alloc((size_t)n * sizeof(int));
    int*    cursor  = (int*)alloc((size_t)n * sizeof(int));
    int*    bsums   = (int*)alloc((size_t)nScanBlocks * sizeof(int));
    int*    csr_src = (int*)alloc((size_t)e * sizeof(int));
    unsigned short* Abf = (unsigned short*)alloc(NFB);
    unsigned short* Bbf = (unsigned short*)alloc(NFB);
    unsigned short* Cbf = (unsigned short*)alloc(NFB);
    unsigned short* G0  = (unsigned short*)alloc((size_t)n * 32 * sizeof(unsigned short));
    unsigned short* G12 = (unsigned short*)alloc((size_t)n * 64 * sizeof(unsigned short));
    unsigned short* H12 = (unsigned short*)alloc((size_t)n * 64 * sizeof(unsigned short));
    unsigned short* Zbf = (unsigned short*)alloc((size_t)n * ZD * sizeof(unsigned short));
    unsigned short* Wcat  = (unsigned short*)alloc(96 * 128 * sizeof(unsigned short));
    unsigned short* w1bf  = (unsigned short*)alloc(128 * 128 * sizeof(unsigned short));
    unsigned short* wd2_a = (unsigned short*)alloc(128 * 128 * sizeof(unsigned short));
    unsigned short* wd2_b = (unsigned short*)alloc(128 * 128 * sizeof(unsigned short));
    unsigned short* wd2_c = (unsigned short*)alloc(128 * 128 * sizeof(unsigned short));
    unsigned short* wrd   = (unsigned short*)alloc(128 * 32 * sizeof(unsigned short));
    float* bmu = (float*)alloc(32 * sizeof(float));
    float* brd = (float*)alloc(128 * sizeof(float));
    double* acc = (double*)alloc(2 * sizeof(double));

    const int gemm64   = (n + 63) / 64;     // 1563
    const int gathBlks = (n + 3) / 4;       // 25000 (128-wide)
    const int g64Blks  = (n + 7) / 8;       // 12500
    const int g32Blks  = (n + 15) / 16;     // 6250

    // graph structure
    hipMemsetAsync(degs, 0, (size_t)n * sizeof(int), stream);
    hipMemsetAsync(acc, 0, 2 * sizeof(double), stream);
    deg_kernel<<<(e + 255) / 256, 256, 0, stream>>>(dst, degs, e);
    scan_block_kernel<<<nScanBlocks, SCAN_B, 0, stream>>>(degs, rowst, bsums, dinv, n);
    scan_sums_kernel<<<1, 512, 0, stream>>>(bsums, nScanBlocks);
    scan_add_kernel<<<nScanBlocks, SCAN_B, 0, stream>>>(rowst, cursor, bsums, n);
    csr_build_kernel<<<(e + 255) / 256, 256, 0, stream>>>(src, dst, cursor, csr_src, e);

    // weight prep (single kernel)
    prep_all_kernel<<<161, 256, 0, stream>>>(rep_w, enc_w2, enc_b2, rep_b, dec_w2,
                                             dec_w1, rec_w, rec_b, dec_b1, enc_w1,
                                             Wcat, bmu, wd2_a, wd2_b, wd2_c, wrd, brd, w1bf);

    // encoder
    fc1_mfma_kernel<<<gemm64, 256, 0, stream>>>(feats, w1bf, enc_b1, Abf, n);
    encproj_kernel<<<gemm64, 256, 0, stream>>>(Abf, Wcat, G0, G12, n);
    gather64_kernel<<<g64Blks, 256, 0, stream>>>(G12, csr_src, rowst, degs, dinv, H12, n);
    gather32_mukl_kernel<<<g32Blks, 256, 0, stream>>>(H12, G0, csr_src, rowst, degs, dinv,
                                                      bmu, Zbf, acc, n);

    // decoder
    recdec1_mfma_kernel<<<gemm64, 256, 0, stream>>>(Zbf, wrd, brd, Abf, n);
    spmm_gather_bf_kernel<<<gathBlks, 256, 0, stream>>>(Abf, csr_src, rowst, degs, dinv, Bbf, n);
    spmm_gather_bf_kernel<<<gathBlks, 256, 0, stream>>>(Bbf, csr_src, rowst, degs, dinv, Cbf, n);
    dec2loss_mfma_kernel<<<gemm64, 256, 0, stream>>>(Abf, Bbf, Cbf, wd2_a, wd2_b, wd2_c,
                                                     dec_b2, feats, acc, n);

    finalize_kernel<<<1, 1, 0, stream>>>(acc, (float*)d_out);
}

// Round 5
// 648.002 us; speedup vs baseline: 19.5517x; 1.1732x over previous
//
#include <hip/hip_runtime.h>
#include <math.h>

// Problem constants (fixed by the reference).
#define NN   100000
#define EE   1600000
#define F    128      // IN_FEATS == H == 128
#define ZD   32       // Z_DIM
#define SCAN_B 256
#define PREP_BLOCKS 161
#define FC1_BLOCKS  1563   // ceil(100000/64)

// Algebra:
//  hs = [3x-3y1+0.75y2 | 3y1-1.5y2 | 0.75y2], y1=P(x), y2=P(y1)
//  hs @ W^T = x@(3W0)^T + y1@(3W1-3W0)^T + y2@(0.75W0-1.5W1+0.75W2)^T
//  P commutes with right-multiplication: (P X) M = P (X M).
//  Encoder (mu weights are 32x128):
//    [G0|G1|G2] = A @ Wcat^T ; [H1|H2]=P([G1|G2]) (64-wide); H3=P(H2) (32-wide)
//    mu = G0 + H1 + H3 + bmu   (fused with KL + reparam z)
//  Decoder keeps the 128-wide form (weights are square).
//  out = vgae_loss = sum((x_rec-feats)^2) - 0.5*sum(1+mu-mu^2-exp(mu))

typedef float f32x4 __attribute__((ext_vector_type(4)));
typedef int   i32x4 __attribute__((ext_vector_type(4)));
typedef __bf16 bf16x8 __attribute__((ext_vector_type(8)));

__device__ __forceinline__ f32x4 mfma16(i32x4 a, i32x4 b, f32x4 c) {
    return __builtin_amdgcn_mfma_f32_16x16x32_bf16(
        __builtin_bit_cast(bf16x8, a), __builtin_bit_cast(bf16x8, b), c, 0, 0, 0);
}

__device__ __forceinline__ unsigned f2bf(float f) {   // RNE float->bf16 (as u16)
    unsigned u = __float_as_uint(f);
    return (u + 0x7fffu + ((u >> 16) & 1u)) >> 16;
}
__device__ __forceinline__ float bf2f(unsigned h) { return __uint_as_float(h << 16); }

__device__ __forceinline__ unsigned pcg_hash(unsigned v) {
    v = v * 747796405u + 2891336453u;
    unsigned w = ((v >> ((v >> 28u) + 4u)) ^ v) * 277803737u;
    return (w >> 22u) ^ w;
}

__device__ __forceinline__ float block_reduce_sum(float v) {
    #pragma unroll
    for (int o = 32; o > 0; o >>= 1) v += __shfl_down(v, o, 64);
    __shared__ float s[8];
    int lane = threadIdx.x & 63, w = threadIdx.x >> 6;
    if (lane == 0) s[w] = v;
    __syncthreads();
    float t = 0.f;
    if (threadIdx.x == 0) {
        int nw = (blockDim.x + 63) >> 6;
        for (int i = 0; i < nw; ++i) t += s[i];
    }
    return t;
}

// ---------- fused: weight prep (blocks 0..160) || degree count (rest) ----------
__global__ __launch_bounds__(256) void prep_deg_kernel(
        const float* __restrict__ repw, const float* __restrict__ w2e,
        const float* __restrict__ b2e,  const float* __restrict__ repb,
        const float* __restrict__ w2d,
        const float* __restrict__ w1d,  const float* __restrict__ recw,
        const float* __restrict__ recb, const float* __restrict__ b1d,
        const float* __restrict__ w1e,
        unsigned short* __restrict__ Wcat,   // 96 x 128
        float* __restrict__ bmu,             // 32
        unsigned short* __restrict__ wd2_a,  // 128 x 128
        unsigned short* __restrict__ wd2_b,
        unsigned short* __restrict__ wd2_c,
        unsigned short* __restrict__ wrd,    // 128 x 32
        float* __restrict__ brd,             // 128
        unsigned short* __restrict__ w1bf,   // 128 x 128
        const int* __restrict__ dst, int* __restrict__ degs, int e) {
    int bid = blockIdx.x, tid = threadIdx.x;
    if (bid >= PREP_BLOCKS) {             // degree count
        int i = (bid - PREP_BLOCKS) * 256 + tid;
        if (i < e) atomicAdd(&degs[dst[i]], 1);
        return;
    }
    if (bid < 16) {                       // Wcat: 32*128 entries
        int idx = bid * 256 + tid;
        int i = idx >> 7, k = idx & 127;
        float m0 = 0.f, m1 = 0.f, m2 = 0.f;
        for (int h = 0; h < 128; ++h) {
            float r = repw[i * 128 + h];
            const float* wr = w2e + (size_t)h * 384 + k;
            m0 += r * wr[0];
            m1 += r * wr[128];
            m2 += r * wr[256];
        }
        Wcat[(size_t)i * 128 + k]        = (unsigned short)f2bf(3.f * m0);
        Wcat[(size_t)(32 + i) * 128 + k] = (unsigned short)f2bf(3.f * (m1 - m0));
        Wcat[(size_t)(64 + i) * 128 + k] = (unsigned short)f2bf(0.75f * m0 - 1.5f * m1 + 0.75f * m2);
    } else if (bid == 16) {               // bmu
        if (tid < 32) {
            float s = repb[tid];
            for (int h = 0; h < 128; ++h) s += repw[tid * 128 + h] * b2e[h];
            bmu[tid] = s;
        }
    } else if (bid < 81) {                // wd2: 128*128
        int idx = (bid - 17) * 256 + tid;
        int j = idx >> 7, k = idx & 127;
        const float* wr = w2d + (size_t)j * 384 + k;
        float w0 = wr[0], w1 = wr[128], w2v = wr[256];
        wd2_a[idx] = (unsigned short)f2bf(3.f * w0);
        wd2_b[idx] = (unsigned short)f2bf(3.f * (w1 - w0));
        wd2_c[idx] = (unsigned short)f2bf(0.75f * w0 - 1.5f * w1 + 0.75f * w2v);
    } else if (bid < 97) {                // wrd: 128*32 (+brd)
        int idx = (bid - 81) * 256 + tid;
        int j = idx >> 5, i = idx & 31;
        float s = 0.f;
        for (int h = 0; h < 128; ++h) s += w1d[j * 128 + h] * recw[h * 32 + i];
        wrd[idx] = (unsigned short)f2bf(s);
        if (idx < 128) {
            float b = b1d[idx];
            for (int h = 0; h < 128; ++h) b += w1d[idx * 128 + h] * recb[h];
            brd[idx] = b;
        }
    } else {                              // w1 convert: 128*128
        int idx = (bid - 97) * 256 + tid;
        w1bf[idx] = (unsigned short)f2bf(w1e[idx]);
    }
}

// ---------- two-level exclusive scan -> rowstart (+ dinv fused) ----------
__global__ __launch_bounds__(SCAN_B) void scan_block_kernel(const int* __restrict__ degs,
                                                            int* __restrict__ rowstart,
                                                            int* __restrict__ blocksums,
                                                            float* __restrict__ dinv, int n) {
    __shared__ int sh[SCAN_B];
    int i = blockIdx.x * SCAN_B + threadIdx.x;
    int v = (i < n) ? degs[i] : 0;
    sh[threadIdx.x] = v;
    __syncthreads();
    for (int o = 1; o < SCAN_B; o <<= 1) {
        int t = (threadIdx.x >= o) ? sh[threadIdx.x - o] : 0;
        __syncthreads();
        sh[threadIdx.x] += t;
        __syncthreads();
    }
    if (i < n) {
        rowstart[i] = sh[threadIdx.x] - v;
        dinv[i] = 1.f / sqrtf(fmaxf((float)v, 1.f));
    }
    if (threadIdx.x == SCAN_B - 1) blocksums[blockIdx.x] = sh[threadIdx.x];
}

__global__ __launch_bounds__(512) void scan_sums_kernel(int* __restrict__ blocksums, int nb) {
    __shared__ int sh[512];
    int v = (threadIdx.x < nb) ? blocksums[threadIdx.x] : 0;
    sh[threadIdx.x] = v;
    __syncthreads();
    for (int o = 1; o < 512; o <<= 1) {
        int t = (threadIdx.x >= o) ? sh[threadIdx.x - o] : 0;
        __syncthreads();
        sh[threadIdx.x] += t;
        __syncthreads();
    }
    if (threadIdx.x < nb) blocksums[threadIdx.x] = sh[threadIdx.x] - v;
}

__global__ __launch_bounds__(SCAN_B) void scan_add_kernel(int* __restrict__ rowstart,
                                                          int* __restrict__ cursor,
                                                          const int* __restrict__ blocksums, int n) {
    int i = blockIdx.x * SCAN_B + threadIdx.x;
    if (i < n) {
        int v = rowstart[i] + blocksums[blockIdx.x];
        rowstart[i] = v;
        cursor[i] = v;
    }
}

// ---------- fused: fc1 MFMA GEMM (blocks < FC1_BLOCKS) || CSR build (rest) ----------
__global__ __launch_bounds__(256) void fc1_csr_kernel(const float* __restrict__ x,
                                                      const unsigned short* __restrict__ wbf,
                                                      const float* __restrict__ b,
                                                      unsigned short* __restrict__ out,
                                                      const int* __restrict__ src,
                                                      const int* __restrict__ dst,
                                                      int* __restrict__ cursor,
                                                      int* __restrict__ csr_src,
                                                      int n, int e) {
    if (blockIdx.x >= FC1_BLOCKS) {       // CSR bucket-scatter
        int i = (blockIdx.x - FC1_BLOCKS) * 256 + threadIdx.x;
        if (i < e) {
            int pos = atomicAdd(&cursor[dst[i]], 1);
            csr_src[pos] = src[i];
        }
        return;
    }
    int wv = threadIdx.x >> 6, lane = threadIdx.x & 63;
    int l16 = lane & 15, lhi = lane >> 4;
    int rowbase = blockIdx.x * 64 + wv * 16;
    int arow = rowbase + l16;
    f32x4 acc[8];
    #pragma unroll
    for (int jt = 0; jt < 8; ++jt) {
        float bj = b[jt * 16 + l16];
        acc[jt] = (f32x4){bj, bj, bj, bj};
    }
    #pragma unroll
    for (int kk = 0; kk < 4; ++kk) {
        int kbase = kk * 32 + lhi * 8;
        i32x4 afrag = {0, 0, 0, 0};
        if (arow < n) {
            const float* ap = x + (size_t)arow * F + kbase;
            f32x4 f0 = *reinterpret_cast<const f32x4*>(ap);
            f32x4 f1 = *reinterpret_cast<const f32x4*>(ap + 4);
            afrag.x = (int)(f2bf(f0.x) | (f2bf(f0.y) << 16));
            afrag.y = (int)(f2bf(f0.z) | (f2bf(f0.w) << 16));
            afrag.z = (int)(f2bf(f1.x) | (f2bf(f1.y) << 16));
            afrag.w = (int)(f2bf(f1.z) | (f2bf(f1.w) << 16));
        }
        #pragma unroll
        for (int jt = 0; jt < 8; ++jt) {
            i32x4 bfrag = *reinterpret_cast<const i32x4*>(wbf + (size_t)(jt * 16 + l16) * F + kbase);
            acc[jt] = mfma16(afrag, bfrag, acc[jt]);
        }
    }
    #pragma unroll
    for (int jt = 0; jt < 8; ++jt)
        #pragma unroll
        for (int r = 0; r < 4; ++r) {
            int row = rowbase + lhi * 4 + r;
            if (row < n)
                out[(size_t)row * F + jt * 16 + l16] =
                    (unsigned short)f2bf(fmaxf(acc[jt][r], 0.f));
        }
}

// ---------- encoder projection: G = A @ Wcat^T  (n x 96) ----------
__global__ __launch_bounds__(256) void encproj_kernel(const unsigned short* __restrict__ A,
                                                      const unsigned short* __restrict__ Wcat,
                                                      unsigned short* __restrict__ G0,   // n x 32
                                                      unsigned short* __restrict__ G12,  // n x 64
                                                      int n) {
    int wv = threadIdx.x >> 6, lane = threadIdx.x & 63;
    int l16 = lane & 15, lhi = lane >> 4;
    int rowbase = blockIdx.x * 64 + wv * 16;
    int arow = rowbase + l16;
    f32x4 acc[6];
    #pragma unroll
    for (int jt = 0; jt < 6; ++jt) acc[jt] = (f32x4){0.f, 0.f, 0.f, 0.f};
    #pragma unroll
    for (int kk = 0; kk < 4; ++kk) {
        int kbase = kk * 32 + lhi * 8;
        i32x4 afrag = {0, 0, 0, 0};
        if (arow < n)
            afrag = *reinterpret_cast<const i32x4*>(A + (size_t)arow * F + kbase);
        #pragma unroll
        for (int jt = 0; jt < 6; ++jt) {
            i32x4 bfrag = *reinterpret_cast<const i32x4*>(Wcat + (size_t)(jt * 16 + l16) * F + kbase);
            acc[jt] = mfma16(afrag, bfrag, acc[jt]);
        }
    }
    #pragma unroll
    for (int jt = 0; jt < 6; ++jt)
        #pragma unroll
        for (int r = 0; r < 4; ++r) {
            int row = rowbase + lhi * 4 + r;
            int j = jt * 16 + l16;
            if (row < n) {
                unsigned short v = (unsigned short)f2bf(acc[jt][r]);
                if (j < 32) G0[(size_t)row * 32 + j] = v;
                else        G12[(size_t)row * 64 + (j - 32)] = v;
            }
        }
}

// ---------- 64-wide gather: H12 = P(G12); 32-lane groups, shfl index prefetch ----------
__global__ __launch_bounds__(256) void gather64_kernel(const unsigned short* __restrict__ X,
                                                       const int* __restrict__ csr_src,
                                                       const int* __restrict__ rowstart,
                                                       const int* __restrict__ degs,
                                                       const float* __restrict__ dinv,
                                                       unsigned short* __restrict__ out, int n) {
    int r = blockIdx.x * 8 + (threadIdx.x >> 5);
    if (r >= n) return;
    int lane = threadIdx.x & 31;
    int c = lane * 2;
    int start = rowstart[r], deg = degs[r];
    float ax = 0.f, ay = 0.f;
    for (int base = 0; base < deg; base += 32) {
        int cnt = min(deg - base, 32);
        int s = 0; float sc = 0.f;
        if (lane < cnt) { s = csr_src[start + base + lane]; sc = dinv[s]; }
        int k = 0;
        for (; k + 4 <= cnt; k += 4) {
            int s0 = __shfl(s, k, 32), s1 = __shfl(s, k + 1, 32);
            int s2 = __shfl(s, k + 2, 32), s3 = __shfl(s, k + 3, 32);
            float c0 = __shfl(sc, k, 32), c1 = __shfl(sc, k + 1, 32);
            float c2 = __shfl(sc, k + 2, 32), c3 = __shfl(sc, k + 3, 32);
            unsigned v0 = *reinterpret_cast<const unsigned*>(X + (size_t)s0 * 64 + c);
            unsigned v1 = *reinterpret_cast<const unsigned*>(X + (size_t)s1 * 64 + c);
            unsigned v2 = *reinterpret_cast<const unsigned*>(X + (size_t)s2 * 64 + c);
            unsigned v3 = *reinterpret_cast<const unsigned*>(X + (size_t)s3 * 64 + c);
            ax += bf2f(v0 & 0xffffu) * c0 + bf2f(v1 & 0xffffu) * c1
                + bf2f(v2 & 0xffffu) * c2 + bf2f(v3 & 0xffffu) * c3;
            ay += bf2f(v0 >> 16) * c0 + bf2f(v1 >> 16) * c1
                + bf2f(v2 >> 16) * c2 + bf2f(v3 >> 16) * c3;
        }
        for (; k < cnt; ++k) {
            int sk = __shfl(s, k, 32);
            float ck = __shfl(sc, k, 32);
            unsigned v = *reinterpret_cast<const unsigned*>(X + (size_t)sk * 64 + c);
            ax += bf2f(v & 0xffffu) * ck;
            ay += bf2f(v >> 16) * ck;
        }
    }
    float di = dinv[r];
    unsigned xv = *reinterpret_cast<const unsigned*>(X + (size_t)r * 64 + c);
    float ox = bf2f(xv & 0xffffu) - di * ax;
    float oy = bf2f(xv >> 16) - di * ay;
    *reinterpret_cast<unsigned*>(out + (size_t)r * 64 + c) = f2bf(ox) | (f2bf(oy) << 16);
}

// ---------- 32-wide gather H3=P(H2) fused with mu/KL/reparam; 16-lane groups ----------
__global__ __launch_bounds__(256) void gather32_mukl_kernel(const unsigned short* __restrict__ H12,
                                                            const unsigned short* __restrict__ G0,
                                                            const int* __restrict__ csr_src,
                                                            const int* __restrict__ rowstart,
                                                            const int* __restrict__ degs,
                                                            const float* __restrict__ dinv,
                                                            const float* __restrict__ bmu,
                                                            unsigned short* __restrict__ Z,
                                                            double* __restrict__ accd, int n) {
    int r = blockIdx.x * 16 + (threadIdx.x >> 4);
    int lane = threadIdx.x & 15;
    int c = lane * 2;
    float kl = 0.f;
    if (r < n) {
        int start = rowstart[r], deg = degs[r];
        float ax = 0.f, ay = 0.f;
        for (int base = 0; base < deg; base += 16) {
            int cnt = min(deg - base, 16);
            int s = 0; float sc = 0.f;
            if (lane < cnt) { s = csr_src[start + base + lane]; sc = dinv[s]; }
            int k = 0;
            for (; k + 4 <= cnt; k += 4) {
                int s0 = __shfl(s, k, 16), s1 = __shfl(s, k + 1, 16);
                int s2 = __shfl(s, k + 2, 16), s3 = __shfl(s, k + 3, 16);
                float c0 = __shfl(sc, k, 16), c1 = __shfl(sc, k + 1, 16);
                float c2 = __shfl(sc, k + 2, 16), c3 = __shfl(sc, k + 3, 16);
                unsigned v0 = *reinterpret_cast<const unsigned*>(H12 + (size_t)s0 * 64 + 32 + c);
                unsigned v1 = *reinterpret_cast<const unsigned*>(H12 + (size_t)s1 * 64 + 32 + c);
                unsigned v2 = *reinterpret_cast<const unsigned*>(H12 + (size_t)s2 * 64 + 32 + c);
                unsigned v3 = *reinterpret_cast<const unsigned*>(H12 + (size_t)s3 * 64 + 32 + c);
                ax += bf2f(v0 & 0xffffu) * c0 + bf2f(v1 & 0xffffu) * c1
                    + bf2f(v2 & 0xffffu) * c2 + bf2f(v3 & 0xffffu) * c3;
                ay += bf2f(v0 >> 16) * c0 + bf2f(v1 >> 16) * c1
                    + bf2f(v2 >> 16) * c2 + bf2f(v3 >> 16) * c3;
            }
            for (; k < cnt; ++k) {
                int sk = __shfl(s, k, 16);
                float ck = __shfl(sc, k, 16);
                unsigned v = *reinterpret_cast<const unsigned*>(H12 + (size_t)sk * 64 + 32 + c);
                ax += bf2f(v & 0xffffu) * ck;
                ay += bf2f(v >> 16) * ck;
            }
        }
        float di = dinv[r];
        unsigned h2v = *reinterpret_cast<const unsigned*>(H12 + (size_t)r * 64 + 32 + c);
        float h3x = bf2f(h2v & 0xffffu) - di * ax;
        float h3y = bf2f(h2v >> 16) - di * ay;
        unsigned g0v = *reinterpret_cast<const unsigned*>(G0 + (size_t)r * 32 + c);
        unsigned h1v = *reinterpret_cast<const unsigned*>(H12 + (size_t)r * 64 + c);
        float mu0 = bf2f(g0v & 0xffffu) + bf2f(h1v & 0xffffu) + h3x + bmu[c];
        float mu1 = bf2f(g0v >> 16)     + bf2f(h1v >> 16)     + h3y + bmu[c + 1];
        kl = (1.f + mu0 - mu0 * mu0 - expf(mu0)) + (1.f + mu1 - mu1 * mu1 - expf(mu1));
        unsigned idx0 = (unsigned)(r * ZD + c);
        unsigned h1 = pcg_hash(2u * idx0 + 1u);
        unsigned h2 = pcg_hash(2u * idx0 + 2u);
        float u1 = ((float)h1 + 0.5f) * 2.3283064365386963e-10f;
        float u2 = ((float)h2 + 0.5f) * 2.3283064365386963e-10f;
        float eps0 = sqrtf(-2.f * logf(u1)) * cosf(6.283185307179586f * u2);
        unsigned idx1 = idx0 + 1u;
        unsigned h3 = pcg_hash(2u * idx1 + 1u);
        unsigned h4 = pcg_hash(2u * idx1 + 2u);
        float u3 = ((float)h3 + 0.5f) * 2.3283064365386963e-10f;
        float u4 = ((float)h4 + 0.5f) * 2.3283064365386963e-10f;
        float eps1 = sqrtf(-2.f * logf(u3)) * cosf(6.283185307179586f * u4);
        float z0 = mu0 + eps0 * expf(0.5f * mu0);
        float z1 = mu1 + eps1 * expf(0.5f * mu1);
        *reinterpret_cast<unsigned*>(Z + (size_t)r * ZD + c) = f2bf(z0) | (f2bf(z1) << 16);
    }
    float bs = block_reduce_sum(kl);
    if (threadIdx.x == 0) atomicAdd(&accd[1], (double)bs);
}

// ---------- 128-wide gather (decoder); 64-lane rows, shfl index prefetch ----------
__global__ __launch_bounds__(256) void gather128_kernel(const unsigned short* __restrict__ x,
                                                        const int* __restrict__ csr_src,
                                                        const int* __restrict__ rowstart,
                                                        const int* __restrict__ degs,
                                                        const float* __restrict__ dinv,
                                                        unsigned short* __restrict__ out, int n) {
    int r = blockIdx.x * 4 + (threadIdx.x >> 6);
    if (r >= n) return;
    int lane = threadIdx.x & 63;
    int c = lane * 2;
    int start = rowstart[r], deg = degs[r];
    float ax = 0.f, ay = 0.f;
    for (int base = 0; base < deg; base += 64) {
        int cnt = min(deg - base, 64);
        int s = 0; float sc = 0.f;
        if (lane < cnt) { s = csr_src[start + base + lane]; sc = dinv[s]; }
        int k = 0;
        for (; k + 4 <= cnt; k += 4) {
            int s0 = __shfl(s, k), s1 = __shfl(s, k + 1);
            int s2 = __shfl(s, k + 2), s3 = __shfl(s, k + 3);
            float c0 = __shfl(sc, k), c1 = __shfl(sc, k + 1);
            float c2 = __shfl(sc, k + 2), c3 = __shfl(sc, k + 3);
            unsigned v0 = *reinterpret_cast<const unsigned*>(x + (size_t)s0 * F + c);
            unsigned v1 = *reinterpret_cast<const unsigned*>(x + (size_t)s1 * F + c);
            unsigned v2 = *reinterpret_cast<const unsigned*>(x + (size_t)s2 * F + c);
            unsigned v3 = *reinterpret_cast<const unsigned*>(x + (size_t)s3 * F + c);
            ax += bf2f(v0 & 0xffffu) * c0 + bf2f(v1 & 0xffffu) * c1
                + bf2f(v2 & 0xffffu) * c2 + bf2f(v3 & 0xffffu) * c3;
            ay += bf2f(v0 >> 16) * c0 + bf2f(v1 >> 16) * c1
                + bf2f(v2 >> 16) * c2 + bf2f(v3 >> 16) * c3;
        }
        for (; k < cnt; ++k) {
            int sk = __shfl(s, k);
            float ck = __shfl(sc, k);
            unsigned v = *reinterpret_cast<const unsigned*>(x + (size_t)sk * F + c);
            ax += bf2f(v & 0xffffu) * ck;
            ay += bf2f(v >> 16) * ck;
        }
    }
    float di = dinv[r];
    unsigned xv = *reinterpret_cast<const unsigned*>(x + (size_t)r * F + c);
    float ox = bf2f(xv & 0xffffu) - di * ax;
    float oy = bf2f(xv >> 16) - di * ay;
    *reinterpret_cast<unsigned*>(out + (size_t)r * F + c) = f2bf(ox) | (f2bf(oy) << 16);
}

// ---------- recdec1: A = relu(Z @ Wrd^T + brd), K=32 ----------
__global__ __launch_bounds__(256) void recdec1_mfma_kernel(const unsigned short* __restrict__ Z,
                                                           const unsigned short* __restrict__ Wrd,
                                                           const float* __restrict__ brd,
                                                           unsigned short* __restrict__ out, int n) {
    int wv = threadIdx.x >> 6, lane = threadIdx.x & 63;
    int l16 = lane & 15, lhi = lane >> 4;
    int rowbase = blockIdx.x * 64 + wv * 16;
    int arow = rowbase + l16;
    int kbase = lhi * 8;
    i32x4 afrag = {0, 0, 0, 0};
    if (arow < n)
        afrag = *reinterpret_cast<const i32x4*>(Z + (size_t)arow * ZD + kbase);
    #pragma unroll
    for (int jt = 0; jt < 8; ++jt) {
        float bj = brd[jt * 16 + l16];
        f32x4 acc = (f32x4){bj, bj, bj, bj};
        i32x4 bfrag = *reinterpret_cast<const i32x4*>(Wrd + (size_t)(jt * 16 + l16) * ZD + kbase);
        acc = mfma16(afrag, bfrag, acc);
        #pragma unroll
        for (int r = 0; r < 4; ++r) {
            int row = rowbase + lhi * 4 + r;
            if (row < n)
                out[(size_t)row * F + jt * 16 + l16] =
                    (unsigned short)f2bf(fmaxf(acc[r], 0.f));
        }
    }
}

// ---------- dec2 GEMM (K=384 distributed) fused with reconstruction loss ----------
__global__ __launch_bounds__(256) void dec2loss_mfma_kernel(const unsigned short* __restrict__ A,
                                                            const unsigned short* __restrict__ B,
                                                            const unsigned short* __restrict__ C,
                                                            const unsigned short* __restrict__ Wa,
                                                            const unsigned short* __restrict__ Wb,
                                                            const unsigned short* __restrict__ Wc,
                                                            const float* __restrict__ b2,
                                                            const float* __restrict__ feats,
                                                            double* __restrict__ accd, int n) {
    int wv = threadIdx.x >> 6, lane = threadIdx.x & 63;
    int l16 = lane & 15, lhi = lane >> 4;
    int rowbase = blockIdx.x * 64 + wv * 16;
    int arow = rowbase + l16;
    f32x4 acc[8];
    #pragma unroll
    for (int jt = 0; jt < 8; ++jt) {
        float bj = b2[jt * 16 + l16];
        acc[jt] = (f32x4){bj, bj, bj, bj};
    }
    const unsigned short* mats[3] = {A, B, C};
    const unsigned short* ws[3]   = {Wa, Wb, Wc};
    #pragma unroll
    for (int s = 0; s < 3; ++s) {
        #pragma unroll
        for (int kk = 0; kk < 4; ++kk) {
            int kbase = kk * 32 + lhi * 8;
            i32x4 afrag = {0, 0, 0, 0};
            if (arow < n)
                afrag = *reinterpret_cast<const i32x4*>(mats[s] + (size_t)arow * F + kbase);
            #pragma unroll
            for (int jt = 0; jt < 8; ++jt) {
                i32x4 bfrag = *reinterpret_cast<const i32x4*>(ws[s] + (size_t)(jt * 16 + l16) * F + kbase);
                acc[jt] = mfma16(afrag, bfrag, acc[jt]);
            }
        }
    }
    float local = 0.f;
    #pragma unroll
    for (int jt = 0; jt < 8; ++jt)
        #pragma unroll
        for (int r = 0; r < 4; ++r) {
            int row = rowbase + lhi * 4 + r;
            if (row < n) {
                float d = acc[jt][r] - feats[(size_t)row * F + jt * 16 + l16];
                local += d * d;
            }
        }
    float bs = block_reduce_sum(local);
    if (threadIdx.x == 0) atomicAdd(&accd[0], (double)bs);
}

__global__ void finalize_kernel(const double* __restrict__ acc, float* __restrict__ out) {
    out[0] = (float)(acc[0] - 0.5 * acc[1]);
}

extern "C" void kernel_launch(void* const* d_in, const int* in_sizes, int n_in,
                              void* d_out, int out_size, void* d_ws, size_t ws_size,
                              hipStream_t stream) {
    const float* feats  = (const float*)d_in[0];
    const int*   src    = (const int*)d_in[1];
    const int*   dst    = (const int*)d_in[2];
    const float* enc_w1 = (const float*)d_in[3];
    const float* enc_b1 = (const float*)d_in[4];
    const float* enc_w2 = (const float*)d_in[5];
    const float* enc_b2 = (const float*)d_in[6];
    const float* dec_w1 = (const float*)d_in[7];
    const float* dec_b1 = (const float*)d_in[8];
    const float* dec_w2 = (const float*)d_in[9];
    const float* dec_b2 = (const float*)d_in[10];
    const float* rep_w  = (const float*)d_in[11];
    const float* rep_b  = (const float*)d_in[12];
    const float* rec_w  = (const float*)d_in[13];
    const float* rec_b  = (const float*)d_in[14];
    // d_in[15] = disc_w: unused (dgi branch cancels analytically)

    const int n = NN, e = EE;
    char* ws = (char*)d_ws;
    size_t off = 0;
    auto alloc = [&](size_t bytes) -> void* {
        void* p = ws + off;
        off += (bytes + 255) & ~(size_t)255;
        return p;
    };
    const size_t NFB = (size_t)n * F * sizeof(unsigned short);   // 25.6 MB
    const int nScanBlocks = (n + SCAN_B - 1) / SCAN_B;
    int*    degs    = (int*)alloc((size_t)n * sizeof(int));
    float*  dinv    = (float*)alloc((size_t)n * sizeof(float));
    int*    rowst   = (int*)alloc((size_t)n * sizeof(int));
    int*    cursor  = (int*)alloc((size_t)n * sizeof(int));
    int*    bsums   = (int*)alloc((size_t)nScanBlocks * sizeof(int));
    int*    csr_src = (int*)alloc((size_t)e * sizeof(int));
    unsigned short* Abf = (unsigned short*)alloc(NFB);
    unsigned short* Bbf = (unsigned short*)alloc(NFB);
    unsigned short* Cbf = (unsigned short*)alloc(NFB);
    unsigned short* G0  = (unsigned short*)alloc((size_t)n * 32 * sizeof(unsigned short));
    unsigned short* G12 = (unsigned short*)alloc((size_t)n * 64 * sizeof(unsigned short));
    unsigned short* H12 = (unsigned short*)alloc((size_t)n * 64 * sizeof(unsigned short));
    unsigned short* Zbf = (unsigned short*)alloc((size_t)n * ZD * sizeof(unsigned short));
    unsigned short* Wcat  = (unsigned short*)alloc(96 * 128 * sizeof(unsigned short));
    unsigned short* w1bf  = (unsigned short*)alloc(128 * 128 * sizeof(unsigned short));
    unsigned short* wd2_a = (unsigned short*)alloc(128 * 128 * sizeof(unsigned short));
    unsigned short* wd2_b = (unsigned short*)alloc(128 * 128 * sizeof(unsigned short));
    unsigned short* wd2_c = (unsigned short*)alloc(128 * 128 * sizeof(unsigned short));
    unsigned short* wrd   = (unsigned short*)alloc(128 * 32 * sizeof(unsigned short));
    float* bmu = (float*)alloc(32 * sizeof(float));
    float* brd = (float*)alloc(128 * sizeof(float));
    double* acc = (double*)alloc(2 * sizeof(double));

    const int gemm64   = (n + 63) / 64;     // 1563
    const int csrBlks  = (e + 255) / 256;   // 6250
    const int gathBlks = (n + 3) / 4;       // 25000 (128-wide)
    const int g64Blks  = (n + 7) / 8;       // 12500
    const int g32Blks  = (n + 15) / 16;     // 6250

    hipMemsetAsync(degs, 0, (size_t)n * sizeof(int), stream);
    hipMemsetAsync(acc, 0, 2 * sizeof(double), stream);

    // weight prep || degree count (fused)
    prep_deg_kernel<<<PREP_BLOCKS + csrBlks, 256, 0, stream>>>(
        rep_w, enc_w2, enc_b2, rep_b, dec_w2, dec_w1, rec_w, rec_b, dec_b1, enc_w1,
        Wcat, bmu, wd2_a, wd2_b, wd2_c, wrd, brd, w1bf, dst, degs, e);

    scan_block_kernel<<<nScanBlocks, SCAN_B, 0, stream>>>(degs, rowst, bsums, dinv, n);
    scan_sums_kernel<<<1, 512, 0, stream>>>(bsums, nScanBlocks);
    scan_add_kernel<<<nScanBlocks, SCAN_B, 0, stream>>>(rowst, cursor, bsums, n);

    // fc1 GEMM || CSR build (fused; independent subsystems)
    fc1_csr_kernel<<<FC1_BLOCKS + csrBlks, 256, 0, stream>>>(
        feats, w1bf, enc_b1, Abf, src, dst, cursor, csr_src, n, e);

    // encoder
    encproj_kernel<<<gemm64, 256, 0, stream>>>(Abf, Wcat, G0, G12, n);
    gather64_kernel<<<g64Blks, 256, 0, stream>>>(G12, csr_src, rowst, degs, dinv, H12, n);
    gather32_mukl_kernel<<<g32Blks, 256, 0, stream>>>(H12, G0, csr_src, rowst, degs, dinv,
                                                      bmu, Zbf, acc, n);

    // decoder
    recdec1_mfma_kernel<<<gemm64, 256, 0, stream>>>(Zbf, wrd, brd, Abf, n);
    gather128_kernel<<<gathBlks, 256, 0, stream>>>(Abf, csr_src, rowst, degs, dinv, Bbf, n);
    gather128_kernel<<<gathBlks, 256, 0, stream>>>(Bbf, csr_src, rowst, degs, dinv, Cbf, n);
    dec2loss_mfma_kernel<<<gemm64, 256, 0, stream>>>(Abf, Bbf, Cbf, wd2_a, wd2_b, wd2_c,
                                                     dec_b2, feats, acc, n);

    finalize_kernel<<<1, 1, 0, stream>>>(acc, (float*)d_out);
}

// Round 6
// 575.021 us; speedup vs baseline: 22.0332x; 1.1269x over previous
//
#include <hip/hip_runtime.h>
#include <math.h>

// Problem constants (fixed by the reference).
#define NN   100000
#define EE   1600000
#define F    128      // IN_FEATS == H == 128
#define ZD   32       // Z_DIM
#define SCAN_B 256
#define PREP_BLOCKS 161
#define FC1_BLOCKS  1563   // ceil(100000/64)
#define ENC_BLOCKS  1563
#define NBUCK 391          // ceil(100000/256) dst-range buckets
#define PART_CHUNK 8192
#define PART_BLOCKS 196    // ceil(1600000/8192)

// Algebra:
//  hs = [3x-3y1+0.75y2 | 3y1-1.5y2 | 0.75y2], y1=P(x), y2=P(y1)
//  hs @ W^T = x@(3W0)^T + y1@(3W1-3W0)^T + y2@(0.75W0-1.5W1+0.75W2)^T
//  P commutes with right-mult AND is linear:
//    mu = G0 + P(G1) + P^2(G2) + bmu = G0 + P(G1 + P(G2)) + bmu
//  Encoder: [G0|G1|G2] = A @ Wcat^T (n x 96);  W = G1 + P(G2) (32-wide gather);
//           mu = G0 + P(W) + bmu (32-wide gather, fused KL + reparam z)
//  Decoder keeps the 128-wide form (square weights).
//  out = vgae_loss = sum((x_rec-feats)^2) - 0.5*sum(1+mu-mu^2-exp(mu))
//  CSR build: two-phase (bucket partition with coalesced flushes, then
//  within-bucket scatter into L2-resident 16KB windows) to kill the 16x
//  write amplification of random 4B scatters.

typedef float f32x4 __attribute__((ext_vector_type(4)));
typedef int   i32x4 __attribute__((ext_vector_type(4)));
typedef __bf16 bf16x8 __attribute__((ext_vector_type(8)));

__device__ __forceinline__ f32x4 mfma16(i32x4 a, i32x4 b, f32x4 c) {
    return __builtin_amdgcn_mfma_f32_16x16x32_bf16(
        __builtin_bit_cast(bf16x8, a), __builtin_bit_cast(bf16x8, b), c, 0, 0, 0);
}

__device__ __forceinline__ unsigned f2bf(float f) {   // RNE float->bf16 (as u16)
    unsigned u = __float_as_uint(f);
    return (u + 0x7fffu + ((u >> 16) & 1u)) >> 16;
}
__device__ __forceinline__ float bf2f(unsigned h) { return __uint_as_float(h << 16); }

__device__ __forceinline__ unsigned pcg_hash(unsigned v) {
    v = v * 747796405u + 2891336453u;
    unsigned w = ((v >> ((v >> 28u) + 4u)) ^ v) * 277803737u;
    return (w >> 22u) ^ w;
}

__device__ __forceinline__ float block_reduce_sum(float v) {
    #pragma unroll
    for (int o = 32; o > 0; o >>= 1) v += __shfl_down(v, o, 64);
    __shared__ float s[8];
    int lane = threadIdx.x & 63, w = threadIdx.x >> 6;
    if (lane == 0) s[w] = v;
    __syncthreads();
    float t = 0.f;
    if (threadIdx.x == 0) {
        int nw = (blockDim.x + 63) >> 6;
        for (int i = 0; i < nw; ++i) t += s[i];
    }
    return t;
}

// ---------- fused: weight prep (blocks 0..160) || degree count (rest) ----------
__global__ __launch_bounds__(256) void prep_deg_kernel(
        const float* __restrict__ repw, const float* __restrict__ w2e,
        const float* __restrict__ b2e,  const float* __restrict__ repb,
        const float* __restrict__ w2d,
        const float* __restrict__ w1d,  const float* __restrict__ recw,
        const float* __restrict__ recb, const float* __restrict__ b1d,
        const float* __restrict__ w1e,
        unsigned short* __restrict__ Wcat,   // 96 x 128
        float* __restrict__ bmu,             // 32
        unsigned short* __restrict__ wd2_a,  // 128 x 128
        unsigned short* __restrict__ wd2_b,
        unsigned short* __restrict__ wd2_c,
        unsigned short* __restrict__ wrd,    // 128 x 32
        float* __restrict__ brd,             // 128
        unsigned short* __restrict__ w1bf,   // 128 x 128
        const int* __restrict__ dst, int* __restrict__ degs, int e) {
    int bid = blockIdx.x, tid = threadIdx.x;
    if (bid >= PREP_BLOCKS) {             // degree count
        int i = (bid - PREP_BLOCKS) * 256 + tid;
        if (i < e) atomicAdd(&degs[dst[i]], 1);
        return;
    }
    if (bid < 16) {                       // Wcat: 32*128 entries
        int idx = bid * 256 + tid;
        int i = idx >> 7, k = idx & 127;
        float m0 = 0.f, m1 = 0.f, m2 = 0.f;
        for (int h = 0; h < 128; ++h) {
            float r = repw[i * 128 + h];
            const float* wr = w2e + (size_t)h * 384 + k;
            m0 += r * wr[0];
            m1 += r * wr[128];
            m2 += r * wr[256];
        }
        Wcat[(size_t)i * 128 + k]        = (unsigned short)f2bf(3.f * m0);
        Wcat[(size_t)(32 + i) * 128 + k] = (unsigned short)f2bf(3.f * (m1 - m0));
        Wcat[(size_t)(64 + i) * 128 + k] = (unsigned short)f2bf(0.75f * m0 - 1.5f * m1 + 0.75f * m2);
    } else if (bid == 16) {               // bmu
        if (tid < 32) {
            float s = repb[tid];
            for (int h = 0; h < 128; ++h) s += repw[tid * 128 + h] * b2e[h];
            bmu[tid] = s;
        }
    } else if (bid < 81) {                // wd2: 128*128
        int idx = (bid - 17) * 256 + tid;
        int j = idx >> 7, k = idx & 127;
        const float* wr = w2d + (size_t)j * 384 + k;
        float w0 = wr[0], w1 = wr[128], w2v = wr[256];
        wd2_a[idx] = (unsigned short)f2bf(3.f * w0);
        wd2_b[idx] = (unsigned short)f2bf(3.f * (w1 - w0));
        wd2_c[idx] = (unsigned short)f2bf(0.75f * w0 - 1.5f * w1 + 0.75f * w2v);
    } else if (bid < 97) {                // wrd: 128*32 (+brd)
        int idx = (bid - 81) * 256 + tid;
        int j = idx >> 5, i = idx & 31;
        float s = 0.f;
        for (int h = 0; h < 128; ++h) s += w1d[j * 128 + h] * recw[h * 32 + i];
        wrd[idx] = (unsigned short)f2bf(s);
        if (idx < 128) {
            float b = b1d[idx];
            for (int h = 0; h < 128; ++h) b += w1d[idx * 128 + h] * recb[h];
            brd[idx] = b;
        }
    } else {                              // w1 convert: 128*128
        int idx = (bid - 97) * 256 + tid;
        w1bf[idx] = (unsigned short)f2bf(w1e[idx]);
    }
}

// ---------- two-level exclusive scan -> rowstart (+ dinv fused) ----------
__global__ __launch_bounds__(SCAN_B) void scan_block_kernel(const int* __restrict__ degs,
                                                            int* __restrict__ rowstart,
                                                            int* __restrict__ blocksums,
                                                            float* __restrict__ dinv, int n) {
    __shared__ int sh[SCAN_B];
    int i = blockIdx.x * SCAN_B + threadIdx.x;
    int v = (i < n) ? degs[i] : 0;
    sh[threadIdx.x] = v;
    __syncthreads();
    for (int o = 1; o < SCAN_B; o <<= 1) {
        int t = (threadIdx.x >= o) ? sh[threadIdx.x - o] : 0;
        __syncthreads();
        sh[threadIdx.x] += t;
        __syncthreads();
    }
    if (i < n) {
        rowstart[i] = sh[threadIdx.x] - v;
        dinv[i] = 1.f / sqrtf(fmaxf((float)v, 1.f));
    }
    if (threadIdx.x == SCAN_B - 1) blocksums[blockIdx.x] = sh[threadIdx.x];
}

__global__ __launch_bounds__(512) void scan_sums_kernel(int* __restrict__ blocksums, int nb) {
    __shared__ int sh[512];
    int v = (threadIdx.x < nb) ? blocksums[threadIdx.x] : 0;
    sh[threadIdx.x] = v;
    __syncthreads();
    for (int o = 1; o < 512; o <<= 1) {
        int t = (threadIdx.x >= o) ? sh[threadIdx.x - o] : 0;
        __syncthreads();
        sh[threadIdx.x] += t;
        __syncthreads();
    }
    if (threadIdx.x < nb) blocksums[threadIdx.x] = sh[threadIdx.x] - v;
}

__global__ __launch_bounds__(SCAN_B) void scan_add_kernel(int* __restrict__ rowstart,
                                                          int* __restrict__ cursor,
                                                          const int* __restrict__ blocksums,
                                                          int* __restrict__ bstart,
                                                          int* __restrict__ bcursor,
                                                          int n, int e) {
    int i = blockIdx.x * SCAN_B + threadIdx.x;
    if (i < n) {
        int v = rowstart[i] + blocksums[blockIdx.x];
        rowstart[i] = v;
        cursor[i] = v;
        if ((i & 255) == 0) { bstart[i >> 8] = v; bcursor[i >> 8] = v; }
        if (i == 0) bstart[NBUCK] = e;
    }
}

// ---------- fused: fc1 MFMA GEMM || edge partition (phase C) ----------
__global__ __launch_bounds__(256) void fc1_part_kernel(const float* __restrict__ x,
                                                       const unsigned short* __restrict__ wbf,
                                                       const float* __restrict__ b,
                                                       unsigned short* __restrict__ out,
                                                       const int* __restrict__ src,
                                                       const int* __restrict__ dst,
                                                       int* __restrict__ bcursor,
                                                       int* __restrict__ ebuf,
                                                       int n, int e) {
    if (blockIdx.x >= FC1_BLOCKS) {       // partition: bucket edges by dst>>8
        __shared__ int hist[NBUCK], lofs[NBUCK], gbase[NBUCK];
        int pid = blockIdx.x - FC1_BLOCKS;
        int e0 = pid * PART_CHUNK;
        int e1 = min(e0 + PART_CHUNK, e);
        int tid = threadIdx.x;
        for (int bb = tid; bb < NBUCK; bb += 256) hist[bb] = 0;
        __syncthreads();
        for (int i = e0 + tid; i < e1; i += 256) atomicAdd(&hist[dst[i] >> 8], 1);
        __syncthreads();
        for (int bb = tid; bb < NBUCK; bb += 256) {
            int cct = hist[bb];
            gbase[bb] = cct ? atomicAdd(&bcursor[bb], cct) : 0;
            lofs[bb] = 0;
        }
        __syncthreads();
        for (int i = e0 + tid; i < e1; i += 256) {
            int d = dst[i];
            int bb = d >> 8;
            int pos = gbase[bb] + atomicAdd(&lofs[bb], 1);
            ebuf[pos] = (src[i] << 8) | (d & 255);
        }
        return;
    }
    int wv = threadIdx.x >> 6, lane = threadIdx.x & 63;
    int l16 = lane & 15, lhi = lane >> 4;
    int rowbase = blockIdx.x * 64 + wv * 16;
    int arow = rowbase + l16;
    f32x4 acc[8];
    #pragma unroll
    for (int jt = 0; jt < 8; ++jt) {
        float bj = b[jt * 16 + l16];
        acc[jt] = (f32x4){bj, bj, bj, bj};
    }
    #pragma unroll
    for (int kk = 0; kk < 4; ++kk) {
        int kbase = kk * 32 + lhi * 8;
        i32x4 afrag = {0, 0, 0, 0};
        if (arow < n) {
            const float* ap = x + (size_t)arow * F + kbase;
            f32x4 f0 = *reinterpret_cast<const f32x4*>(ap);
            f32x4 f1 = *reinterpret_cast<const f32x4*>(ap + 4);
            afrag.x = (int)(f2bf(f0.x) | (f2bf(f0.y) << 16));
            afrag.y = (int)(f2bf(f0.z) | (f2bf(f0.w) << 16));
            afrag.z = (int)(f2bf(f1.x) | (f2bf(f1.y) << 16));
            afrag.w = (int)(f2bf(f1.z) | (f2bf(f1.w) << 16));
        }
        #pragma unroll
        for (int jt = 0; jt < 8; ++jt) {
            i32x4 bfrag = *reinterpret_cast<const i32x4*>(wbf + (size_t)(jt * 16 + l16) * F + kbase);
            acc[jt] = mfma16(afrag, bfrag, acc[jt]);
        }
    }
    #pragma unroll
    for (int jt = 0; jt < 8; ++jt)
        #pragma unroll
        for (int r = 0; r < 4; ++r) {
            int row = rowbase + lhi * 4 + r;
            if (row < n)
                out[(size_t)row * F + jt * 16 + l16] =
                    (unsigned short)f2bf(fmaxf(acc[jt][r], 0.f));
        }
}

// ---------- fused: encoder projection G=[G0|G1|G2] || CSR phase D ----------
__global__ __launch_bounds__(256) void encproj_csr_kernel(const unsigned short* __restrict__ A,
                                                          const unsigned short* __restrict__ Wcat,
                                                          unsigned short* __restrict__ G0,
                                                          unsigned short* __restrict__ G1,
                                                          unsigned short* __restrict__ G2,
                                                          const int* __restrict__ ebuf,
                                                          const int* __restrict__ bstart,
                                                          int* __restrict__ cursor,
                                                          int* __restrict__ csr_src,
                                                          int n) {
    if (blockIdx.x >= ENC_BLOCKS) {       // phase D: within-bucket scatter
        int bb = blockIdx.x - ENC_BLOCKS;
        int s0 = bstart[bb], s1 = bstart[bb + 1];
        for (int i = s0 + (int)threadIdx.x; i < s1; i += 256) {
            int p = ebuf[i];
            int d = (bb << 8) | (p & 255);
            int pos = atomicAdd(&cursor[d], 1);
            csr_src[pos] = p >> 8;
        }
        return;
    }
    int wv = threadIdx.x >> 6, lane = threadIdx.x & 63;
    int l16 = lane & 15, lhi = lane >> 4;
    int rowbase = blockIdx.x * 64 + wv * 16;
    int arow = rowbase + l16;
    f32x4 acc[6];
    #pragma unroll
    for (int jt = 0; jt < 6; ++jt) acc[jt] = (f32x4){0.f, 0.f, 0.f, 0.f};
    #pragma unroll
    for (int kk = 0; kk < 4; ++kk) {
        int kbase = kk * 32 + lhi * 8;
        i32x4 afrag = {0, 0, 0, 0};
        if (arow < n)
            afrag = *reinterpret_cast<const i32x4*>(A + (size_t)arow * F + kbase);
        #pragma unroll
        for (int jt = 0; jt < 6; ++jt) {
            i32x4 bfrag = *reinterpret_cast<const i32x4*>(Wcat + (size_t)(jt * 16 + l16) * F + kbase);
            acc[jt] = mfma16(afrag, bfrag, acc[jt]);
        }
    }
    #pragma unroll
    for (int jt = 0; jt < 6; ++jt)
        #pragma unroll
        for (int r = 0; r < 4; ++r) {
            int row = rowbase + lhi * 4 + r;
            int j = jt * 16 + l16;
            if (row < n) {
                unsigned short v = (unsigned short)f2bf(acc[jt][r]);
                if (j < 32)      G0[(size_t)row * 32 + j] = v;
                else if (j < 64) G1[(size_t)row * 32 + (j - 32)] = v;
                else             G2[(size_t)row * 32 + (j - 64)] = v;
            }
        }
}

// ---------- 32-wide gather: W = G1 + P(G2); 16-lane groups, shfl prefetch ----------
__global__ __launch_bounds__(256) void gather32_W_kernel(const unsigned short* __restrict__ G2,
                                                         const unsigned short* __restrict__ G1,
                                                         const int* __restrict__ csr_src,
                                                         const int* __restrict__ rowstart,
                                                         const int* __restrict__ degs,
                                                         const float* __restrict__ dinv,
                                                         unsigned short* __restrict__ W, int n) {
    int r = blockIdx.x * 16 + (threadIdx.x >> 4);
    if (r >= n) return;
    int lane = threadIdx.x & 15;
    int c = lane * 2;
    int start = rowstart[r], deg = degs[r];
    float ax = 0.f, ay = 0.f;
    for (int base = 0; base < deg; base += 16) {
        int cnt = min(deg - base, 16);
        int s = 0; float sc = 0.f;
        if (lane < cnt) { s = csr_src[start + base + lane]; sc = dinv[s]; }
        int k = 0;
        for (; k + 4 <= cnt; k += 4) {
            int s0 = __shfl(s, k, 16), s1 = __shfl(s, k + 1, 16);
            int s2 = __shfl(s, k + 2, 16), s3 = __shfl(s, k + 3, 16);
            float c0 = __shfl(sc, k, 16), c1 = __shfl(sc, k + 1, 16);
            float c2 = __shfl(sc, k + 2, 16), c3 = __shfl(sc, k + 3, 16);
            unsigned v0 = *reinterpret_cast<const unsigned*>(G2 + (size_t)s0 * 32 + c);
            unsigned v1 = *reinterpret_cast<const unsigned*>(G2 + (size_t)s1 * 32 + c);
            unsigned v2 = *reinterpret_cast<const unsigned*>(G2 + (size_t)s2 * 32 + c);
            unsigned v3 = *reinterpret_cast<const unsigned*>(G2 + (size_t)s3 * 32 + c);
            ax += bf2f(v0 & 0xffffu) * c0 + bf2f(v1 & 0xffffu) * c1
                + bf2f(v2 & 0xffffu) * c2 + bf2f(v3 & 0xffffu) * c3;
            ay += bf2f(v0 >> 16) * c0 + bf2f(v1 >> 16) * c1
                + bf2f(v2 >> 16) * c2 + bf2f(v3 >> 16) * c3;
        }
        for (; k < cnt; ++k) {
            int sk = __shfl(s, k, 16);
            float ck = __shfl(sc, k, 16);
            unsigned v = *reinterpret_cast<const unsigned*>(G2 + (size_t)sk * 32 + c);
            ax += bf2f(v & 0xffffu) * ck;
            ay += bf2f(v >> 16) * ck;
        }
    }
    float di = dinv[r];
    unsigned g2v = *reinterpret_cast<const unsigned*>(G2 + (size_t)r * 32 + c);
    unsigned g1v = *reinterpret_cast<const unsigned*>(G1 + (size_t)r * 32 + c);
    float wx = bf2f(g1v & 0xffffu) + bf2f(g2v & 0xffffu) - di * ax;
    float wy = bf2f(g1v >> 16)     + bf2f(g2v >> 16)     - di * ay;
    *reinterpret_cast<unsigned*>(W + (size_t)r * 32 + c) = f2bf(wx) | (f2bf(wy) << 16);
}

// ---------- 32-wide gather mu = G0 + P(W) + bmu, fused KL + reparam ----------
__global__ __launch_bounds__(256) void gather32_mukl_kernel(const unsigned short* __restrict__ W,
                                                            const unsigned short* __restrict__ G0,
                                                            const int* __restrict__ csr_src,
                                                            const int* __restrict__ rowstart,
                                                            const int* __restrict__ degs,
                                                            const float* __restrict__ dinv,
                                                            const float* __restrict__ bmu,
                                                            unsigned short* __restrict__ Z,
                                                            double* __restrict__ accd, int n) {
    int r = blockIdx.x * 16 + (threadIdx.x >> 4);
    int lane = threadIdx.x & 15;
    int c = lane * 2;
    float kl = 0.f;
    if (r < n) {
        int start = rowstart[r], deg = degs[r];
        float ax = 0.f, ay = 0.f;
        for (int base = 0; base < deg; base += 16) {
            int cnt = min(deg - base, 16);
            int s = 0; float sc = 0.f;
            if (lane < cnt) { s = csr_src[start + base + lane]; sc = dinv[s]; }
            int k = 0;
            for (; k + 4 <= cnt; k += 4) {
                int s0 = __shfl(s, k, 16), s1 = __shfl(s, k + 1, 16);
                int s2 = __shfl(s, k + 2, 16), s3 = __shfl(s, k + 3, 16);
                float c0 = __shfl(sc, k, 16), c1 = __shfl(sc, k + 1, 16);
                float c2 = __shfl(sc, k + 2, 16), c3 = __shfl(sc, k + 3, 16);
                unsigned v0 = *reinterpret_cast<const unsigned*>(W + (size_t)s0 * 32 + c);
                unsigned v1 = *reinterpret_cast<const unsigned*>(W + (size_t)s1 * 32 + c);
                unsigned v2 = *reinterpret_cast<const unsigned*>(W + (size_t)s2 * 32 + c);
                unsigned v3 = *reinterpret_cast<const unsigned*>(W + (size_t)s3 * 32 + c);
                ax += bf2f(v0 & 0xffffu) * c0 + bf2f(v1 & 0xffffu) * c1
                    + bf2f(v2 & 0xffffu) * c2 + bf2f(v3 & 0xffffu) * c3;
                ay += bf2f(v0 >> 16) * c0 + bf2f(v1 >> 16) * c1
                    + bf2f(v2 >> 16) * c2 + bf2f(v3 >> 16) * c3;
            }
            for (; k < cnt; ++k) {
                int sk = __shfl(s, k, 16);
                float ck = __shfl(sc, k, 16);
                unsigned v = *reinterpret_cast<const unsigned*>(W + (size_t)sk * 32 + c);
                ax += bf2f(v & 0xffffu) * ck;
                ay += bf2f(v >> 16) * ck;
            }
        }
        float di = dinv[r];
        unsigned wv = *reinterpret_cast<const unsigned*>(W + (size_t)r * 32 + c);
        unsigned g0v = *reinterpret_cast<const unsigned*>(G0 + (size_t)r * 32 + c);
        float mu0 = bf2f(g0v & 0xffffu) + bf2f(wv & 0xffffu) - di * ax + bmu[c];
        float mu1 = bf2f(g0v >> 16)     + bf2f(wv >> 16)     - di * ay + bmu[c + 1];
        kl = (1.f + mu0 - mu0 * mu0 - expf(mu0)) + (1.f + mu1 - mu1 * mu1 - expf(mu1));
        unsigned idx0 = (unsigned)(r * ZD + c);
        unsigned h1 = pcg_hash(2u * idx0 + 1u);
        unsigned h2 = pcg_hash(2u * idx0 + 2u);
        float u1 = ((float)h1 + 0.5f) * 2.3283064365386963e-10f;
        float u2 = ((float)h2 + 0.5f) * 2.3283064365386963e-10f;
        float eps0 = sqrtf(-2.f * logf(u1)) * cosf(6.283185307179586f * u2);
        unsigned idx1 = idx0 + 1u;
        unsigned h3 = pcg_hash(2u * idx1 + 1u);
        unsigned h4 = pcg_hash(2u * idx1 + 2u);
        float u3 = ((float)h3 + 0.5f) * 2.3283064365386963e-10f;
        float u4 = ((float)h4 + 0.5f) * 2.3283064365386963e-10f;
        float eps1 = sqrtf(-2.f * logf(u3)) * cosf(6.283185307179586f * u4);
        float z0 = mu0 + eps0 * expf(0.5f * mu0);
        float z1 = mu1 + eps1 * expf(0.5f * mu1);
        *reinterpret_cast<unsigned*>(Z + (size_t)r * ZD + c) = f2bf(z0) | (f2bf(z1) << 16);
    }
    float bs = block_reduce_sum(kl);
    if (threadIdx.x == 0) atomicAdd(&accd[1], (double)bs);
}

// ---------- 128-wide gather (decoder); 64-lane rows, shfl index prefetch ----------
__global__ __launch_bounds__(256) void gather128_kernel(const unsigned short* __restrict__ x,
                                                        const int* __restrict__ csr_src,
                                                        const int* __restrict__ rowstart,
                                                        const int* __restrict__ degs,
                                                        const float* __restrict__ dinv,
                                                        unsigned short* __restrict__ out, int n) {
    int r = blockIdx.x * 4 + (threadIdx.x >> 6);
    if (r >= n) return;
    int lane = threadIdx.x & 63;
    int c = lane * 2;
    int start = rowstart[r], deg = degs[r];
    float ax = 0.f, ay = 0.f;
    for (int base = 0; base < deg; base += 64) {
        int cnt = min(deg - base, 64);
        int s = 0; float sc = 0.f;
        if (lane < cnt) { s = csr_src[start + base + lane]; sc = dinv[s]; }
        int k = 0;
        for (; k + 4 <= cnt; k += 4) {
            int s0 = __shfl(s, k), s1 = __shfl(s, k + 1);
            int s2 = __shfl(s, k + 2), s3 = __shfl(s, k + 3);
            float c0 = __shfl(sc, k), c1 = __shfl(sc, k + 1);
            float c2 = __shfl(sc, k + 2), c3 = __shfl(sc, k + 3);
            unsigned v0 = *reinterpret_cast<const unsigned*>(x + (size_t)s0 * F + c);
            unsigned v1 = *reinterpret_cast<const unsigned*>(x + (size_t)s1 * F + c);
            unsigned v2 = *reinterpret_cast<const unsigned*>(x + (size_t)s2 * F + c);
            unsigned v3 = *reinterpret_cast<const unsigned*>(x + (size_t)s3 * F + c);
            ax += bf2f(v0 & 0xffffu) * c0 + bf2f(v1 & 0xffffu) * c1
                + bf2f(v2 & 0xffffu) * c2 + bf2f(v3 & 0xffffu) * c3;
            ay += bf2f(v0 >> 16) * c0 + bf2f(v1 >> 16) * c1
                + bf2f(v2 >> 16) * c2 + bf2f(v3 >> 16) * c3;
        }
        for (; k < cnt; ++k) {
            int sk = __shfl(s, k);
            float ck = __shfl(sc, k);
            unsigned v = *reinterpret_cast<const unsigned*>(x + (size_t)sk * F + c);
            ax += bf2f(v & 0xffffu) * ck;
            ay += bf2f(v >> 16) * ck;
        }
    }
    float di = dinv[r];
    unsigned xv = *reinterpret_cast<const unsigned*>(x + (size_t)r * F + c);
    float ox = bf2f(xv & 0xffffu) - di * ax;
    float oy = bf2f(xv >> 16) - di * ay;
    *reinterpret_cast<unsigned*>(out + (size_t)r * F + c) = f2bf(ox) | (f2bf(oy) << 16);
}

// ---------- recdec1: A = relu(Z @ Wrd^T + brd), K=32 ----------
__global__ __launch_bounds__(256) void recdec1_mfma_kernel(const unsigned short* __restrict__ Z,
                                                           const unsigned short* __restrict__ Wrd,
                                                           const float* __restrict__ brd,
                                                           unsigned short* __restrict__ out, int n) {
    int wv = threadIdx.x >> 6, lane = threadIdx.x & 63;
    int l16 = lane & 15, lhi = lane >> 4;
    int rowbase = blockIdx.x * 64 + wv * 16;
    int arow = rowbase + l16;
    int kbase = lhi * 8;
    i32x4 afrag = {0, 0, 0, 0};
    if (arow < n)
        afrag = *reinterpret_cast<const i32x4*>(Z + (size_t)arow * ZD + kbase);
    #pragma unroll
    for (int jt = 0; jt < 8; ++jt) {
        float bj = brd[jt * 16 + l16];
        f32x4 acc = (f32x4){bj, bj, bj, bj};
        i32x4 bfrag = *reinterpret_cast<const i32x4*>(Wrd + (size_t)(jt * 16 + l16) * ZD + kbase);
        acc = mfma16(afrag, bfrag, acc);
        #pragma unroll
        for (int r = 0; r < 4; ++r) {
            int row = rowbase + lhi * 4 + r;
            if (row < n)
                out[(size_t)row * F + jt * 16 + l16] =
                    (unsigned short)f2bf(fmaxf(acc[r], 0.f));
        }
    }
}

// ---------- dec2 GEMM (K=384 distributed) fused with reconstruction loss ----------
__global__ __launch_bounds__(256) void dec2loss_mfma_kernel(const unsigned short* __restrict__ A,
                                                            const unsigned short* __restrict__ B,
                                                            const unsigned short* __restrict__ C,
                                                            const unsigned short* __restrict__ Wa,
                                                            const unsigned short* __restrict__ Wb,
                                                            const unsigned short* __restrict__ Wc,
                                                            const float* __restrict__ b2,
                                                            const float* __restrict__ feats,
                                                            double* __restrict__ accd, int n) {
    int wv = threadIdx.x >> 6, lane = threadIdx.x & 63;
    int l16 = lane & 15, lhi = lane >> 4;
    int rowbase = blockIdx.x * 64 + wv * 16;
    int arow = rowbase + l16;
    f32x4 acc[8];
    #pragma unroll
    for (int jt = 0; jt < 8; ++jt) {
        float bj = b2[jt * 16 + l16];
        acc[jt] = (f32x4){bj, bj, bj, bj};
    }
    const unsigned short* mats[3] = {A, B, C};
    const unsigned short* ws[3]   = {Wa, Wb, Wc};
    #pragma unroll
    for (int s = 0; s < 3; ++s) {
        #pragma unroll
        for (int kk = 0; kk < 4; ++kk) {
            int kbase = kk * 32 + lhi * 8;
            i32x4 afrag = {0, 0, 0, 0};
            if (arow < n)
                afrag = *reinterpret_cast<const i32x4*>(mats[s] + (size_t)arow * F + kbase);
            #pragma unroll
            for (int jt = 0; jt < 8; ++jt) {
                i32x4 bfrag = *reinterpret_cast<const i32x4*>(ws[s] + (size_t)(jt * 16 + l16) * F + kbase);
                acc[jt] = mfma16(afrag, bfrag, acc[jt]);
            }
        }
    }
    float local = 0.f;
    #pragma unroll
    for (int jt = 0; jt < 8; ++jt)
        #pragma unroll
        for (int r = 0; r < 4; ++r) {
            int row = rowbase + lhi * 4 + r;
            if (row < n) {
                float d = acc[jt][r] - feats[(size_t)row * F + jt * 16 + l16];
                local += d * d;
            }
        }
    float bs = block_reduce_sum(local);
    if (threadIdx.x == 0) atomicAdd(&accd[0], (double)bs);
}

__global__ void finalize_kernel(const double* __restrict__ acc, float* __restrict__ out) {
    out[0] = (float)(acc[0] - 0.5 * acc[1]);
}

extern "C" void kernel_launch(void* const* d_in, const int* in_sizes, int n_in,
                              void* d_out, int out_size, void* d_ws, size_t ws_size,
                              hipStream_t stream) {
    const float* feats  = (const float*)d_in[0];
    const int*   src    = (const int*)d_in[1];
    const int*   dst    = (const int*)d_in[2];
    const float* enc_w1 = (const float*)d_in[3];
    const float* enc_b1 = (const float*)d_in[4];
    const float* enc_w2 = (const float*)d_in[5];
    const float* enc_b2 = (const float*)d_in[6];
    const float* dec_w1 = (const float*)d_in[7];
    const float* dec_b1 = (const float*)d_in[8];
    const float* dec_w2 = (const float*)d_in[9];
    const float* dec_b2 = (const float*)d_in[10];
    const float* rep_w  = (const float*)d_in[11];
    const float* rep_b  = (const float*)d_in[12];
    const float* rec_w  = (const float*)d_in[13];
    const float* rec_b  = (const float*)d_in[14];
    // d_in[15] = disc_w: unused (dgi branch cancels analytically)

    const int n = NN, e = EE;
    char* ws = (char*)d_ws;
    size_t off = 0;
    auto alloc = [&](size_t bytes) -> void* {
        void* p = ws + off;
        off += (bytes + 255) & ~(size_t)255;
        return p;
    };
    const size_t NFB = (size_t)n * F * sizeof(unsigned short);   // 25.6 MB
    const int nScanBlocks = (n + SCAN_B - 1) / SCAN_B;
    int*    degs    = (int*)alloc((size_t)n * sizeof(int));
    float*  dinv    = (float*)alloc((size_t)n * sizeof(float));
    int*    rowst   = (int*)alloc((size_t)n * sizeof(int));
    int*    cursor  = (int*)alloc((size_t)n * sizeof(int));
    int*    bsums   = (int*)alloc((size_t)nScanBlocks * sizeof(int));
    int*    bstart  = (int*)alloc((NBUCK + 1) * sizeof(int));
    int*    bcursor = (int*)alloc(NBUCK * sizeof(int));
    int*    ebuf    = (int*)alloc((size_t)e * sizeof(int));
    int*    csr_src = (int*)alloc((size_t)e * sizeof(int));
    unsigned short* Abf = (unsigned short*)alloc(NFB);
    unsigned short* Bbf = (unsigned short*)alloc(NFB);
    unsigned short* Cbf = (unsigned short*)alloc(NFB);
    unsigned short* G0  = (unsigned short*)alloc((size_t)n * 32 * sizeof(unsigned short));
    unsigned short* G1  = (unsigned short*)alloc((size_t)n * 32 * sizeof(unsigned short));
    unsigned short* G2  = (unsigned short*)alloc((size_t)n * 32 * sizeof(unsigned short));
    unsigned short* Wg  = (unsigned short*)alloc((size_t)n * 32 * sizeof(unsigned short));
    unsigned short* Zbf = (unsigned short*)alloc((size_t)n * ZD * sizeof(unsigned short));
    unsigned short* Wcat  = (unsigned short*)alloc(96 * 128 * sizeof(unsigned short));
    unsigned short* w1bf  = (unsigned short*)alloc(128 * 128 * sizeof(unsigned short));
    unsigned short* wd2_a = (unsigned short*)alloc(128 * 128 * sizeof(unsigned short));
    unsigned short* wd2_b = (unsigned short*)alloc(128 * 128 * sizeof(unsigned short));
    unsigned short* wd2_c = (unsigned short*)alloc(128 * 128 * sizeof(unsigned short));
    unsigned short* wrd   = (unsigned short*)alloc(128 * 32 * sizeof(unsigned short));
    float* bmu = (float*)alloc(32 * sizeof(float));
    float* brd = (float*)alloc(128 * sizeof(float));
    double* acc = (double*)alloc(2 * sizeof(double));

    const int gemm64   = (n + 63) / 64;     // 1563
    const int csrBlks  = (e + 255) / 256;   // 6250 (deg count)
    const int gathBlks = (n + 3) / 4;       // 25000 (128-wide)
    const int g32Blks  = (n + 15) / 16;     // 6250

    hipMemsetAsync(degs, 0, (size_t)n * sizeof(int), stream);
    hipMemsetAsync(acc, 0, 2 * sizeof(double), stream);

    // weight prep || degree count (fused)
    prep_deg_kernel<<<PREP_BLOCKS + csrBlks, 256, 0, stream>>>(
        rep_w, enc_w2, enc_b2, rep_b, dec_w2, dec_w1, rec_w, rec_b, dec_b1, enc_w1,
        Wcat, bmu, wd2_a, wd2_b, wd2_c, wrd, brd, w1bf, dst, degs, e);

    scan_block_kernel<<<nScanBlocks, SCAN_B, 0, stream>>>(degs, rowst, bsums, dinv, n);
    scan_sums_kernel<<<1, 512, 0, stream>>>(bsums, nScanBlocks);
    scan_add_kernel<<<nScanBlocks, SCAN_B, 0, stream>>>(rowst, cursor, bsums,
                                                        bstart, bcursor, n, e);

    // fc1 GEMM || edge partition phase C (fused; independent)
    fc1_part_kernel<<<FC1_BLOCKS + PART_BLOCKS, 256, 0, stream>>>(
        feats, w1bf, enc_b1, Abf, src, dst, bcursor, ebuf, n, e);

    // encoder projection || CSR phase D (fused; independent)
    encproj_csr_kernel<<<ENC_BLOCKS + NBUCK, 256, 0, stream>>>(
        Abf, Wcat, G0, G1, G2, ebuf, bstart, cursor, csr_src, n);

    // encoder gathers (32-wide x2 via linearity)
    gather32_W_kernel<<<g32Blks, 256, 0, stream>>>(G2, G1, csr_src, rowst, degs, dinv, Wg, n);
    gather32_mukl_kernel<<<g32Blks, 256, 0, stream>>>(Wg, G0, csr_src, rowst, degs, dinv,
                                                      bmu, Zbf, acc, n);

    // decoder
    recdec1_mfma_kernel<<<gemm64, 256, 0, stream>>>(Zbf, wrd, brd, Abf, n);
    gather128_kernel<<<gathBlks, 256, 0, stream>>>(Abf, csr_src, rowst, degs, dinv, Bbf, n);
    gather128_kernel<<<gathBlks, 256, 0, stream>>>(Bbf, csr_src, rowst, degs, dinv, Cbf, n);
    dec2loss_mfma_kernel<<<gemm64, 256, 0, stream>>>(Abf, Bbf, Cbf, wd2_a, wd2_b, wd2_c,
                                                     dec_b2, feats, acc, n);

    finalize_kernel<<<1, 1, 0, stream>>>(acc, (float*)d_out);
}

// Round 7
// 502.465 us; speedup vs baseline: 25.2148x; 1.1444x over previous
//
#include <hip/hip_runtime.h>
#include <math.h>

// Problem constants (fixed by the reference).
#define NN   100000
#define EE   1600000
#define F    128      // IN_FEATS == H == 128
#define ZD   32       // Z_DIM
#define SCAN_B 256
#define PREP_BLOCKS 161
#define FC1_BLOCKS  1563   // ceil(100000/64)
#define ENC_BLOCKS  1563
#define NBUCK 391          // ceil(100000/256) dst-range buckets
#define PART_CHUNK 8192
#define PART_BLOCKS 196    // ceil(1600000/8192)

// Algebra:
//  hs = [3x-3y1+0.75y2 | 3y1-1.5y2 | 0.75y2], y1=P(x), y2=P(y1)
//  hs @ W^T = x@(3W0)^T + y1@(3W1-3W0)^T + y2@(0.75W0-1.5W1+0.75W2)^T
//  P commutes with right-mult AND is linear:
//    mu = G0 + P(G1) + P^2(G2) + bmu = G0 + P(G1 + P(G2)) + bmu
//  Encoder: [G0|G1|G2] = A @ Wcat^T (n x 96);  W = G1 + P(G2) (32-wide gather);
//           mu = G0 + P(W) + bmu (32-wide gather, fused KL + reparam z)
//  Decoder keeps the 128-wide form (square weights).
//  out = vgae_loss = sum((x_rec-feats)^2) - 0.5*sum(1+mu-mu^2-exp(mu))
//  dec2loss: weights staged via LDS (XOR-swizzled, G4) to kill L2-latency
//  stalls on B-fragment loads.

typedef float f32x4 __attribute__((ext_vector_type(4)));
typedef int   i32x4 __attribute__((ext_vector_type(4)));
typedef __bf16 bf16x8 __attribute__((ext_vector_type(8)));

__device__ __forceinline__ f32x4 mfma16(i32x4 a, i32x4 b, f32x4 c) {
    return __builtin_amdgcn_mfma_f32_16x16x32_bf16(
        __builtin_bit_cast(bf16x8, a), __builtin_bit_cast(bf16x8, b), c, 0, 0, 0);
}

__device__ __forceinline__ unsigned f2bf(float f) {   // RNE float->bf16 (as u16)
    unsigned u = __float_as_uint(f);
    return (u + 0x7fffu + ((u >> 16) & 1u)) >> 16;
}
__device__ __forceinline__ float bf2f(unsigned h) { return __uint_as_float(h << 16); }

__device__ __forceinline__ unsigned pcg_hash(unsigned v) {
    v = v * 747796405u + 2891336453u;
    unsigned w = ((v >> ((v >> 28u) + 4u)) ^ v) * 277803737u;
    return (w >> 22u) ^ w;
}

__device__ __forceinline__ float block_reduce_sum(float v) {
    #pragma unroll
    for (int o = 32; o > 0; o >>= 1) v += __shfl_down(v, o, 64);
    __shared__ float s[8];
    int lane = threadIdx.x & 63, w = threadIdx.x >> 6;
    if (lane == 0) s[w] = v;
    __syncthreads();
    float t = 0.f;
    if (threadIdx.x == 0) {
        int nw = (blockDim.x + 63) >> 6;
        for (int i = 0; i < nw; ++i) t += s[i];
    }
    return t;
}

// ---------- fused: weight prep (blocks 0..160) || degree count (rest) ----------
__global__ __launch_bounds__(256) void prep_deg_kernel(
        const float* __restrict__ repw, const float* __restrict__ w2e,
        const float* __restrict__ b2e,  const float* __restrict__ repb,
        const float* __restrict__ w2d,
        const float* __restrict__ w1d,  const float* __restrict__ recw,
        const float* __restrict__ recb, const float* __restrict__ b1d,
        const float* __restrict__ w1e,
        unsigned short* __restrict__ Wcat,   // 96 x 128
        float* __restrict__ bmu,             // 32
        unsigned short* __restrict__ wd2_a,  // 128 x 128
        unsigned short* __restrict__ wd2_b,
        unsigned short* __restrict__ wd2_c,
        unsigned short* __restrict__ wrd,    // 128 x 32
        float* __restrict__ brd,             // 128
        unsigned short* __restrict__ w1bf,   // 128 x 128
        const int* __restrict__ dst, int* __restrict__ degs, int e) {
    int bid = blockIdx.x, tid = threadIdx.x;
    if (bid >= PREP_BLOCKS) {             // degree count
        int i = (bid - PREP_BLOCKS) * 256 + tid;
        if (i < e) atomicAdd(&degs[dst[i]], 1);
        return;
    }
    if (bid < 16) {                       // Wcat: 32*128 entries
        int idx = bid * 256 + tid;
        int i = idx >> 7, k = idx & 127;
        float m0 = 0.f, m1 = 0.f, m2 = 0.f;
        for (int h = 0; h < 128; ++h) {
            float r = repw[i * 128 + h];
            const float* wr = w2e + (size_t)h * 384 + k;
            m0 += r * wr[0];
            m1 += r * wr[128];
            m2 += r * wr[256];
        }
        Wcat[(size_t)i * 128 + k]        = (unsigned short)f2bf(3.f * m0);
        Wcat[(size_t)(32 + i) * 128 + k] = (unsigned short)f2bf(3.f * (m1 - m0));
        Wcat[(size_t)(64 + i) * 128 + k] = (unsigned short)f2bf(0.75f * m0 - 1.5f * m1 + 0.75f * m2);
    } else if (bid == 16) {               // bmu
        if (tid < 32) {
            float s = repb[tid];
            for (int h = 0; h < 128; ++h) s += repw[tid * 128 + h] * b2e[h];
            bmu[tid] = s;
        }
    } else if (bid < 81) {                // wd2: 128*128
        int idx = (bid - 17) * 256 + tid;
        int j = idx >> 7, k = idx & 127;
        const float* wr = w2d + (size_t)j * 384 + k;
        float w0 = wr[0], w1 = wr[128], w2v = wr[256];
        wd2_a[idx] = (unsigned short)f2bf(3.f * w0);
        wd2_b[idx] = (unsigned short)f2bf(3.f * (w1 - w0));
        wd2_c[idx] = (unsigned short)f2bf(0.75f * w0 - 1.5f * w1 + 0.75f * w2v);
    } else if (bid < 97) {                // wrd: 128*32 (+brd)
        int idx = (bid - 81) * 256 + tid;
        int j = idx >> 5, i = idx & 31;
        float s = 0.f;
        for (int h = 0; h < 128; ++h) s += w1d[j * 128 + h] * recw[h * 32 + i];
        wrd[idx] = (unsigned short)f2bf(s);
        if (idx < 128) {
            float b = b1d[idx];
            for (int h = 0; h < 128; ++h) b += w1d[idx * 128 + h] * recb[h];
            brd[idx] = b;
        }
    } else {                              // w1 convert: 128*128
        int idx = (bid - 97) * 256 + tid;
        w1bf[idx] = (unsigned short)f2bf(w1e[idx]);
    }
}

// ---------- two-level exclusive scan -> rowstart (+ dinv fused) ----------
__global__ __launch_bounds__(SCAN_B) void scan_block_kernel(const int* __restrict__ degs,
                                                            int* __restrict__ rowstart,
                                                            int* __restrict__ blocksums,
                                                            float* __restrict__ dinv, int n) {
    __shared__ int sh[SCAN_B];
    int i = blockIdx.x * SCAN_B + threadIdx.x;
    int v = (i < n) ? degs[i] : 0;
    sh[threadIdx.x] = v;
    __syncthreads();
    for (int o = 1; o < SCAN_B; o <<= 1) {
        int t = (threadIdx.x >= o) ? sh[threadIdx.x - o] : 0;
        __syncthreads();
        sh[threadIdx.x] += t;
        __syncthreads();
    }
    if (i < n) {
        rowstart[i] = sh[threadIdx.x] - v;
        dinv[i] = 1.f / sqrtf(fmaxf((float)v, 1.f));
    }
    if (threadIdx.x == SCAN_B - 1) blocksums[blockIdx.x] = sh[threadIdx.x];
}

__global__ __launch_bounds__(512) void scan_sums_kernel(int* __restrict__ blocksums, int nb) {
    __shared__ int sh[512];
    int v = (threadIdx.x < nb) ? blocksums[threadIdx.x] : 0;
    sh[threadIdx.x] = v;
    __syncthreads();
    for (int o = 1; o < 512; o <<= 1) {
        int t = (threadIdx.x >= o) ? sh[threadIdx.x - o] : 0;
        __syncthreads();
        sh[threadIdx.x] += t;
        __syncthreads();
    }
    if (threadIdx.x < nb) blocksums[threadIdx.x] = sh[threadIdx.x] - v;
}

__global__ __launch_bounds__(SCAN_B) void scan_add_kernel(int* __restrict__ rowstart,
                                                          int* __restrict__ cursor,
                                                          const int* __restrict__ blocksums,
                                                          int* __restrict__ bstart,
                                                          int* __restrict__ bcursor,
                                                          int n, int e) {
    int i = blockIdx.x * SCAN_B + threadIdx.x;
    if (i < n) {
        int v = rowstart[i] + blocksums[blockIdx.x];
        rowstart[i] = v;
        cursor[i] = v;
        if ((i & 255) == 0) { bstart[i >> 8] = v; bcursor[i >> 8] = v; }
        if (i == 0) bstart[NBUCK] = e;
    }
}

// ---------- fused: fc1 MFMA GEMM || edge partition (phase C) ----------
__global__ __launch_bounds__(256) void fc1_part_kernel(const float* __restrict__ x,
                                                       const unsigned short* __restrict__ wbf,
                                                       const float* __restrict__ b,
                                                       unsigned short* __restrict__ out,
                                                       const int* __restrict__ src,
                                                       const int* __restrict__ dst,
                                                       int* __restrict__ bcursor,
                                                       int* __restrict__ ebuf,
                                                       int n, int e) {
    if (blockIdx.x >= FC1_BLOCKS) {       // partition: bucket edges by dst>>8
        __shared__ int hist[NBUCK], lofs[NBUCK], gbase[NBUCK];
        int pid = blockIdx.x - FC1_BLOCKS;
        int e0 = pid * PART_CHUNK;
        int e1 = min(e0 + PART_CHUNK, e);
        int tid = threadIdx.x;
        for (int bb = tid; bb < NBUCK; bb += 256) hist[bb] = 0;
        __syncthreads();
        for (int i = e0 + tid; i < e1; i += 256) atomicAdd(&hist[dst[i] >> 8], 1);
        __syncthreads();
        for (int bb = tid; bb < NBUCK; bb += 256) {
            int cct = hist[bb];
            gbase[bb] = cct ? atomicAdd(&bcursor[bb], cct) : 0;
            lofs[bb] = 0;
        }
        __syncthreads();
        for (int i = e0 + tid; i < e1; i += 256) {
            int d = dst[i];
            int bb = d >> 8;
            int pos = gbase[bb] + atomicAdd(&lofs[bb], 1);
            ebuf[pos] = (src[i] << 8) | (d & 255);
        }
        return;
    }
    int wv = threadIdx.x >> 6, lane = threadIdx.x & 63;
    int l16 = lane & 15, lhi = lane >> 4;
    int rowbase = blockIdx.x * 64 + wv * 16;
    int arow = rowbase + l16;
    f32x4 acc[8];
    #pragma unroll
    for (int jt = 0; jt < 8; ++jt) {
        float bj = b[jt * 16 + l16];
        acc[jt] = (f32x4){bj, bj, bj, bj};
    }
    #pragma unroll
    for (int kk = 0; kk < 4; ++kk) {
        int kbase = kk * 32 + lhi * 8;
        i32x4 afrag = {0, 0, 0, 0};
        if (arow < n) {
            const float* ap = x + (size_t)arow * F + kbase;
            f32x4 f0 = *reinterpret_cast<const f32x4*>(ap);
            f32x4 f1 = *reinterpret_cast<const f32x4*>(ap + 4);
            afrag.x = (int)(f2bf(f0.x) | (f2bf(f0.y) << 16));
            afrag.y = (int)(f2bf(f0.z) | (f2bf(f0.w) << 16));
            afrag.z = (int)(f2bf(f1.x) | (f2bf(f1.y) << 16));
            afrag.w = (int)(f2bf(f1.z) | (f2bf(f1.w) << 16));
        }
        #pragma unroll
        for (int jt = 0; jt < 8; ++jt) {
            i32x4 bfrag = *reinterpret_cast<const i32x4*>(wbf + (size_t)(jt * 16 + l16) * F + kbase);
            acc[jt] = mfma16(afrag, bfrag, acc[jt]);
        }
    }
    #pragma unroll
    for (int jt = 0; jt < 8; ++jt)
        #pragma unroll
        for (int r = 0; r < 4; ++r) {
            int row = rowbase + lhi * 4 + r;
            if (row < n)
                out[(size_t)row * F + jt * 16 + l16] =
                    (unsigned short)f2bf(fmaxf(acc[jt][r], 0.f));
        }
}

// ---------- fused: encoder projection G=[G0|G1|G2] || CSR phase D ----------
__global__ __launch_bounds__(256) void encproj_csr_kernel(const unsigned short* __restrict__ A,
                                                          const unsigned short* __restrict__ Wcat,
                                                          unsigned short* __restrict__ G0,
                                                          unsigned short* __restrict__ G1,
                                                          unsigned short* __restrict__ G2,
                                                          const int* __restrict__ ebuf,
                                                          const int* __restrict__ bstart,
                                                          int* __restrict__ cursor,
                                                          int* __restrict__ csr_src,
                                                          int n) {
    if (blockIdx.x >= ENC_BLOCKS) {       // phase D: within-bucket scatter
        int bb = blockIdx.x - ENC_BLOCKS;
        int s0 = bstart[bb], s1 = bstart[bb + 1];
        for (int i = s0 + (int)threadIdx.x; i < s1; i += 256) {
            int p = ebuf[i];
            int d = (bb << 8) | (p & 255);
            int pos = atomicAdd(&cursor[d], 1);
            csr_src[pos] = p >> 8;
        }
        return;
    }
    int wv = threadIdx.x >> 6, lane = threadIdx.x & 63;
    int l16 = lane & 15, lhi = lane >> 4;
    int rowbase = blockIdx.x * 64 + wv * 16;
    int arow = rowbase + l16;
    f32x4 acc[6];
    #pragma unroll
    for (int jt = 0; jt < 6; ++jt) acc[jt] = (f32x4){0.f, 0.f, 0.f, 0.f};
    #pragma unroll
    for (int kk = 0; kk < 4; ++kk) {
        int kbase = kk * 32 + lhi * 8;
        i32x4 afrag = {0, 0, 0, 0};
        if (arow < n)
            afrag = *reinterpret_cast<const i32x4*>(A + (size_t)arow * F + kbase);
        #pragma unroll
        for (int jt = 0; jt < 6; ++jt) {
            i32x4 bfrag = *reinterpret_cast<const i32x4*>(Wcat + (size_t)(jt * 16 + l16) * F + kbase);
            acc[jt] = mfma16(afrag, bfrag, acc[jt]);
        }
    }
    #pragma unroll
    for (int jt = 0; jt < 6; ++jt)
        #pragma unroll
        for (int r = 0; r < 4; ++r) {
            int row = rowbase + lhi * 4 + r;
            int j = jt * 16 + l16;
            if (row < n) {
                unsigned short v = (unsigned short)f2bf(acc[jt][r]);
                if (j < 32)      G0[(size_t)row * 32 + j] = v;
                else if (j < 64) G1[(size_t)row * 32 + (j - 32)] = v;
                else             G2[(size_t)row * 32 + (j - 64)] = v;
            }
        }
}

// ---------- 32-wide gather: W = G1 + P(G2); 16-lane groups, shfl prefetch ----------
__global__ __launch_bounds__(256) void gather32_W_kernel(const unsigned short* __restrict__ G2,
                                                         const unsigned short* __restrict__ G1,
                                                         const int* __restrict__ csr_src,
                                                         const int* __restrict__ rowstart,
                                                         const int* __restrict__ degs,
                                                         const float* __restrict__ dinv,
                                                         unsigned short* __restrict__ W, int n) {
    int r = blockIdx.x * 16 + (threadIdx.x >> 4);
    if (r >= n) return;
    int lane = threadIdx.x & 15;
    int c = lane * 2;
    int start = rowstart[r], deg = degs[r];
    float ax = 0.f, ay = 0.f;
    for (int base = 0; base < deg; base += 16) {
        int cnt = min(deg - base, 16);
        int s = 0; float sc = 0.f;
        if (lane < cnt) { s = csr_src[start + base + lane]; sc = dinv[s]; }
        int k = 0;
        for (; k + 4 <= cnt; k += 4) {
            int s0 = __shfl(s, k, 16), s1 = __shfl(s, k + 1, 16);
            int s2 = __shfl(s, k + 2, 16), s3 = __shfl(s, k + 3, 16);
            float c0 = __shfl(sc, k, 16), c1 = __shfl(sc, k + 1, 16);
            float c2 = __shfl(sc, k + 2, 16), c3 = __shfl(sc, k + 3, 16);
            unsigned v0 = *reinterpret_cast<const unsigned*>(G2 + (size_t)s0 * 32 + c);
            unsigned v1 = *reinterpret_cast<const unsigned*>(G2 + (size_t)s1 * 32 + c);
            unsigned v2 = *reinterpret_cast<const unsigned*>(G2 + (size_t)s2 * 32 + c);
            unsigned v3 = *reinterpret_cast<const unsigned*>(G2 + (size_t)s3 * 32 + c);
            ax += bf2f(v0 & 0xffffu) * c0 + bf2f(v1 & 0xffffu) * c1
                + bf2f(v2 & 0xffffu) * c2 + bf2f(v3 & 0xffffu) * c3;
            ay += bf2f(v0 >> 16) * c0 + bf2f(v1 >> 16) * c1
                + bf2f(v2 >> 16) * c2 + bf2f(v3 >> 16) * c3;
        }
        for (; k < cnt; ++k) {
            int sk = __shfl(s, k, 16);
            float ck = __shfl(sc, k, 16);
            unsigned v = *reinterpret_cast<const unsigned*>(G2 + (size_t)sk * 32 + c);
            ax += bf2f(v & 0xffffu) * ck;
            ay += bf2f(v >> 16) * ck;
        }
    }
    float di = dinv[r];
    unsigned g2v = *reinterpret_cast<const unsigned*>(G2 + (size_t)r * 32 + c);
    unsigned g1v = *reinterpret_cast<const unsigned*>(G1 + (size_t)r * 32 + c);
    float wx = bf2f(g1v & 0xffffu) + bf2f(g2v & 0xffffu) - di * ax;
    float wy = bf2f(g1v >> 16)     + bf2f(g2v >> 16)     - di * ay;
    *reinterpret_cast<unsigned*>(W + (size_t)r * 32 + c) = f2bf(wx) | (f2bf(wy) << 16);
}

// ---------- 32-wide gather mu = G0 + P(W) + bmu, fused KL + reparam ----------
__global__ __launch_bounds__(256) void gather32_mukl_kernel(const unsigned short* __restrict__ W,
                                                            const unsigned short* __restrict__ G0,
                                                            const int* __restrict__ csr_src,
                                                            const int* __restrict__ rowstart,
                                                            const int* __restrict__ degs,
                                                            const float* __restrict__ dinv,
                                                            const float* __restrict__ bmu,
                                                            unsigned short* __restrict__ Z,
                                                            double* __restrict__ accd, int n) {
    int r = blockIdx.x * 16 + (threadIdx.x >> 4);
    int lane = threadIdx.x & 15;
    int c = lane * 2;
    float kl = 0.f;
    if (r < n) {
        int start = rowstart[r], deg = degs[r];
        float ax = 0.f, ay = 0.f;
        for (int base = 0; base < deg; base += 16) {
            int cnt = min(deg - base, 16);
            int s = 0; float sc = 0.f;
            if (lane < cnt) { s = csr_src[start + base + lane]; sc = dinv[s]; }
            int k = 0;
            for (; k + 4 <= cnt; k += 4) {
                int s0 = __shfl(s, k, 16), s1 = __shfl(s, k + 1, 16);
                int s2 = __shfl(s, k + 2, 16), s3 = __shfl(s, k + 3, 16);
                float c0 = __shfl(sc, k, 16), c1 = __shfl(sc, k + 1, 16);
                float c2 = __shfl(sc, k + 2, 16), c3 = __shfl(sc, k + 3, 16);
                unsigned v0 = *reinterpret_cast<const unsigned*>(W + (size_t)s0 * 32 + c);
                unsigned v1 = *reinterpret_cast<const unsigned*>(W + (size_t)s1 * 32 + c);
                unsigned v2 = *reinterpret_cast<const unsigned*>(W + (size_t)s2 * 32 + c);
                unsigned v3 = *reinterpret_cast<const unsigned*>(W + (size_t)s3 * 32 + c);
                ax += bf2f(v0 & 0xffffu) * c0 + bf2f(v1 & 0xffffu) * c1
                    + bf2f(v2 & 0xffffu) * c2 + bf2f(v3 & 0xffffu) * c3;
                ay += bf2f(v0 >> 16) * c0 + bf2f(v1 >> 16) * c1
                    + bf2f(v2 >> 16) * c2 + bf2f(v3 >> 16) * c3;
            }
            for (; k < cnt; ++k) {
                int sk = __shfl(s, k, 16);
                float ck = __shfl(sc, k, 16);
                unsigned v = *reinterpret_cast<const unsigned*>(W + (size_t)sk * 32 + c);
                ax += bf2f(v & 0xffffu) * ck;
                ay += bf2f(v >> 16) * ck;
            }
        }
        float di = dinv[r];
        unsigned wv = *reinterpret_cast<const unsigned*>(W + (size_t)r * 32 + c);
        unsigned g0v = *reinterpret_cast<const unsigned*>(G0 + (size_t)r * 32 + c);
        float mu0 = bf2f(g0v & 0xffffu) + bf2f(wv & 0xffffu) - di * ax + bmu[c];
        float mu1 = bf2f(g0v >> 16)     + bf2f(wv >> 16)     - di * ay + bmu[c + 1];
        kl = (1.f + mu0 - mu0 * mu0 - expf(mu0)) + (1.f + mu1 - mu1 * mu1 - expf(mu1));
        unsigned idx0 = (unsigned)(r * ZD + c);
        unsigned h1 = pcg_hash(2u * idx0 + 1u);
        unsigned h2 = pcg_hash(2u * idx0 + 2u);
        float u1 = ((float)h1 + 0.5f) * 2.3283064365386963e-10f;
        float u2 = ((float)h2 + 0.5f) * 2.3283064365386963e-10f;
        float eps0 = sqrtf(-2.f * logf(u1)) * cosf(6.283185307179586f * u2);
        unsigned idx1 = idx0 + 1u;
        unsigned h3 = pcg_hash(2u * idx1 + 1u);
        unsigned h4 = pcg_hash(2u * idx1 + 2u);
        float u3 = ((float)h3 + 0.5f) * 2.3283064365386963e-10f;
        float u4 = ((float)h4 + 0.5f) * 2.3283064365386963e-10f;
        float eps1 = sqrtf(-2.f * logf(u3)) * cosf(6.283185307179586f * u4);
        float z0 = mu0 + eps0 * expf(0.5f * mu0);
        float z1 = mu1 + eps1 * expf(0.5f * mu1);
        *reinterpret_cast<unsigned*>(Z + (size_t)r * ZD + c) = f2bf(z0) | (f2bf(z1) << 16);
    }
    float bs = block_reduce_sum(kl);
    if (threadIdx.x == 0) atomicAdd(&accd[1], (double)bs);
}

// ---------- 128-wide gather (decoder); 64-lane rows, shfl index prefetch ----------
__global__ __launch_bounds__(256) void gather128_kernel(const unsigned short* __restrict__ x,
                                                        const int* __restrict__ csr_src,
                                                        const int* __restrict__ rowstart,
                                                        const int* __restrict__ degs,
                                                        const float* __restrict__ dinv,
                                                        unsigned short* __restrict__ out, int n) {
    int r = blockIdx.x * 4 + (threadIdx.x >> 6);
    if (r >= n) return;
    int lane = threadIdx.x & 63;
    int c = lane * 2;
    int start = rowstart[r], deg = degs[r];
    float ax = 0.f, ay = 0.f;
    for (int base = 0; base < deg; base += 64) {
        int cnt = min(deg - base, 64);
        int s = 0; float sc = 0.f;
        if (lane < cnt) { s = csr_src[start + base + lane]; sc = dinv[s]; }
        int k = 0;
        for (; k + 4 <= cnt; k += 4) {
            int s0 = __shfl(s, k), s1 = __shfl(s, k + 1);
            int s2 = __shfl(s, k + 2), s3 = __shfl(s, k + 3);
            float c0 = __shfl(sc, k), c1 = __shfl(sc, k + 1);
            float c2 = __shfl(sc, k + 2), c3 = __shfl(sc, k + 3);
            unsigned v0 = *reinterpret_cast<const unsigned*>(x + (size_t)s0 * F + c);
            unsigned v1 = *reinterpret_cast<const unsigned*>(x + (size_t)s1 * F + c);
            unsigned v2 = *reinterpret_cast<const unsigned*>(x + (size_t)s2 * F + c);
            unsigned v3 = *reinterpret_cast<const unsigned*>(x + (size_t)s3 * F + c);
            ax += bf2f(v0 & 0xffffu) * c0 + bf2f(v1 & 0xffffu) * c1
                + bf2f(v2 & 0xffffu) * c2 + bf2f(v3 & 0xffffu) * c3;
            ay += bf2f(v0 >> 16) * c0 + bf2f(v1 >> 16) * c1
                + bf2f(v2 >> 16) * c2 + bf2f(v3 >> 16) * c3;
        }
        for (; k < cnt; ++k) {
            int sk = __shfl(s, k);
            float ck = __shfl(sc, k);
            unsigned v = *reinterpret_cast<const unsigned*>(x + (size_t)sk * F + c);
            ax += bf2f(v & 0xffffu) * ck;
            ay += bf2f(v >> 16) * ck;
        }
    }
    float di = dinv[r];
    unsigned xv = *reinterpret_cast<const unsigned*>(x + (size_t)r * F + c);
    float ox = bf2f(xv & 0xffffu) - di * ax;
    float oy = bf2f(xv >> 16) - di * ay;
    *reinterpret_cast<unsigned*>(out + (size_t)r * F + c) = f2bf(ox) | (f2bf(oy) << 16);
}

// ---------- recdec1: A = relu(Z @ Wrd^T + brd), K=32 ----------
__global__ __launch_bounds__(256) void recdec1_mfma_kernel(const unsigned short* __restrict__ Z,
                                                           const unsigned short* __restrict__ Wrd,
                                                           const float* __restrict__ brd,
                                                           unsigned short* __restrict__ out, int n) {
    int wv = threadIdx.x >> 6, lane = threadIdx.x & 63;
    int l16 = lane & 15, lhi = lane >> 4;
    int rowbase = blockIdx.x * 64 + wv * 16;
    int arow = rowbase + l16;
    int kbase = lhi * 8;
    i32x4 afrag = {0, 0, 0, 0};
    if (arow < n)
        afrag = *reinterpret_cast<const i32x4*>(Z + (size_t)arow * ZD + kbase);
    #pragma unroll
    for (int jt = 0; jt < 8; ++jt) {
        float bj = brd[jt * 16 + l16];
        f32x4 acc = (f32x4){bj, bj, bj, bj};
        i32x4 bfrag = *reinterpret_cast<const i32x4*>(Wrd + (size_t)(jt * 16 + l16) * ZD + kbase);
        acc = mfma16(afrag, bfrag, acc);
        #pragma unroll
        for (int r = 0; r < 4; ++r) {
            int row = rowbase + lhi * 4 + r;
            if (row < n)
                out[(size_t)row * F + jt * 16 + l16] =
                    (unsigned short)f2bf(fmaxf(acc[r], 0.f));
        }
    }
}

// ---------- dec2 GEMM (K=384) with LDS-staged swizzled weights + loss ----------
__global__ __launch_bounds__(256) void dec2loss_mfma_kernel(const unsigned short* __restrict__ A,
                                                            const unsigned short* __restrict__ B,
                                                            const unsigned short* __restrict__ C,
                                                            const unsigned short* __restrict__ Wa,
                                                            const unsigned short* __restrict__ Wb,
                                                            const unsigned short* __restrict__ Wc,
                                                            const float* __restrict__ b2,
                                                            const float* __restrict__ feats,
                                                            double* __restrict__ accd, int n) {
    __shared__ __align__(16) unsigned short wsh[128 * 128];   // 32 KB, XOR-swizzled
    int tid = threadIdx.x;
    int wv = tid >> 6, lane = tid & 63;
    int l16 = lane & 15, lhi = lane >> 4;
    int rowbase = blockIdx.x * 64 + wv * 16;
    int arow = rowbase + l16;
    // prefetch feats (loss operand) into registers: overlaps with staging+MFMA
    float fpre[8][4];
    #pragma unroll
    for (int jt = 0; jt < 8; ++jt)
        #pragma unroll
        for (int r = 0; r < 4; ++r) {
            int row = rowbase + lhi * 4 + r;
            fpre[jt][r] = (row < n) ? feats[(size_t)row * F + jt * 16 + l16] : 0.f;
        }
    f32x4 acc[8];
    #pragma unroll
    for (int jt = 0; jt < 8; ++jt) {
        float bj = b2[jt * 16 + l16];
        acc[jt] = (f32x4){bj, bj, bj, bj};
    }
    const unsigned short* mats[3] = {A, B, C};
    const unsigned short* wsrc[3] = {Wa, Wb, Wc};
    #pragma unroll
    for (int s = 0; s < 3; ++s) {
        __syncthreads();
        // stage 32 KB: 2048 x 16B chunks; swizzle byte-col ^= (row&7)<<4
        #pragma unroll
        for (int it = 0; it < 8; ++it) {
            int idx = it * 256 + tid;           // 0..2047
            int j = idx >> 4;                   // row
            int colb = (idx & 15) << 4;         // byte col within row
            i32x4 v = *reinterpret_cast<const i32x4*>(wsrc[s] + (size_t)j * 128 + ((idx & 15) << 3));
            *reinterpret_cast<i32x4*>((char*)wsh + j * 256 + (colb ^ ((j & 7) << 4))) = v;
        }
        __syncthreads();
        #pragma unroll
        for (int kk = 0; kk < 4; ++kk) {
            i32x4 afrag = {0, 0, 0, 0};
            if (arow < n)
                afrag = *reinterpret_cast<const i32x4*>(mats[s] + (size_t)arow * F + kk * 32 + lhi * 8);
            #pragma unroll
            for (int jt = 0; jt < 8; ++jt) {
                int j = jt * 16 + l16;
                int colb = (kk * 64 + lhi * 16) ^ ((j & 7) << 4);
                i32x4 bfrag = *reinterpret_cast<const i32x4*>((const char*)wsh + j * 256 + colb);
                acc[jt] = mfma16(afrag, bfrag, acc[jt]);
            }
        }
    }
    float local = 0.f;
    #pragma unroll
    for (int jt = 0; jt < 8; ++jt)
        #pragma unroll
        for (int r = 0; r < 4; ++r) {
            int row = rowbase + lhi * 4 + r;
            if (row < n) {
                float d = acc[jt][r] - fpre[jt][r];
                local += d * d;
            }
        }
    float bs = block_reduce_sum(local);
    if (threadIdx.x == 0) atomicAdd(&accd[0], (double)bs);
}

__global__ void finalize_kernel(const double* __restrict__ acc, float* __restrict__ out) {
    out[0] = (float)(acc[0] - 0.5 * acc[1]);
}

extern "C" void kernel_launch(void* const* d_in, const int* in_sizes, int n_in,
                              void* d_out, int out_size, void* d_ws, size_t ws_size,
                              hipStream_t stream) {
    const float* feats  = (const float*)d_in[0];
    const int*   src    = (const int*)d_in[1];
    const int*   dst    = (const int*)d_in[2];
    const float* enc_w1 = (const float*)d_in[3];
    const float* enc_b1 = (const float*)d_in[4];
    const float* enc_w2 = (const float*)d_in[5];
    const float* enc_b2 = (const float*)d_in[6];
    const float* dec_w1 = (const float*)d_in[7];
    const float* dec_b1 = (const float*)d_in[8];
    const float* dec_w2 = (const float*)d_in[9];
    const float* dec_b2 = (const float*)d_in[10];
    const float* rep_w  = (const float*)d_in[11];
    const float* rep_b  = (const float*)d_in[12];
    const float* rec_w  = (const float*)d_in[13];
    const float* rec_b  = (const float*)d_in[14];
    // d_in[15] = disc_w: unused (dgi branch cancels analytically)

    const int n = NN, e = EE;
    char* ws = (char*)d_ws;
    size_t off = 0;
    auto alloc = [&](size_t bytes) -> void* {
        void* p = ws + off;
        off += (bytes + 255) & ~(size_t)255;
        return p;
    };
    const size_t NFB = (size_t)n * F * sizeof(unsigned short);   // 25.6 MB
    const int nScanBlocks = (n + SCAN_B - 1) / SCAN_B;
    int*    degs    = (int*)alloc((size_t)n * sizeof(int));
    float*  dinv    = (float*)alloc((size_t)n * sizeof(float));
    int*    rowst   = (int*)alloc((size_t)n * sizeof(int));
    int*    cursor  = (int*)alloc((size_t)n * sizeof(int));
    int*    bsums   = (int*)alloc((size_t)nScanBlocks * sizeof(int));
    int*    bstart  = (int*)alloc((NBUCK + 1) * sizeof(int));
    int*    bcursor = (int*)alloc(NBUCK * sizeof(int));
    int*    ebuf    = (int*)alloc((size_t)e * sizeof(int));
    int*    csr_src = (int*)alloc((size_t)e * sizeof(int));
    unsigned short* Abf = (unsigned short*)alloc(NFB);
    unsigned short* Bbf = (unsigned short*)alloc(NFB);
    unsigned short* Cbf = (unsigned short*)alloc(NFB);
    unsigned short* G0  = (unsigned short*)alloc((size_t)n * 32 * sizeof(unsigned short));
    unsigned short* G1  = (unsigned short*)alloc((size_t)n * 32 * sizeof(unsigned short));
    unsigned short* G2  = (unsigned short*)alloc((size_t)n * 32 * sizeof(unsigned short));
    unsigned short* Wg  = (unsigned short*)alloc((size_t)n * 32 * sizeof(unsigned short));
    unsigned short* Zbf = (unsigned short*)alloc((size_t)n * ZD * sizeof(unsigned short));
    unsigned short* Wcat  = (unsigned short*)alloc(96 * 128 * sizeof(unsigned short));
    unsigned short* w1bf  = (unsigned short*)alloc(128 * 128 * sizeof(unsigned short));
    unsigned short* wd2_a = (unsigned short*)alloc(128 * 128 * sizeof(unsigned short));
    unsigned short* wd2_b = (unsigned short*)alloc(128 * 128 * sizeof(unsigned short));
    unsigned short* wd2_c = (unsigned short*)alloc(128 * 128 * sizeof(unsigned short));
    unsigned short* wrd   = (unsigned short*)alloc(128 * 32 * sizeof(unsigned short));
    float* bmu = (float*)alloc(32 * sizeof(float));
    float* brd = (float*)alloc(128 * sizeof(float));
    double* acc = (double*)alloc(2 * sizeof(double));

    const int gemm64   = (n + 63) / 64;     // 1563
    const int csrBlks  = (e + 255) / 256;   // 6250 (deg count)
    const int gathBlks = (n + 3) / 4;       // 25000 (128-wide)
    const int g32Blks  = (n + 15) / 16;     // 6250

    hipMemsetAsync(degs, 0, (size_t)n * sizeof(int), stream);
    hipMemsetAsync(acc, 0, 2 * sizeof(double), stream);

    // weight prep || degree count (fused)
    prep_deg_kernel<<<PREP_BLOCKS + csrBlks, 256, 0, stream>>>(
        rep_w, enc_w2, enc_b2, rep_b, dec_w2, dec_w1, rec_w, rec_b, dec_b1, enc_w1,
        Wcat, bmu, wd2_a, wd2_b, wd2_c, wrd, brd, w1bf, dst, degs, e);

    scan_block_kernel<<<nScanBlocks, SCAN_B, 0, stream>>>(degs, rowst, bsums, dinv, n);
    scan_sums_kernel<<<1, 512, 0, stream>>>(bsums, nScanBlocks);
    scan_add_kernel<<<nScanBlocks, SCAN_B, 0, stream>>>(rowst, cursor, bsums,
                                                        bstart, bcursor, n, e);

    // fc1 GEMM || edge partition phase C (fused; independent)
    fc1_part_kernel<<<FC1_BLOCKS + PART_BLOCKS, 256, 0, stream>>>(
        feats, w1bf, enc_b1, Abf, src, dst, bcursor, ebuf, n, e);

    // encoder projection || CSR phase D (fused; independent)
    encproj_csr_kernel<<<ENC_BLOCKS + NBUCK, 256, 0, stream>>>(
        Abf, Wcat, G0, G1, G2, ebuf, bstart, cursor, csr_src, n);

    // encoder gathers (32-wide x2 via linearity)
    gather32_W_kernel<<<g32Blks, 256, 0, stream>>>(G2, G1, csr_src, rowst, degs, dinv, Wg, n);
    gather32_mukl_kernel<<<g32Blks, 256, 0, stream>>>(Wg, G0, csr_src, rowst, degs, dinv,
                                                      bmu, Zbf, acc, n);

    // decoder
    recdec1_mfma_kernel<<<gemm64, 256, 0, stream>>>(Zbf, wrd, brd, Abf, n);
    gather128_kernel<<<gathBlks, 256, 0, stream>>>(Abf, csr_src, rowst, degs, dinv, Bbf, n);
    gather128_kernel<<<gathBlks, 256, 0, stream>>>(Bbf, csr_src, rowst, degs, dinv, Cbf, n);
    dec2loss_mfma_kernel<<<gemm64, 256, 0, stream>>>(Abf, Bbf, Cbf, wd2_a, wd2_b, wd2_c,
                                                     dec_b2, feats, acc, n);

    finalize_kernel<<<1, 1, 0, stream>>>(acc, (float*)d_out);
}

// Round 8
// 501.438 us; speedup vs baseline: 25.2664x; 1.0020x over previous
//
#include <hip/hip_runtime.h>
#include <math.h>

// Problem constants (fixed by the reference).
#define NN   100000
#define EE   1600000
#define F    128      // IN_FEATS == H == 128
#define ZD   32       // Z_DIM
#define SCAN_B 256
#define PREP_BLOCKS 161
#define FC1_BLOCKS  1563   // ceil(100000/64)
#define ENC_BLOCKS  1563
#define NBUCK 391          // ceil(100000/256) dst-range buckets
#define PART_CHUNK 8192
#define PART_BLOCKS 196    // ceil(1600000/8192)

// Algebra (scaled-propagation form; D = diag(dinv)):
//  All propagated matrices stored pre-scaled: X~ = D X. Then
//  P(X)~ = X~ - D^2 (sum_e X~[src])  -- NO per-edge dinv loads in gathers.
//  Row scaling commutes with right-mult: X @ W^T = D^-1 (X~ @ W^T).
//  Encoder: [G0|G~1|G~2] = A @ Wcat^T (G1,G2 scaled at write);
//    W~ = G~1 + G~2 - dinv^2 * sum(G~2[s]);  mu = G0 + rsq*W~ - dinv*sum(W~[s]) + bmu
//  Decoder: A~ = dinv*relu(z@Wrd^T+brd); B~ = A~ - dinv^2*sum(A~); C~ likewise;
//    x_rec = rsq*(A~@Wa + B~@Wb + C~@Wc) + b2
//  out = vgae_loss = sum((x_rec-feats)^2) - 0.5*sum(1+mu-mu^2-exp(mu))

typedef float f32x4 __attribute__((ext_vector_type(4)));
typedef int   i32x4 __attribute__((ext_vector_type(4)));
typedef __bf16 bf16x8 __attribute__((ext_vector_type(8)));

__device__ __forceinline__ f32x4 mfma16(i32x4 a, i32x4 b, f32x4 c) {
    return __builtin_amdgcn_mfma_f32_16x16x32_bf16(
        __builtin_bit_cast(bf16x8, a), __builtin_bit_cast(bf16x8, b), c, 0, 0, 0);
}

__device__ __forceinline__ unsigned f2bf(float f) {   // RNE float->bf16 (as u16)
    unsigned u = __float_as_uint(f);
    return (u + 0x7fffu + ((u >> 16) & 1u)) >> 16;
}
__device__ __forceinline__ float bf2f(unsigned h) { return __uint_as_float(h << 16); }

__device__ __forceinline__ unsigned pcg_hash(unsigned v) {
    v = v * 747796405u + 2891336453u;
    unsigned w = ((v >> ((v >> 28u) + 4u)) ^ v) * 277803737u;
    return (w >> 22u) ^ w;
}

__device__ __forceinline__ float block_reduce_sum(float v) {
    #pragma unroll
    for (int o = 32; o > 0; o >>= 1) v += __shfl_down(v, o, 64);
    __shared__ float s[8];
    int lane = threadIdx.x & 63, w = threadIdx.x >> 6;
    if (lane == 0) s[w] = v;
    __syncthreads();
    float t = 0.f;
    if (threadIdx.x == 0) {
        int nw = (blockDim.x + 63) >> 6;
        for (int i = 0; i < nw; ++i) t += s[i];
    }
    return t;
}

// ---------- fused: weight prep (blocks 0..160) || degree count (rest) ----------
__global__ __launch_bounds__(256) void prep_deg_kernel(
        const float* __restrict__ repw, const float* __restrict__ w2e,
        const float* __restrict__ b2e,  const float* __restrict__ repb,
        const float* __restrict__ w2d,
        const float* __restrict__ w1d,  const float* __restrict__ recw,
        const float* __restrict__ recb, const float* __restrict__ b1d,
        const float* __restrict__ w1e,
        unsigned short* __restrict__ Wcat,   // 96 x 128
        float* __restrict__ bmu,             // 32
        unsigned short* __restrict__ wd2_a,  // 128 x 128
        unsigned short* __restrict__ wd2_b,
        unsigned short* __restrict__ wd2_c,
        unsigned short* __restrict__ wrd,    // 128 x 32
        float* __restrict__ brd,             // 128
        unsigned short* __restrict__ w1bf,   // 128 x 128
        const int* __restrict__ dst, int* __restrict__ degs, int e) {
    int bid = blockIdx.x, tid = threadIdx.x;
    if (bid >= PREP_BLOCKS) {             // degree count
        int i = (bid - PREP_BLOCKS) * 256 + tid;
        if (i < e) atomicAdd(&degs[dst[i]], 1);
        return;
    }
    if (bid < 16) {                       // Wcat: 32*128 entries
        int idx = bid * 256 + tid;
        int i = idx >> 7, k = idx & 127;
        float m0 = 0.f, m1 = 0.f, m2 = 0.f;
        for (int h = 0; h < 128; ++h) {
            float r = repw[i * 128 + h];
            const float* wr = w2e + (size_t)h * 384 + k;
            m0 += r * wr[0];
            m1 += r * wr[128];
            m2 += r * wr[256];
        }
        Wcat[(size_t)i * 128 + k]        = (unsigned short)f2bf(3.f * m0);
        Wcat[(size_t)(32 + i) * 128 + k] = (unsigned short)f2bf(3.f * (m1 - m0));
        Wcat[(size_t)(64 + i) * 128 + k] = (unsigned short)f2bf(0.75f * m0 - 1.5f * m1 + 0.75f * m2);
    } else if (bid == 16) {               // bmu
        if (tid < 32) {
            float s = repb[tid];
            for (int h = 0; h < 128; ++h) s += repw[tid * 128 + h] * b2e[h];
            bmu[tid] = s;
        }
    } else if (bid < 81) {                // wd2: 128*128
        int idx = (bid - 17) * 256 + tid;
        int j = idx >> 7, k = idx & 127;
        const float* wr = w2d + (size_t)j * 384 + k;
        float w0 = wr[0], w1 = wr[128], w2v = wr[256];
        wd2_a[idx] = (unsigned short)f2bf(3.f * w0);
        wd2_b[idx] = (unsigned short)f2bf(3.f * (w1 - w0));
        wd2_c[idx] = (unsigned short)f2bf(0.75f * w0 - 1.5f * w1 + 0.75f * w2v);
    } else if (bid < 97) {                // wrd: 128*32 (+brd)
        int idx = (bid - 81) * 256 + tid;
        int j = idx >> 5, i = idx & 31;
        float s = 0.f;
        for (int h = 0; h < 128; ++h) s += w1d[j * 128 + h] * recw[h * 32 + i];
        wrd[idx] = (unsigned short)f2bf(s);
        if (idx < 128) {
            float b = b1d[idx];
            for (int h = 0; h < 128; ++h) b += w1d[idx * 128 + h] * recb[h];
            brd[idx] = b;
        }
    } else {                              // w1 convert: 128*128
        int idx = (bid - 97) * 256 + tid;
        w1bf[idx] = (unsigned short)f2bf(w1e[idx]);
    }
}

// ---------- two-level exclusive scan -> rowstart (+ dinv, rsq fused) ----------
__global__ __launch_bounds__(SCAN_B) void scan_block_kernel(const int* __restrict__ degs,
                                                            int* __restrict__ rowstart,
                                                            int* __restrict__ blocksums,
                                                            float* __restrict__ dinv,
                                                            float* __restrict__ rsq, int n) {
    __shared__ int sh[SCAN_B];
    int i = blockIdx.x * SCAN_B + threadIdx.x;
    int v = (i < n) ? degs[i] : 0;
    sh[threadIdx.x] = v;
    __syncthreads();
    for (int o = 1; o < SCAN_B; o <<= 1) {
        int t = (threadIdx.x >= o) ? sh[threadIdx.x - o] : 0;
        __syncthreads();
        sh[threadIdx.x] += t;
        __syncthreads();
    }
    if (i < n) {
        rowstart[i] = sh[threadIdx.x] - v;
        float d = fmaxf((float)v, 1.f);
        float s = sqrtf(d);
        rsq[i] = s;
        dinv[i] = 1.f / s;
    }
    if (threadIdx.x == SCAN_B - 1) blocksums[blockIdx.x] = sh[threadIdx.x];
}

__global__ __launch_bounds__(512) void scan_sums_kernel(int* __restrict__ blocksums, int nb) {
    __shared__ int sh[512];
    int v = (threadIdx.x < nb) ? blocksums[threadIdx.x] : 0;
    sh[threadIdx.x] = v;
    __syncthreads();
    for (int o = 1; o < 512; o <<= 1) {
        int t = (threadIdx.x >= o) ? sh[threadIdx.x - o] : 0;
        __syncthreads();
        sh[threadIdx.x] += t;
        __syncthreads();
    }
    if (threadIdx.x < nb) blocksums[threadIdx.x] = sh[threadIdx.x] - v;
}

__global__ __launch_bounds__(SCAN_B) void scan_add_kernel(int* __restrict__ rowstart,
                                                          int* __restrict__ cursor,
                                                          const int* __restrict__ blocksums,
                                                          int* __restrict__ bstart,
                                                          int* __restrict__ bcursor,
                                                          int n, int e) {
    int i = blockIdx.x * SCAN_B + threadIdx.x;
    if (i < n) {
        int v = rowstart[i] + blocksums[blockIdx.x];
        rowstart[i] = v;
        cursor[i] = v;
        if ((i & 255) == 0) { bstart[i >> 8] = v; bcursor[i >> 8] = v; }
        if (i == 0) bstart[NBUCK] = e;
    }
}

// ---------- fused: fc1 MFMA GEMM || edge partition (phase C) ----------
__global__ __launch_bounds__(256) void fc1_part_kernel(const float* __restrict__ x,
                                                       const unsigned short* __restrict__ wbf,
                                                       const float* __restrict__ b,
                                                       unsigned short* __restrict__ out,
                                                       const int* __restrict__ src,
                                                       const int* __restrict__ dst,
                                                       int* __restrict__ bcursor,
                                                       int* __restrict__ ebuf,
                                                       int n, int e) {
    if (blockIdx.x >= FC1_BLOCKS) {       // partition: bucket edges by dst>>8
        __shared__ int hist[NBUCK], lofs[NBUCK], gbase[NBUCK];
        int pid = blockIdx.x - FC1_BLOCKS;
        int e0 = pid * PART_CHUNK;
        int e1 = min(e0 + PART_CHUNK, e);
        int tid = threadIdx.x;
        for (int bb = tid; bb < NBUCK; bb += 256) hist[bb] = 0;
        __syncthreads();
        for (int i = e0 + tid; i < e1; i += 256) atomicAdd(&hist[dst[i] >> 8], 1);
        __syncthreads();
        for (int bb = tid; bb < NBUCK; bb += 256) {
            int cct = hist[bb];
            gbase[bb] = cct ? atomicAdd(&bcursor[bb], cct) : 0;
            lofs[bb] = 0;
        }
        __syncthreads();
        for (int i = e0 + tid; i < e1; i += 256) {
            int d = dst[i];
            int bb = d >> 8;
            int pos = gbase[bb] + atomicAdd(&lofs[bb], 1);
            ebuf[pos] = (src[i] << 8) | (d & 255);
        }
        return;
    }
    int wv = threadIdx.x >> 6, lane = threadIdx.x & 63;
    int l16 = lane & 15, lhi = lane >> 4;
    int rowbase = blockIdx.x * 64 + wv * 16;
    int arow = rowbase + l16;
    f32x4 acc[8];
    #pragma unroll
    for (int jt = 0; jt < 8; ++jt) {
        float bj = b[jt * 16 + l16];
        acc[jt] = (f32x4){bj, bj, bj, bj};
    }
    #pragma unroll
    for (int kk = 0; kk < 4; ++kk) {
        int kbase = kk * 32 + lhi * 8;
        i32x4 afrag = {0, 0, 0, 0};
        if (arow < n) {
            const float* ap = x + (size_t)arow * F + kbase;
            f32x4 f0 = *reinterpret_cast<const f32x4*>(ap);
            f32x4 f1 = *reinterpret_cast<const f32x4*>(ap + 4);
            afrag.x = (int)(f2bf(f0.x) | (f2bf(f0.y) << 16));
            afrag.y = (int)(f2bf(f0.z) | (f2bf(f0.w) << 16));
            afrag.z = (int)(f2bf(f1.x) | (f2bf(f1.y) << 16));
            afrag.w = (int)(f2bf(f1.z) | (f2bf(f1.w) << 16));
        }
        #pragma unroll
        for (int jt = 0; jt < 8; ++jt) {
            i32x4 bfrag = *reinterpret_cast<const i32x4*>(wbf + (size_t)(jt * 16 + l16) * F + kbase);
            acc[jt] = mfma16(afrag, bfrag, acc[jt]);
        }
    }
    #pragma unroll
    for (int jt = 0; jt < 8; ++jt)
        #pragma unroll
        for (int r = 0; r < 4; ++r) {
            int row = rowbase + lhi * 4 + r;
            if (row < n)
                out[(size_t)row * F + jt * 16 + l16] =
                    (unsigned short)f2bf(fmaxf(acc[jt][r], 0.f));
        }
}

// ---------- fused: encoder projection [G0|G~1|G~2] || CSR phase D ----------
__global__ __launch_bounds__(256) void encproj_csr_kernel(const unsigned short* __restrict__ A,
                                                          const unsigned short* __restrict__ Wcat,
                                                          const float* __restrict__ dinv,
                                                          unsigned short* __restrict__ G0,
                                                          unsigned short* __restrict__ G1s,
                                                          unsigned short* __restrict__ G2s,
                                                          const int* __restrict__ ebuf,
                                                          const int* __restrict__ bstart,
                                                          int* __restrict__ cursor,
                                                          int* __restrict__ csr_src,
                                                          int n) {
    if (blockIdx.x >= ENC_BLOCKS) {       // phase D: within-bucket scatter
        int bb = blockIdx.x - ENC_BLOCKS;
        int s0 = bstart[bb], s1 = bstart[bb + 1];
        for (int i = s0 + (int)threadIdx.x; i < s1; i += 256) {
            int p = ebuf[i];
            int d = (bb << 8) | (p & 255);
            int pos = atomicAdd(&cursor[d], 1);
            csr_src[pos] = p >> 8;
        }
        return;
    }
    int wv = threadIdx.x >> 6, lane = threadIdx.x & 63;
    int l16 = lane & 15, lhi = lane >> 4;
    int rowbase = blockIdx.x * 64 + wv * 16;
    int arow = rowbase + l16;
    float dv[4];
    #pragma unroll
    for (int r = 0; r < 4; ++r) {
        int row = rowbase + lhi * 4 + r;
        dv[r] = (row < n) ? dinv[row] : 1.f;
    }
    f32x4 acc[6];
    #pragma unroll
    for (int jt = 0; jt < 6; ++jt) acc[jt] = (f32x4){0.f, 0.f, 0.f, 0.f};
    #pragma unroll
    for (int kk = 0; kk < 4; ++kk) {
        int kbase = kk * 32 + lhi * 8;
        i32x4 afrag = {0, 0, 0, 0};
        if (arow < n)
            afrag = *reinterpret_cast<const i32x4*>(A + (size_t)arow * F + kbase);
        #pragma unroll
        for (int jt = 0; jt < 6; ++jt) {
            i32x4 bfrag = *reinterpret_cast<const i32x4*>(Wcat + (size_t)(jt * 16 + l16) * F + kbase);
            acc[jt] = mfma16(afrag, bfrag, acc[jt]);
        }
    }
    #pragma unroll
    for (int jt = 0; jt < 6; ++jt)
        #pragma unroll
        for (int r = 0; r < 4; ++r) {
            int row = rowbase + lhi * 4 + r;
            int j = jt * 16 + l16;
            if (row < n) {
                if (j < 32) {
                    G0[(size_t)row * 32 + j] = (unsigned short)f2bf(acc[jt][r]);
                } else if (j < 64) {
                    G1s[(size_t)row * 32 + (j - 32)] = (unsigned short)f2bf(acc[jt][r] * dv[r]);
                } else {
                    G2s[(size_t)row * 32 + (j - 64)] = (unsigned short)f2bf(acc[jt][r] * dv[r]);
                }
            }
        }
}

// ---------- 32-wide gather: W~ = G~1 + G~2 - dinv^2 * sum(G~2[s]) ----------
__global__ __launch_bounds__(256) void gather32_W_kernel(const unsigned short* __restrict__ G2s,
                                                         const unsigned short* __restrict__ G1s,
                                                         const int* __restrict__ csr_src,
                                                         const int* __restrict__ rowstart,
                                                         const int* __restrict__ degs,
                                                         const float* __restrict__ dinv,
                                                         unsigned short* __restrict__ W, int n) {
    int r = blockIdx.x * 16 + (threadIdx.x >> 4);
    if (r >= n) return;
    int lane = threadIdx.x & 15;
    int c = lane * 2;
    int start = rowstart[r], deg = degs[r];
    float ax = 0.f, ay = 0.f;
    for (int base = 0; base < deg; base += 16) {
        int cnt = min(deg - base, 16);
        int s = 0;
        if (lane < cnt) s = csr_src[start + base + lane];
        int k = 0;
        for (; k + 8 <= cnt; k += 8) {
            unsigned v[8];
            #pragma unroll
            for (int q = 0; q < 8; ++q) {
                int sq = __shfl(s, k + q, 16);
                v[q] = *reinterpret_cast<const unsigned*>(G2s + (size_t)sq * 32 + c);
            }
            #pragma unroll
            for (int q = 0; q < 8; ++q) {
                ax += bf2f(v[q] & 0xffffu);
                ay += bf2f(v[q] >> 16);
            }
        }
        for (; k < cnt; ++k) {
            int sk = __shfl(s, k, 16);
            unsigned v = *reinterpret_cast<const unsigned*>(G2s + (size_t)sk * 32 + c);
            ax += bf2f(v & 0xffffu);
            ay += bf2f(v >> 16);
        }
    }
    float di = dinv[r];
    float di2 = di * di;
    unsigned g2v = *reinterpret_cast<const unsigned*>(G2s + (size_t)r * 32 + c);
    unsigned g1v = *reinterpret_cast<const unsigned*>(G1s + (size_t)r * 32 + c);
    float wx = bf2f(g1v & 0xffffu) + bf2f(g2v & 0xffffu) - di2 * ax;
    float wy = bf2f(g1v >> 16)     + bf2f(g2v >> 16)     - di2 * ay;
    *reinterpret_cast<unsigned*>(W + (size_t)r * 32 + c) = f2bf(wx) | (f2bf(wy) << 16);
}

// ---------- 32-wide gather mu = G0 + rsq*W~ - dinv*sum(W~[s]) + bmu ----------
__global__ __launch_bounds__(256) void gather32_mukl_kernel(const unsigned short* __restrict__ W,
                                                            const unsigned short* __restrict__ G0,
                                                            const int* __restrict__ csr_src,
                                                            const int* __restrict__ rowstart,
                                                            const int* __restrict__ degs,
                                                            const float* __restrict__ dinv,
                                                            const float* __restrict__ rsq,
                                                            const float* __restrict__ bmu,
                                                            unsigned short* __restrict__ Z,
                                                            double* __restrict__ accd, int n) {
    int r = blockIdx.x * 16 + (threadIdx.x >> 4);
    int lane = threadIdx.x & 15;
    int c = lane * 2;
    float kl = 0.f;
    if (r < n) {
        int start = rowstart[r], deg = degs[r];
        float ax = 0.f, ay = 0.f;
        for (int base = 0; base < deg; base += 16) {
            int cnt = min(deg - base, 16);
            int s = 0;
            if (lane < cnt) s = csr_src[start + base + lane];
            int k = 0;
            for (; k + 8 <= cnt; k += 8) {
                unsigned v[8];
                #pragma unroll
                for (int q = 0; q < 8; ++q) {
                    int sq = __shfl(s, k + q, 16);
                    v[q] = *reinterpret_cast<const unsigned*>(W + (size_t)sq * 32 + c);
                }
                #pragma unroll
                for (int q = 0; q < 8; ++q) {
                    ax += bf2f(v[q] & 0xffffu);
                    ay += bf2f(v[q] >> 16);
                }
            }
            for (; k < cnt; ++k) {
                int sk = __shfl(s, k, 16);
                unsigned v = *reinterpret_cast<const unsigned*>(W + (size_t)sk * 32 + c);
                ax += bf2f(v & 0xffffu);
                ay += bf2f(v >> 16);
            }
        }
        float di = dinv[r];
        float rs = rsq[r];
        unsigned wv = *reinterpret_cast<const unsigned*>(W + (size_t)r * 32 + c);
        unsigned g0v = *reinterpret_cast<const unsigned*>(G0 + (size_t)r * 32 + c);
        float mu0 = bf2f(g0v & 0xffffu) + rs * bf2f(wv & 0xffffu) - di * ax + bmu[c];
        float mu1 = bf2f(g0v >> 16)     + rs * bf2f(wv >> 16)     - di * ay + bmu[c + 1];
        kl = (1.f + mu0 - mu0 * mu0 - expf(mu0)) + (1.f + mu1 - mu1 * mu1 - expf(mu1));
        unsigned idx0 = (unsigned)(r * ZD + c);
        unsigned h1 = pcg_hash(2u * idx0 + 1u);
        unsigned h2 = pcg_hash(2u * idx0 + 2u);
        float u1 = ((float)h1 + 0.5f) * 2.3283064365386963e-10f;
        float u2 = ((float)h2 + 0.5f) * 2.3283064365386963e-10f;
        float eps0 = sqrtf(-2.f * logf(u1)) * cosf(6.283185307179586f * u2);
        unsigned idx1 = idx0 + 1u;
        unsigned h3 = pcg_hash(2u * idx1 + 1u);
        unsigned h4 = pcg_hash(2u * idx1 + 2u);
        float u3 = ((float)h3 + 0.5f) * 2.3283064365386963e-10f;
        float u4 = ((float)h4 + 0.5f) * 2.3283064365386963e-10f;
        float eps1 = sqrtf(-2.f * logf(u3)) * cosf(6.283185307179586f * u4);
        float z0 = mu0 + eps0 * expf(0.5f * mu0);
        float z1 = mu1 + eps1 * expf(0.5f * mu1);
        *reinterpret_cast<unsigned*>(Z + (size_t)r * ZD + c) = f2bf(z0) | (f2bf(z1) << 16);
    }
    float bs = block_reduce_sum(kl);
    if (threadIdx.x == 0) atomicAdd(&accd[1], (double)bs);
}

// ---------- 128-wide gather (scaled space): out = x~ - dinv^2 * sum(x~[s]) ----------
__global__ __launch_bounds__(256) void gather128_kernel(const unsigned short* __restrict__ x,
                                                        const int* __restrict__ csr_src,
                                                        const int* __restrict__ rowstart,
                                                        const int* __restrict__ degs,
                                                        const float* __restrict__ dinv,
                                                        unsigned short* __restrict__ out, int n) {
    int r = blockIdx.x * 4 + (threadIdx.x >> 6);
    if (r >= n) return;
    int lane = threadIdx.x & 63;
    int c = lane * 2;
    int start = rowstart[r], deg = degs[r];
    float ax = 0.f, ay = 0.f;
    for (int base = 0; base < deg; base += 64) {
        int cnt = min(deg - base, 64);
        int s = 0;
        if (lane < cnt) s = csr_src[start + base + lane];
        int k = 0;
        for (; k + 8 <= cnt; k += 8) {
            unsigned v[8];
            #pragma unroll
            for (int q = 0; q < 8; ++q) {
                int sq = __shfl(s, k + q);
                v[q] = *reinterpret_cast<const unsigned*>(x + (size_t)sq * F + c);
            }
            #pragma unroll
            for (int q = 0; q < 8; ++q) {
                ax += bf2f(v[q] & 0xffffu);
                ay += bf2f(v[q] >> 16);
            }
        }
        for (; k < cnt; ++k) {
            int sk = __shfl(s, k);
            unsigned v = *reinterpret_cast<const unsigned*>(x + (size_t)sk * F + c);
            ax += bf2f(v & 0xffffu);
            ay += bf2f(v >> 16);
        }
    }
    float di = dinv[r];
    float di2 = di * di;
    unsigned xv = *reinterpret_cast<const unsigned*>(x + (size_t)r * F + c);
    float ox = bf2f(xv & 0xffffu) - di2 * ax;
    float oy = bf2f(xv >> 16) - di2 * ay;
    *reinterpret_cast<unsigned*>(out + (size_t)r * F + c) = f2bf(ox) | (f2bf(oy) << 16);
}

// ---------- recdec1: A~ = dinv * relu(Z @ Wrd^T + brd), K=32 ----------
__global__ __launch_bounds__(256) void recdec1_mfma_kernel(const unsigned short* __restrict__ Z,
                                                           const unsigned short* __restrict__ Wrd,
                                                           const float* __restrict__ brd,
                                                           const float* __restrict__ dinv,
                                                           unsigned short* __restrict__ out, int n) {
    int wv = threadIdx.x >> 6, lane = threadIdx.x & 63;
    int l16 = lane & 15, lhi = lane >> 4;
    int rowbase = blockIdx.x * 64 + wv * 16;
    int arow = rowbase + l16;
    int kbase = lhi * 8;
    float dv[4];
    #pragma unroll
    for (int r = 0; r < 4; ++r) {
        int row = rowbase + lhi * 4 + r;
        dv[r] = (row < n) ? dinv[row] : 1.f;
    }
    i32x4 afrag = {0, 0, 0, 0};
    if (arow < n)
        afrag = *reinterpret_cast<const i32x4*>(Z + (size_t)arow * ZD + kbase);
    #pragma unroll
    for (int jt = 0; jt < 8; ++jt) {
        float bj = brd[jt * 16 + l16];
        f32x4 acc = (f32x4){bj, bj, bj, bj};
        i32x4 bfrag = *reinterpret_cast<const i32x4*>(Wrd + (size_t)(jt * 16 + l16) * ZD + kbase);
        acc = mfma16(afrag, bfrag, acc);
        #pragma unroll
        for (int r = 0; r < 4; ++r) {
            int row = rowbase + lhi * 4 + r;
            if (row < n)
                out[(size_t)row * F + jt * 16 + l16] =
                    (unsigned short)f2bf(fmaxf(acc[r], 0.f) * dv[r]);
        }
    }
}

// ---------- dec2 GEMM (scaled inputs, LDS-staged weights) + loss ----------
__global__ __launch_bounds__(256) void dec2loss_mfma_kernel(const unsigned short* __restrict__ A,
                                                            const unsigned short* __restrict__ B,
                                                            const unsigned short* __restrict__ C,
                                                            const unsigned short* __restrict__ Wa,
                                                            const unsigned short* __restrict__ Wb,
                                                            const unsigned short* __restrict__ Wc,
                                                            const float* __restrict__ b2,
                                                            const float* __restrict__ rsq,
                                                            const float* __restrict__ feats,
                                                            double* __restrict__ accd, int n) {
    __shared__ __align__(16) unsigned short wsh[128 * 128];   // 32 KB, XOR-swizzled
    int tid = threadIdx.x;
    int wv = tid >> 6, lane = tid & 63;
    int l16 = lane & 15, lhi = lane >> 4;
    int rowbase = blockIdx.x * 64 + wv * 16;
    int arow = rowbase + l16;
    // prefetch feats + rsq into registers
    float fpre[8][4];
    float rsv[4];
    #pragma unroll
    for (int r = 0; r < 4; ++r) {
        int row = rowbase + lhi * 4 + r;
        rsv[r] = (row < n) ? rsq[row] : 1.f;
    }
    #pragma unroll
    for (int jt = 0; jt < 8; ++jt)
        #pragma unroll
        for (int r = 0; r < 4; ++r) {
            int row = rowbase + lhi * 4 + r;
            fpre[jt][r] = (row < n) ? feats[(size_t)row * F + jt * 16 + l16] : 0.f;
        }
    f32x4 acc[8];
    #pragma unroll
    for (int jt = 0; jt < 8; ++jt) acc[jt] = (f32x4){0.f, 0.f, 0.f, 0.f};
    const unsigned short* mats[3] = {A, B, C};
    const unsigned short* wsrc[3] = {Wa, Wb, Wc};
    #pragma unroll
    for (int s = 0; s < 3; ++s) {
        __syncthreads();
        // stage 32 KB: 2048 x 16B chunks; swizzle byte-col ^= (row&7)<<4
        #pragma unroll
        for (int it = 0; it < 8; ++it) {
            int idx = it * 256 + tid;           // 0..2047
            int j = idx >> 4;                   // row
            int colb = (idx & 15) << 4;         // byte col within row
            i32x4 v = *reinterpret_cast<const i32x4*>(wsrc[s] + (size_t)j * 128 + ((idx & 15) << 3));
            *reinterpret_cast<i32x4*>((char*)wsh + j * 256 + (colb ^ ((j & 7) << 4))) = v;
        }
        __syncthreads();
        #pragma unroll
        for (int kk = 0; kk < 4; ++kk) {
            i32x4 afrag = {0, 0, 0, 0};
            if (arow < n)
                afrag = *reinterpret_cast<const i32x4*>(mats[s] + (size_t)arow * F + kk * 32 + lhi * 8);
            #pragma unroll
            for (int jt = 0; jt < 8; ++jt) {
                int j = jt * 16 + l16;
                int colb = (kk * 64 + lhi * 16) ^ ((j & 7) << 4);
                i32x4 bfrag = *reinterpret_cast<const i32x4*>((const char*)wsh + j * 256 + colb);
                acc[jt] = mfma16(afrag, bfrag, acc[jt]);
            }
        }
    }
    float local = 0.f;
    #pragma unroll
    for (int jt = 0; jt < 8; ++jt) {
        float bj = b2[jt * 16 + l16];
        #pragma unroll
        for (int r = 0; r < 4; ++r) {
            int row = rowbase + lhi * 4 + r;
            if (row < n) {
                float d = acc[jt][r] * rsv[r] + bj - fpre[jt][r];
                local += d * d;
            }
        }
    }
    float bs = block_reduce_sum(local);
    if (threadIdx.x == 0) atomicAdd(&accd[0], (double)bs);
}

__global__ void finalize_kernel(const double* __restrict__ acc, float* __restrict__ out) {
    out[0] = (float)(acc[0] - 0.5 * acc[1]);
}

extern "C" void kernel_launch(void* const* d_in, const int* in_sizes, int n_in,
                              void* d_out, int out_size, void* d_ws, size_t ws_size,
                              hipStream_t stream) {
    const float* feats  = (const float*)d_in[0];
    const int*   src    = (const int*)d_in[1];
    const int*   dst    = (const int*)d_in[2];
    const float* enc_w1 = (const float*)d_in[3];
    const float* enc_b1 = (const float*)d_in[4];
    const float* enc_w2 = (const float*)d_in[5];
    const float* enc_b2 = (const float*)d_in[6];
    const float* dec_w1 = (const float*)d_in[7];
    const float* dec_b1 = (const float*)d_in[8];
    const float* dec_w2 = (const float*)d_in[9];
    const float* dec_b2 = (const float*)d_in[10];
    const float* rep_w  = (const float*)d_in[11];
    const float* rep_b  = (const float*)d_in[12];
    const float* rec_w  = (const float*)d_in[13];
    const float* rec_b  = (const float*)d_in[14];
    // d_in[15] = disc_w: unused (dgi branch cancels analytically)

    const int n = NN, e = EE;
    char* ws = (char*)d_ws;
    size_t off = 0;
    auto alloc = [&](size_t bytes) -> void* {
        void* p = ws + off;
        off += (bytes + 255) & ~(size_t)255;
        return p;
    };
    const size_t NFB = (size_t)n * F * sizeof(unsigned short);   // 25.6 MB
    const int nScanBlocks = (n + SCAN_B - 1) / SCAN_B;
    int*    degs    = (int*)alloc((size_t)n * sizeof(int));
    float*  dinv    = (float*)alloc((size_t)n * sizeof(float));
    float*  rsq     = (float*)alloc((size_t)n * sizeof(float));
    int*    rowst   = (int*)alloc((size_t)n * sizeof(int));
    int*    cursor  = (int*)alloc((size_t)n * sizeof(int));
    int*    bsums   = (int*)alloc((size_t)nScanBlocks * sizeof(int));
    int*    bstart  = (int*)alloc((NBUCK + 1) * sizeof(int));
    int*    bcursor = (int*)alloc(NBUCK * sizeof(int));
    int*    ebuf    = (int*)alloc((size_t)e * sizeof(int));
    int*    csr_src = (int*)alloc((size_t)e * sizeof(int));
    unsigned short* Abf = (unsigned short*)alloc(NFB);
    unsigned short* Bbf = (unsigned short*)alloc(NFB);
    unsigned short* Cbf = (unsigned short*)alloc(NFB);
    unsigned short* G0  = (unsigned short*)alloc((size_t)n * 32 * sizeof(unsigned short));
    unsigned short* G1  = (unsigned short*)alloc((size_t)n * 32 * sizeof(unsigned short));
    unsigned short* G2  = (unsigned short*)alloc((size_t)n * 32 * sizeof(unsigned short));
    unsigned short* Wg  = (unsigned short*)alloc((size_t)n * 32 * sizeof(unsigned short));
    unsigned short* Zbf = (unsigned short*)alloc((size_t)n * ZD * sizeof(unsigned short));
    unsigned short* Wcat  = (unsigned short*)alloc(96 * 128 * sizeof(unsigned short));
    unsigned short* w1bf  = (unsigned short*)alloc(128 * 128 * sizeof(unsigned short));
    unsigned short* wd2_a = (unsigned short*)alloc(128 * 128 * sizeof(unsigned short));
    unsigned short* wd2_b = (unsigned short*)alloc(128 * 128 * sizeof(unsigned short));
    unsigned short* wd2_c = (unsigned short*)alloc(128 * 128 * sizeof(unsigned short));
    unsigned short* wrd   = (unsigned short*)alloc(128 * 32 * sizeof(unsigned short));
    float* bmu = (float*)alloc(32 * sizeof(float));
    float* brd = (float*)alloc(128 * sizeof(float));
    double* acc = (double*)alloc(2 * sizeof(double));

    const int gemm64   = (n + 63) / 64;     // 1563
    const int csrBlks  = (e + 255) / 256;   // 6250 (deg count)
    const int gathBlks = (n + 3) / 4;       // 25000 (128-wide)
    const int g32Blks  = (n + 15) / 16;     // 6250

    hipMemsetAsync(degs, 0, (size_t)n * sizeof(int), stream);
    hipMemsetAsync(acc, 0, 2 * sizeof(double), stream);

    // weight prep || degree count (fused)
    prep_deg_kernel<<<PREP_BLOCKS + csrBlks, 256, 0, stream>>>(
        rep_w, enc_w2, enc_b2, rep_b, dec_w2, dec_w1, rec_w, rec_b, dec_b1, enc_w1,
        Wcat, bmu, wd2_a, wd2_b, wd2_c, wrd, brd, w1bf, dst, degs, e);

    scan_block_kernel<<<nScanBlocks, SCAN_B, 0, stream>>>(degs, rowst, bsums, dinv, rsq, n);
    scan_sums_kernel<<<1, 512, 0, stream>>>(bsums, nScanBlocks);
    scan_add_kernel<<<nScanBlocks, SCAN_B, 0, stream>>>(rowst, cursor, bsums,
                                                        bstart, bcursor, n, e);

    // fc1 GEMM || edge partition phase C (fused; independent)
    fc1_part_kernel<<<FC1_BLOCKS + PART_BLOCKS, 256, 0, stream>>>(
        feats, w1bf, enc_b1, Abf, src, dst, bcursor, ebuf, n, e);

    // encoder projection (scaled G1,G2) || CSR phase D (fused; independent)
    encproj_csr_kernel<<<ENC_BLOCKS + NBUCK, 256, 0, stream>>>(
        Abf, Wcat, dinv, G0, G1, G2, ebuf, bstart, cursor, csr_src, n);

    // encoder gathers (scaled space, no per-edge dinv)
    gather32_W_kernel<<<g32Blks, 256, 0, stream>>>(G2, G1, csr_src, rowst, degs, dinv, Wg, n);
    gather32_mukl_kernel<<<g32Blks, 256, 0, stream>>>(Wg, G0, csr_src, rowst, degs, dinv,
                                                      rsq, bmu, Zbf, acc, n);

    // decoder (scaled space throughout)
    recdec1_mfma_kernel<<<gemm64, 256, 0, stream>>>(Zbf, wrd, brd, dinv, Abf, n);
    gather128_kernel<<<gathBlks, 256, 0, stream>>>(Abf, csr_src, rowst, degs, dinv, Bbf, n);
    gather128_kernel<<<gathBlks, 256, 0, stream>>>(Bbf, csr_src, rowst, degs, dinv, Cbf, n);
    dec2loss_mfma_kernel<<<gemm64, 256, 0, stream>>>(Abf, Bbf, Cbf, wd2_a, wd2_b, wd2_c,
                                                     dec_b2, rsq, feats, acc, n);

    finalize_kernel<<<1, 1, 0, stream>>>(acc, (float*)d_out);
}